// Round 3
// baseline (381.117 us; speedup 1.0000x reference)
//
#include <hip/hip_runtime.h>

// CAMixer agent-attention, fused per-window (8x8).  v3:
//  - xw in LDS as bf16, c-quad tiled [c4][l] (dword pair = 4 channels), 130-dw block stride
//  - fused k/q logit pass (shared xw reads), wave-pair p assignment, in-register softmax
//  - P6b folded into P4 phase (6 barriers total)
//  - b64/b128 LDS everywhere: ~1.9k DS wave-insts/block (v2: ~3.7k)  [DS-pipe bound]
//  - 25.4 KB LDS -> 6 blocks/CU (24 waves)
//
// Algebra (exact refactor, verified round 1):
//   agent   = conv(pool(x), Wq)
//   k-logit[p][l] = xw[l]·gk[p] + bkd[p],  gk = xp @ Mk + bk2,  Mk = Wq^T Wk
//   q-logit[l][p] = xw[l]·gq[p] + bqd[p],  gq = xp @ Mq + bq2,  Mq = Wq^T Wq
//   agent_v = (a_attn @ xw) @ Wv^T + bv

constexpr int C_   = 96;
constexpr int Wimg = 192;
constexpr int HWp  = 192 * 192;
constexpr int NWIN = 24;
constexpr int Pp   = 7;

// ---------------- precompute (weights only) ----------------

__global__ void precompute_mats(const float* __restrict__ Wq,
                                const float* __restrict__ Wk,
                                float* __restrict__ Mk,
                                float* __restrict__ Mq)
{
    const int c  = blockIdx.x;
    const int cp = threadIdx.x;
    float ak = 0.f, aq = 0.f;
    for (int a = 0; a < C_; ++a) {
        const float wq = Wq[a * C_ + c];
        ak = fmaf(wq, Wk[a * C_ + cp], ak);
        aq = fmaf(wq, Wq[a * C_ + cp], aq);
    }
    Mk[c * C_ + cp] = ak;
    Mq[c * C_ + cp] = aq;
}

__global__ void precompute_vecs(const float* __restrict__ Wq,
                                const float* __restrict__ Wk,
                                const float* __restrict__ bq,
                                const float* __restrict__ bk,
                                float* __restrict__ uk,  float* __restrict__ uq,
                                float* __restrict__ bk2, float* __restrict__ bq2,
                                float* __restrict__ scal)
{
    const int c = threadIdx.x;
    float a_uk = 0.f, a_uq = 0.f, a_bk2 = 0.f, a_bq2 = 0.f;
    for (int a = 0; a < C_; ++a) {
        const float wqc = Wq[a * C_ + c];
        a_uk  = fmaf(wqc, bk[a], a_uk);
        a_uq  = fmaf(wqc, bq[a], a_uq);
        a_bk2 = fmaf(bq[a], Wk[a * C_ + c], a_bk2);
        a_bq2 = fmaf(bq[a], Wq[a * C_ + c], a_bq2);
    }
    uk[c] = a_uk; uq[c] = a_uq; bk2[c] = a_bk2; bq2[c] = a_bq2;
    if (c == 0) {
        float sk = 0.f, sq = 0.f;
        for (int a = 0; a < C_; ++a) { sk += bq[a] * bk[a]; sq += bq[a] * bq[a]; }
        scal[0] = sk; scal[1] = sq;
    }
}

// ---------------- helpers ----------------

__device__ __forceinline__ unsigned short f2bf(float f) {
    unsigned u = __float_as_uint(f);
    return (unsigned short)((u + 0x7FFFu + ((u >> 16) & 1u)) >> 16);
}
__device__ __forceinline__ float bflo(unsigned d) { return __uint_as_float(d << 16); }
__device__ __forceinline__ float bfhi(unsigned d) { return __uint_as_float(d & 0xFFFF0000u); }

// smem float-offset map (total 6496 floats = 25,984 B -> 6 blocks/CU)
//   xws  (uint)[24*130]     @ 0      bf16 x-window, tile (c4,l) at dword c4*130+2l
//   gkq  [2][7][96]         @ 3120
//   U1   xp[7][96] -> attn[7][66] -> avT[96][8]   @ 4464 (768)
//   xv   [7][96]            @ 5232
//   qat  [64][9]            @ 5904
//   bkd[8], bqd[8]          @ 6480

// ---------------- main fused kernel ----------------

__global__ __launch_bounds__(256, 6) void camixer_main(
    const float* __restrict__ x,
    const float* __restrict__ Wv,
    const float* __restrict__ bv,
    const float* __restrict__ Mk,
    const float* __restrict__ Mq,
    const float* __restrict__ uk,
    const float* __restrict__ uq,
    const float* __restrict__ bk2,
    const float* __restrict__ bq2,
    const float* __restrict__ scal,
    float* __restrict__ out)
{
    __shared__ __align__(16) float smem[6496];
    unsigned int* xws = (unsigned int*)smem;
    float* gkq = smem + 3120;          // [which][p][96]
    float* xp  = smem + 4464;          // [7][96]
    float* attn= smem + 4464;          // [7][66]
    float* avT = smem + 4464;          // [96][8]
    float* xv  = smem + 5232;          // [7][96]
    float* qat = smem + 5904;          // [64][9]
    float* bkd = smem + 6480;
    float* bqd = smem + 6488;

    const int t = threadIdx.x;
    // bijective XCD swizzle: 4608 = 8 * 576
    const int wid = ((blockIdx.x & 7) * 576) + (blockIdx.x >> 3);
    const int b  = wid / (NWIN * NWIN);
    const int r  = wid % (NWIN * NWIN);
    const int h0 = (r / NWIN) * 8;
    const int w0 = (r % NWIN) * 8;
    const int base = b * C_ * HWp + h0 * Wimg + w0;

    // ---- P0: x window -> bf16 LDS, (c4,l) tiles, b64 writes ----
    {
        const float4* x4 = reinterpret_cast<const float4*>(x);
        #pragma unroll
        for (int rr = 0; rr < 2; ++rr) {
            const int idx = t + (rr << 8);          // 384 tasks = 24 c4 x 8 dh x 2 dw4
            if (idx < 384) {
                const int dw4 = idx & 1;
                const int dh  = (idx >> 1) & 7;
                const int c4  = idx >> 4;
                float vv[4][4];
                #pragma unroll
                for (int j = 0; j < 4; ++j) {
                    const float4 v = x4[(base + (4*c4 + j) * HWp + dh * Wimg + 4*dw4) >> 2];
                    vv[j][0] = v.x; vv[j][1] = v.y; vv[j][2] = v.z; vv[j][3] = v.w;
                }
                const int l0 = dh * 8 + dw4 * 4;
                #pragma unroll
                for (int i = 0; i < 4; ++i) {
                    const unsigned d0 = (unsigned)f2bf(vv[0][i]) | ((unsigned)f2bf(vv[1][i]) << 16);
                    const unsigned d1 = (unsigned)f2bf(vv[2][i]) | ((unsigned)f2bf(vv[3][i]) << 16);
                    *reinterpret_cast<uint2*>(&xws[c4 * 130 + 2 * (l0 + i)]) = make_uint2(d0, d1);
                }
            }
        }
    }
    __syncthreads();

    // ---- P1: adaptive pool 64->7 (segments of 10, weight .1) -> xp ----
    if (t < 168) {                                   // (p, c4)
        const int p = t / 24, c4 = t - p * 24;
        const int s = (p << 6) / 7;                  // {0,9,18,27,36,45,54}
        float a0 = 0.f, a1 = 0.f, a2 = 0.f, a3 = 0.f;
        #pragma unroll
        for (int j = 0; j < 10; ++j) {
            const uint2 d = *reinterpret_cast<const uint2*>(&xws[c4 * 130 + 2 * (s + j)]);
            a0 += bflo(d.x); a1 += bfhi(d.x); a2 += bflo(d.y); a3 += bfhi(d.y);
        }
        *reinterpret_cast<float4*>(&xp[p * C_ + 4 * c4]) =
            make_float4(a0 * 0.1f, a1 * 0.1f, a2 * 0.1f, a3 * 0.1f);
    }
    __syncthreads();

    // ---- P2: gk/gq = xp@M + b2 ; bias dots ----
    if (t < 192) {
        const int which = (t >= C_) ? 1 : 0;
        const int cp = t - which * C_;
        const float* __restrict__ M = which ? Mq : Mk;
        float acc[Pp] = {};
        #pragma unroll 2
        for (int c4 = 0; c4 < 24; ++c4) {
            float4 xq[Pp];
            #pragma unroll
            for (int p = 0; p < Pp; ++p)
                xq[p] = *reinterpret_cast<const float4*>(&xp[p * C_ + 4 * c4]);
            const float m0 = M[(4*c4 + 0) * C_ + cp];
            const float m1 = M[(4*c4 + 1) * C_ + cp];
            const float m2 = M[(4*c4 + 2) * C_ + cp];
            const float m3 = M[(4*c4 + 3) * C_ + cp];
            #pragma unroll
            for (int p = 0; p < Pp; ++p) {
                acc[p] = fmaf(xq[p].x, m0, acc[p]);
                acc[p] = fmaf(xq[p].y, m1, acc[p]);
                acc[p] = fmaf(xq[p].z, m2, acc[p]);
                acc[p] = fmaf(xq[p].w, m3, acc[p]);
            }
        }
        const float b2 = (which ? bq2 : bk2)[cp];
        #pragma unroll
        for (int p = 0; p < Pp; ++p) gkq[which * 672 + p * C_ + cp] = acc[p] + b2;
    } else if (t < 192 + 14) {
        const int j = t - 192;                       // 0..13
        const int p = j % 7;
        const int which = j / 7;
        const float* __restrict__ u = which ? uq : uk;
        float acc = 0.f;
        #pragma unroll 4
        for (int c4 = 0; c4 < 24; ++c4) {
            const float4 xq = *reinterpret_cast<const float4*>(&xp[p * C_ + 4 * c4]);
            const float4 uu = *reinterpret_cast<const float4*>(&u[4 * c4]);
            acc = fmaf(xq.x, uu.x, acc); acc = fmaf(xq.y, uu.y, acc);
            acc = fmaf(xq.z, uu.z, acc); acc = fmaf(xq.w, uu.w, acc);
        }
        if (which) bqd[p] = acc + scal[1]; else bkd[p] = acc + scal[0];
    }
    __syncthreads();

    // ---- P3': fused k+q logits (wave pair {w, w+4}), k-softmax in-register ----
    {
        const int l = t & 63, w = t >> 6;
        const int p0 = w, p1 = 4 + w;
        const bool two = (w < 3);
        float ak0 = 0.f, aq0 = 0.f, ak1 = 0.f, aq1 = 0.f;
        #pragma unroll 6
        for (int c4 = 0; c4 < 24; ++c4) {
            const uint2 d = *reinterpret_cast<const uint2*>(&xws[c4 * 130 + 2 * l]);
            const float x0 = bflo(d.x), x1 = bfhi(d.x), x2 = bflo(d.y), x3 = bfhi(d.y);
            const float4 g0 = *reinterpret_cast<const float4*>(&gkq[p0 * C_ + 4 * c4]);
            const float4 q0 = *reinterpret_cast<const float4*>(&gkq[672 + p0 * C_ + 4 * c4]);
            ak0 = fmaf(x0, g0.x, ak0); ak0 = fmaf(x1, g0.y, ak0);
            ak0 = fmaf(x2, g0.z, ak0); ak0 = fmaf(x3, g0.w, ak0);
            aq0 = fmaf(x0, q0.x, aq0); aq0 = fmaf(x1, q0.y, aq0);
            aq0 = fmaf(x2, q0.z, aq0); aq0 = fmaf(x3, q0.w, aq0);
            if (two) {
                const float4 g1 = *reinterpret_cast<const float4*>(&gkq[p1 * C_ + 4 * c4]);
                const float4 q1 = *reinterpret_cast<const float4*>(&gkq[672 + p1 * C_ + 4 * c4]);
                ak1 = fmaf(x0, g1.x, ak1); ak1 = fmaf(x1, g1.y, ak1);
                ak1 = fmaf(x2, g1.z, ak1); ak1 = fmaf(x3, g1.w, ak1);
                aq1 = fmaf(x0, q1.x, aq1); aq1 = fmaf(x1, q1.y, aq1);
                aq1 = fmaf(x2, q1.z, aq1); aq1 = fmaf(x3, q1.w, aq1);
            }
        }
        // k-softmax over l (64-lane shuffles) + writes
        {
            const float v = ak0 + bkd[p0];
            float mx = v;
            #pragma unroll
            for (int off = 32; off; off >>= 1) mx = fmaxf(mx, __shfl_xor(mx, off));
            const float e = __expf(v - mx);
            float s = e;
            #pragma unroll
            for (int off = 32; off; off >>= 1) s += __shfl_xor(s, off);
            attn[p0 * 66 + l] = e / s;
            qat[l * 9 + p0] = aq0 + bqd[p0];
        }
        if (two) {
            const float v = ak1 + bkd[p1];
            float mx = v;
            #pragma unroll
            for (int off = 32; off; off >>= 1) mx = fmaxf(mx, __shfl_xor(mx, off));
            const float e = __expf(v - mx);
            float s = e;
            #pragma unroll
            for (int off = 32; off; off >>= 1) s += __shfl_xor(s, off);
            attn[p1 * 66 + l] = e / s;
            qat[l * 9 + p1] = aq1 + bqd[p1];
        }
    }
    __syncthreads();

    // ---- P4: xv = attn @ xw^T  (+ P6b q-softmax on wave 3) ----
    if (t < 168) {                                   // (p, c4)
        const int p = t / 24, c4 = t - p * 24;
        float a0 = 0.f, a1 = 0.f, a2 = 0.f, a3 = 0.f;
        #pragma unroll 8
        for (int l = 0; l < 64; ++l) {
            const uint2 d = *reinterpret_cast<const uint2*>(&xws[c4 * 130 + 2 * l]);
            const float aw = attn[p * 66 + l];
            a0 = fmaf(aw, bflo(d.x), a0); a1 = fmaf(aw, bfhi(d.x), a1);
            a2 = fmaf(aw, bflo(d.y), a2); a3 = fmaf(aw, bfhi(d.y), a3);
        }
        *reinterpret_cast<float4*>(&xv[p * C_ + 4 * c4]) = make_float4(a0, a1, a2, a3);
    } else if (t >= 192) {
        const int l = t - 192;                       // P6b: q-softmax over p
        float vv[Pp];
        float mx = -1e30f;
        #pragma unroll
        for (int p = 0; p < Pp; ++p) { vv[p] = qat[l * 9 + p]; mx = fmaxf(mx, vv[p]); }
        float s = 0.f;
        #pragma unroll
        for (int p = 0; p < Pp; ++p) { vv[p] = __expf(vv[p] - mx); s += vv[p]; }
        const float inv = 1.f / s;
        #pragma unroll
        for (int p = 0; p < Pp; ++p) qat[l * 9 + p] = vv[p] * inv;
    }
    __syncthreads();

    // ---- P5: avT[o][p] = xv[p]·Wv[o] + bv[o] ----
    for (int idx = t; idx < Pp * C_; idx += 256) {
        const int p = idx / C_, o = idx - p * C_;
        float acc = 0.f;
        #pragma unroll 6
        for (int c4 = 0; c4 < 24; ++c4) {
            const float4 v4 = *reinterpret_cast<const float4*>(&xv[p * C_ + 4 * c4]);
            const float4 w4 = *reinterpret_cast<const float4*>(&Wv[o * C_ + 4 * c4]);
            acc = fmaf(v4.x, w4.x, acc); acc = fmaf(v4.y, w4.y, acc);
            acc = fmaf(v4.z, w4.z, acc); acc = fmaf(v4.w, w4.w, acc);
        }
        avT[o * 8 + p] = acc + bv[o];
    }
    __syncthreads();

    // ---- P7: out = q_attn @ agent_v ----
    {
        const int l = t & 63, g = t >> 6;
        float qa[Pp];
        #pragma unroll
        for (int p = 0; p < Pp; ++p) qa[p] = qat[l * 9 + p];
        const int dh = l >> 3, dw = l & 7;
        const int obase = b * C_ * HWp + (h0 + dh) * Wimg + (w0 + dw);
        #pragma unroll 4
        for (int j = 0; j < 24; ++j) {
            const int o = g + 4 * j;                 // wave-uniform
            const float4 a0 = *reinterpret_cast<const float4*>(&avT[o * 8]);
            const float4 a1 = *reinterpret_cast<const float4*>(&avT[o * 8 + 4]);
            float acc = qa[0] * a0.x;
            acc = fmaf(qa[1], a0.y, acc);
            acc = fmaf(qa[2], a0.z, acc);
            acc = fmaf(qa[3], a0.w, acc);
            acc = fmaf(qa[4], a1.x, acc);
            acc = fmaf(qa[5], a1.y, acc);
            acc = fmaf(qa[6], a1.z, acc);
            out[obase + o * HWp] = acc;
        }
    }
}

// ---------------- launch ----------------

extern "C" void kernel_launch(void* const* d_in, const int* in_sizes, int n_in,
                              void* d_out, int out_size, void* d_ws, size_t ws_size,
                              hipStream_t stream)
{
    const float* x  = (const float*)d_in[0];
    const float* Wv = (const float*)d_in[1];
    const float* bv = (const float*)d_in[2];
    const float* Wq = (const float*)d_in[3];
    const float* bq = (const float*)d_in[4];
    const float* Wk = (const float*)d_in[5];
    const float* bk = (const float*)d_in[6];
    float* out = (float*)d_out;

    float* ws   = (float*)d_ws;
    float* Mk   = ws;                 // 9216
    float* Mq   = ws + 9216;          // 9216
    float* uk   = ws + 18432;         // 96
    float* uq   = ws + 18528;         // 96
    float* bk2  = ws + 18624;         // 96
    float* bq2  = ws + 18720;         // 96
    float* scal = ws + 18816;         // 2

    hipLaunchKernelGGL(precompute_mats, dim3(C_), dim3(C_), 0, stream,
                       Wq, Wk, Mk, Mq);
    hipLaunchKernelGGL(precompute_vecs, dim3(1), dim3(C_), 0, stream,
                       Wq, Wk, bq, bk, uk, uq, bk2, bq2, scal);
    hipLaunchKernelGGL(camixer_main, dim3(8 * NWIN * NWIN), dim3(256), 0, stream,
                       x, Wv, bv, Mk, Mq, uk, uq, bk2, bq2, scal, out);
}

// Round 4
// 209.339 us; speedup vs baseline: 1.8206x; 1.8206x over previous
//
#include <hip/hip_runtime.h>

// CAMixer agent-attention, fused per-window (8x8).  v4 = v3 with register fix:
//  - launch_bounds(256,4): v3's (256,6) forced VGPR=40 -> ~650MB scratch spill
//    (WRITE_SIZE 765MB vs 113MB output). LDS 25.9KB still allows 6 blocks/CU
//    at runtime if VGPRs land <=64.
//  - attn row stride 66->68 (16B aligned) -> P4 attn reads are b128
//  - P3' unroll 6->3 (register pressure)
//
// Algebra (exact refactor, verified round 1):
//   agent   = conv(pool(x), Wq)
//   k-logit[p][l] = xw[l]·gk[p] + bkd[p],  gk = xp @ Mk + bk2,  Mk = Wq^T Wk
//   q-logit[l][p] = xw[l]·gq[p] + bqd[p],  gq = xp @ Mq + bq2,  Mq = Wq^T Wq
//   agent_v = (a_attn @ xw) @ Wv^T + bv

constexpr int C_   = 96;
constexpr int Wimg = 192;
constexpr int HWp  = 192 * 192;
constexpr int NWIN = 24;
constexpr int Pp   = 7;

// ---------------- precompute (weights only) ----------------

__global__ void precompute_mats(const float* __restrict__ Wq,
                                const float* __restrict__ Wk,
                                float* __restrict__ Mk,
                                float* __restrict__ Mq)
{
    const int c  = blockIdx.x;
    const int cp = threadIdx.x;
    float ak = 0.f, aq = 0.f;
    for (int a = 0; a < C_; ++a) {
        const float wq = Wq[a * C_ + c];
        ak = fmaf(wq, Wk[a * C_ + cp], ak);
        aq = fmaf(wq, Wq[a * C_ + cp], aq);
    }
    Mk[c * C_ + cp] = ak;
    Mq[c * C_ + cp] = aq;
}

__global__ void precompute_vecs(const float* __restrict__ Wq,
                                const float* __restrict__ Wk,
                                const float* __restrict__ bq,
                                const float* __restrict__ bk,
                                float* __restrict__ uk,  float* __restrict__ uq,
                                float* __restrict__ bk2, float* __restrict__ bq2,
                                float* __restrict__ scal)
{
    const int c = threadIdx.x;
    float a_uk = 0.f, a_uq = 0.f, a_bk2 = 0.f, a_bq2 = 0.f;
    for (int a = 0; a < C_; ++a) {
        const float wqc = Wq[a * C_ + c];
        a_uk  = fmaf(wqc, bk[a], a_uk);
        a_uq  = fmaf(wqc, bq[a], a_uq);
        a_bk2 = fmaf(bq[a], Wk[a * C_ + c], a_bk2);
        a_bq2 = fmaf(bq[a], Wq[a * C_ + c], a_bq2);
    }
    uk[c] = a_uk; uq[c] = a_uq; bk2[c] = a_bk2; bq2[c] = a_bq2;
    if (c == 0) {
        float sk = 0.f, sq = 0.f;
        for (int a = 0; a < C_; ++a) { sk += bq[a] * bk[a]; sq += bq[a] * bq[a]; }
        scal[0] = sk; scal[1] = sq;
    }
}

// ---------------- helpers ----------------

__device__ __forceinline__ unsigned short f2bf(float f) {
    unsigned u = __float_as_uint(f);
    return (unsigned short)((u + 0x7FFFu + ((u >> 16) & 1u)) >> 16);
}
__device__ __forceinline__ float bflo(unsigned d) { return __uint_as_float(d << 16); }
__device__ __forceinline__ float bfhi(unsigned d) { return __uint_as_float(d & 0xFFFF0000u); }

// smem float-offset map (total 6496 floats = 25,984 B)
//   xws  (uint)[24*130]     @ 0      bf16 x-window, tile (c4,l) at dword c4*130+2l
//   gkq  [2][7][96]         @ 3120
//   U1   xp[7][96] -> attn[7][68] -> avT[96][8]   @ 4464 (768)
//   xv   [7][96]            @ 5232
//   qat  [64][9]            @ 5904
//   bkd[8], bqd[8]          @ 6480

// ---------------- main fused kernel ----------------

__global__ __launch_bounds__(256, 4) void camixer_main(
    const float* __restrict__ x,
    const float* __restrict__ Wv,
    const float* __restrict__ bv,
    const float* __restrict__ Mk,
    const float* __restrict__ Mq,
    const float* __restrict__ uk,
    const float* __restrict__ uq,
    const float* __restrict__ bk2,
    const float* __restrict__ bq2,
    const float* __restrict__ scal,
    float* __restrict__ out)
{
    __shared__ __align__(16) float smem[6496];
    unsigned int* xws = (unsigned int*)smem;
    float* gkq = smem + 3120;          // [which][p][96]
    float* xp  = smem + 4464;          // [7][96]
    float* attn= smem + 4464;          // [7][68]  (stride 68 -> 16B-aligned rows)
    float* avT = smem + 4464;          // [96][8]
    float* xv  = smem + 5232;          // [7][96]
    float* qat = smem + 5904;          // [64][9]
    float* bkd = smem + 6480;
    float* bqd = smem + 6488;

    const int t = threadIdx.x;
    // bijective XCD swizzle: 4608 = 8 * 576
    const int wid = ((blockIdx.x & 7) * 576) + (blockIdx.x >> 3);
    const int b  = wid / (NWIN * NWIN);
    const int r  = wid % (NWIN * NWIN);
    const int h0 = (r / NWIN) * 8;
    const int w0 = (r % NWIN) * 8;
    const int base = b * C_ * HWp + h0 * Wimg + w0;

    // ---- P0: x window -> bf16 LDS, (c4,l) tiles, b64 writes ----
    {
        const float4* x4 = reinterpret_cast<const float4*>(x);
        #pragma unroll
        for (int rr = 0; rr < 2; ++rr) {
            const int idx = t + (rr << 8);          // 384 tasks = 24 c4 x 8 dh x 2 dw4
            if (idx < 384) {
                const int dw4 = idx & 1;
                const int dh  = (idx >> 1) & 7;
                const int c4  = idx >> 4;
                float vv[4][4];
                #pragma unroll
                for (int j = 0; j < 4; ++j) {
                    const float4 v = x4[(base + (4*c4 + j) * HWp + dh * Wimg + 4*dw4) >> 2];
                    vv[j][0] = v.x; vv[j][1] = v.y; vv[j][2] = v.z; vv[j][3] = v.w;
                }
                const int l0 = dh * 8 + dw4 * 4;
                #pragma unroll
                for (int i = 0; i < 4; ++i) {
                    const unsigned d0 = (unsigned)f2bf(vv[0][i]) | ((unsigned)f2bf(vv[1][i]) << 16);
                    const unsigned d1 = (unsigned)f2bf(vv[2][i]) | ((unsigned)f2bf(vv[3][i]) << 16);
                    *reinterpret_cast<uint2*>(&xws[c4 * 130 + 2 * (l0 + i)]) = make_uint2(d0, d1);
                }
            }
        }
    }
    __syncthreads();

    // ---- P1: adaptive pool 64->7 (segments of 10, weight .1) -> xp ----
    if (t < 168) {                                   // (p, c4)
        const int p = t / 24, c4 = t - p * 24;
        const int s = (p << 6) / 7;                  // {0,9,18,27,36,45,54}
        float a0 = 0.f, a1 = 0.f, a2 = 0.f, a3 = 0.f;
        #pragma unroll
        for (int j = 0; j < 10; ++j) {
            const uint2 d = *reinterpret_cast<const uint2*>(&xws[c4 * 130 + 2 * (s + j)]);
            a0 += bflo(d.x); a1 += bfhi(d.x); a2 += bflo(d.y); a3 += bfhi(d.y);
        }
        *reinterpret_cast<float4*>(&xp[p * C_ + 4 * c4]) =
            make_float4(a0 * 0.1f, a1 * 0.1f, a2 * 0.1f, a3 * 0.1f);
    }
    __syncthreads();

    // ---- P2: gk/gq = xp@M + b2 ; bias dots ----
    if (t < 192) {
        const int which = (t >= C_) ? 1 : 0;
        const int cp = t - which * C_;
        const float* __restrict__ M = which ? Mq : Mk;
        float acc[Pp] = {};
        for (int c4 = 0; c4 < 24; ++c4) {
            float4 xq[Pp];
            #pragma unroll
            for (int p = 0; p < Pp; ++p)
                xq[p] = *reinterpret_cast<const float4*>(&xp[p * C_ + 4 * c4]);
            const float m0 = M[(4*c4 + 0) * C_ + cp];
            const float m1 = M[(4*c4 + 1) * C_ + cp];
            const float m2 = M[(4*c4 + 2) * C_ + cp];
            const float m3 = M[(4*c4 + 3) * C_ + cp];
            #pragma unroll
            for (int p = 0; p < Pp; ++p) {
                acc[p] = fmaf(xq[p].x, m0, acc[p]);
                acc[p] = fmaf(xq[p].y, m1, acc[p]);
                acc[p] = fmaf(xq[p].z, m2, acc[p]);
                acc[p] = fmaf(xq[p].w, m3, acc[p]);
            }
        }
        const float b2 = (which ? bq2 : bk2)[cp];
        #pragma unroll
        for (int p = 0; p < Pp; ++p) gkq[which * 672 + p * C_ + cp] = acc[p] + b2;
    } else if (t < 192 + 14) {
        const int j = t - 192;                       // 0..13
        const int p = j % 7;
        const int which = j / 7;
        const float* __restrict__ u = which ? uq : uk;
        float acc = 0.f;
        #pragma unroll 4
        for (int c4 = 0; c4 < 24; ++c4) {
            const float4 xq = *reinterpret_cast<const float4*>(&xp[p * C_ + 4 * c4]);
            const float4 uu = *reinterpret_cast<const float4*>(&u[4 * c4]);
            acc = fmaf(xq.x, uu.x, acc); acc = fmaf(xq.y, uu.y, acc);
            acc = fmaf(xq.z, uu.z, acc); acc = fmaf(xq.w, uu.w, acc);
        }
        if (which) bqd[p] = acc + scal[1]; else bkd[p] = acc + scal[0];
    }
    __syncthreads();

    // ---- P3': fused k+q logits (wave pair {w, w+4}), k-softmax in-register ----
    {
        const int l = t & 63, w = t >> 6;
        const int p0 = w, p1 = 4 + w;
        const bool two = (w < 3);
        float ak0 = 0.f, aq0 = 0.f, ak1 = 0.f, aq1 = 0.f;
        #pragma unroll 3
        for (int c4 = 0; c4 < 24; ++c4) {
            const uint2 d = *reinterpret_cast<const uint2*>(&xws[c4 * 130 + 2 * l]);
            const float x0 = bflo(d.x), x1 = bfhi(d.x), x2 = bflo(d.y), x3 = bfhi(d.y);
            const float4 g0 = *reinterpret_cast<const float4*>(&gkq[p0 * C_ + 4 * c4]);
            const float4 q0 = *reinterpret_cast<const float4*>(&gkq[672 + p0 * C_ + 4 * c4]);
            ak0 = fmaf(x0, g0.x, ak0); ak0 = fmaf(x1, g0.y, ak0);
            ak0 = fmaf(x2, g0.z, ak0); ak0 = fmaf(x3, g0.w, ak0);
            aq0 = fmaf(x0, q0.x, aq0); aq0 = fmaf(x1, q0.y, aq0);
            aq0 = fmaf(x2, q0.z, aq0); aq0 = fmaf(x3, q0.w, aq0);
            if (two) {
                const float4 g1 = *reinterpret_cast<const float4*>(&gkq[p1 * C_ + 4 * c4]);
                const float4 q1 = *reinterpret_cast<const float4*>(&gkq[672 + p1 * C_ + 4 * c4]);
                ak1 = fmaf(x0, g1.x, ak1); ak1 = fmaf(x1, g1.y, ak1);
                ak1 = fmaf(x2, g1.z, ak1); ak1 = fmaf(x3, g1.w, ak1);
                aq1 = fmaf(x0, q1.x, aq1); aq1 = fmaf(x1, q1.y, aq1);
                aq1 = fmaf(x2, q1.z, aq1); aq1 = fmaf(x3, q1.w, aq1);
            }
        }
        {
            const float v = ak0 + bkd[p0];
            float mx = v;
            #pragma unroll
            for (int off = 32; off; off >>= 1) mx = fmaxf(mx, __shfl_xor(mx, off));
            const float e = __expf(v - mx);
            float s = e;
            #pragma unroll
            for (int off = 32; off; off >>= 1) s += __shfl_xor(s, off);
            attn[p0 * 68 + l] = e / s;
            qat[l * 9 + p0] = aq0 + bqd[p0];
        }
        if (two) {
            const float v = ak1 + bkd[p1];
            float mx = v;
            #pragma unroll
            for (int off = 32; off; off >>= 1) mx = fmaxf(mx, __shfl_xor(mx, off));
            const float e = __expf(v - mx);
            float s = e;
            #pragma unroll
            for (int off = 32; off; off >>= 1) s += __shfl_xor(s, off);
            attn[p1 * 68 + l] = e / s;
            qat[l * 9 + p1] = aq1 + bqd[p1];
        }
    }
    __syncthreads();

    // ---- P4: xv = attn @ xw^T  (+ P6b q-softmax on wave 3) ----
    if (t < 168) {                                   // (p, c4)
        const int p = t / 24, c4 = t - p * 24;
        float a0 = 0.f, a1 = 0.f, a2 = 0.f, a3 = 0.f;
        #pragma unroll 4
        for (int l4 = 0; l4 < 16; ++l4) {
            const float4 aw4 = *reinterpret_cast<const float4*>(&attn[p * 68 + 4 * l4]);
            const uint2 d0 = *reinterpret_cast<const uint2*>(&xws[c4 * 130 + 8 * l4 + 0]);
            const uint2 d1 = *reinterpret_cast<const uint2*>(&xws[c4 * 130 + 8 * l4 + 2]);
            const uint2 d2 = *reinterpret_cast<const uint2*>(&xws[c4 * 130 + 8 * l4 + 4]);
            const uint2 d3 = *reinterpret_cast<const uint2*>(&xws[c4 * 130 + 8 * l4 + 6]);
            a0 = fmaf(aw4.x, bflo(d0.x), a0); a1 = fmaf(aw4.x, bfhi(d0.x), a1);
            a2 = fmaf(aw4.x, bflo(d0.y), a2); a3 = fmaf(aw4.x, bfhi(d0.y), a3);
            a0 = fmaf(aw4.y, bflo(d1.x), a0); a1 = fmaf(aw4.y, bfhi(d1.x), a1);
            a2 = fmaf(aw4.y, bflo(d1.y), a2); a3 = fmaf(aw4.y, bfhi(d1.y), a3);
            a0 = fmaf(aw4.z, bflo(d2.x), a0); a1 = fmaf(aw4.z, bfhi(d2.x), a1);
            a2 = fmaf(aw4.z, bflo(d2.y), a2); a3 = fmaf(aw4.z, bfhi(d2.y), a3);
            a0 = fmaf(aw4.w, bflo(d3.x), a0); a1 = fmaf(aw4.w, bfhi(d3.x), a1);
            a2 = fmaf(aw4.w, bflo(d3.y), a2); a3 = fmaf(aw4.w, bfhi(d3.y), a3);
        }
        *reinterpret_cast<float4*>(&xv[p * C_ + 4 * c4]) = make_float4(a0, a1, a2, a3);
    } else if (t >= 192) {
        const int l = t - 192;                       // P6b: q-softmax over p
        float vv[Pp];
        float mx = -1e30f;
        #pragma unroll
        for (int p = 0; p < Pp; ++p) { vv[p] = qat[l * 9 + p]; mx = fmaxf(mx, vv[p]); }
        float s = 0.f;
        #pragma unroll
        for (int p = 0; p < Pp; ++p) { vv[p] = __expf(vv[p] - mx); s += vv[p]; }
        const float inv = 1.f / s;
        #pragma unroll
        for (int p = 0; p < Pp; ++p) qat[l * 9 + p] = vv[p] * inv;
    }
    __syncthreads();

    // ---- P5: avT[o][p] = xv[p]·Wv[o] + bv[o] ----
    for (int idx = t; idx < Pp * C_; idx += 256) {
        const int p = idx / C_, o = idx - p * C_;
        float acc = 0.f;
        #pragma unroll 6
        for (int c4 = 0; c4 < 24; ++c4) {
            const float4 v4 = *reinterpret_cast<const float4*>(&xv[p * C_ + 4 * c4]);
            const float4 w4 = *reinterpret_cast<const float4*>(&Wv[o * C_ + 4 * c4]);
            acc = fmaf(v4.x, w4.x, acc); acc = fmaf(v4.y, w4.y, acc);
            acc = fmaf(v4.z, w4.z, acc); acc = fmaf(v4.w, w4.w, acc);
        }
        avT[o * 8 + p] = acc + bv[o];
    }
    __syncthreads();

    // ---- P7: out = q_attn @ agent_v ----
    {
        const int l = t & 63, g = t >> 6;
        float qa[Pp];
        #pragma unroll
        for (int p = 0; p < Pp; ++p) qa[p] = qat[l * 9 + p];
        const int dh = l >> 3, dw = l & 7;
        const int obase = b * C_ * HWp + (h0 + dh) * Wimg + (w0 + dw);
        #pragma unroll 4
        for (int j = 0; j < 24; ++j) {
            const int o = g + 4 * j;                 // wave-uniform
            const float4 a0 = *reinterpret_cast<const float4*>(&avT[o * 8]);
            const float4 a1 = *reinterpret_cast<const float4*>(&avT[o * 8 + 4]);
            float acc = qa[0] * a0.x;
            acc = fmaf(qa[1], a0.y, acc);
            acc = fmaf(qa[2], a0.z, acc);
            acc = fmaf(qa[3], a0.w, acc);
            acc = fmaf(qa[4], a1.x, acc);
            acc = fmaf(qa[5], a1.y, acc);
            acc = fmaf(qa[6], a1.z, acc);
            out[obase + o * HWp] = acc;
        }
    }
}

// ---------------- launch ----------------

extern "C" void kernel_launch(void* const* d_in, const int* in_sizes, int n_in,
                              void* d_out, int out_size, void* d_ws, size_t ws_size,
                              hipStream_t stream)
{
    const float* x  = (const float*)d_in[0];
    const float* Wv = (const float*)d_in[1];
    const float* bv = (const float*)d_in[2];
    const float* Wq = (const float*)d_in[3];
    const float* bq = (const float*)d_in[4];
    const float* Wk = (const float*)d_in[5];
    const float* bk = (const float*)d_in[6];
    float* out = (float*)d_out;

    float* ws   = (float*)d_ws;
    float* Mk   = ws;                 // 9216
    float* Mq   = ws + 9216;          // 9216
    float* uk   = ws + 18432;         // 96
    float* uq   = ws + 18528;         // 96
    float* bk2  = ws + 18624;         // 96
    float* bq2  = ws + 18720;         // 96
    float* scal = ws + 18816;         // 2

    hipLaunchKernelGGL(precompute_mats, dim3(C_), dim3(C_), 0, stream,
                       Wq, Wk, Mk, Mq);
    hipLaunchKernelGGL(precompute_vecs, dim3(1), dim3(C_), 0, stream,
                       Wq, Wk, bq, bk, uk, uq, bk2, bq2, scal);
    hipLaunchKernelGGL(camixer_main, dim3(8 * NWIN * NWIN), dim3(256), 0, stream,
                       x, Wv, bv, Mk, Mq, uk, uq, bk2, bq2, scal, out);
}

// Round 5
// 203.799 us; speedup vs baseline: 1.8701x; 1.0272x over previous
//
#include <hip/hip_runtime.h>

// CAMixer agent-attention, fused per-window (8x8).  v5 = v4 + MFMA for the two
// dominant phases (logits GEMM, xv GEMM). Scalar v4 code kept for P0/P1/P2/P5/P7.
//
// Algebra (exact refactor, verified round 1):
//   agent   = conv(pool(x), Wq)
//   k-logit[p][l] = xw[l]·gk[p] + bkd[p],  gk = xp @ Mk + bk2,  Mk = Wq^T Wk
//   q-logit[l][p] = xw[l]·gq[p] + bqd[p],  gq = xp @ Mq + bq2,  Mq = Wq^T Wq
//   agent_v = (a_attn @ xw) @ Wv^T + bv
//
// MFMA mapping (mfma_f32_16x16x32_bf16, assumed std layout):
//   A-frag: lane = row + 16*kblk holds A[row][ks*32 + kblk*8 + j], j=0..7
//   B-frag: lane = col + 16*kblk holds B[ks*32 + kblk*8 + j][col]
//   C-frag: col = lane&15, row = (lane>>4)*4 + reg   (m89-verified)
// Frag-linear LDS: slot = 1KB = 64 lanes x 16B; read = ds_read_b128 at lane*16.

constexpr int C_   = 96;
constexpr int Wimg = 192;
constexpr int HWp  = 192 * 192;
constexpr int NWIN = 24;
constexpr int Pp   = 7;

typedef __attribute__((ext_vector_type(8))) __bf16 bf16x8;
typedef __attribute__((ext_vector_type(8))) short  short8;
typedef __attribute__((ext_vector_type(4))) float  f32x4;
union frag_u { short8 s; bf16x8 b; };

// ---- LDS byte offsets (total 47,168 B -> 3 blocks/CU) ----
constexpr int XWLC  = 0;       // 12 slots: B-frags of logit GEMM  (xw as B[k=c][n=l])
constexpr int XWCL  = 12288;   // 12 slots: A-frags of xv GEMM     (xw as A[m=c][k=l])
constexpr int GKQF  = 24576;   // 6 slots: gkq A-frags, hi ks0..2, lo ks0..2
constexpr int ATTNF = 30720;   // 4 slots: attn B-frags, hi ks0..1, lo ks0..1
constexpr int LRAW  = 34816;   // [16][66] f32 raw logits; aliased by xp_f32 [7][96]
constexpr int XVF   = 39040;   // xv [7][96] f32
constexpr int QAT   = 41728;   // qat [64][9] f32
constexpr int AVT   = 44032;   // avT [96][8] f32
constexpr int BIAS  = 47104;   // biases16 [16] f32
constexpr int SMEMB = 47168;

// ---------------- precompute (weights only) ----------------

__global__ void precompute_mats(const float* __restrict__ Wq,
                                const float* __restrict__ Wk,
                                float* __restrict__ Mk,
                                float* __restrict__ Mq)
{
    const int c  = blockIdx.x;
    const int cp = threadIdx.x;
    float ak = 0.f, aq = 0.f;
    for (int a = 0; a < C_; ++a) {
        const float wq = Wq[a * C_ + c];
        ak = fmaf(wq, Wk[a * C_ + cp], ak);
        aq = fmaf(wq, Wq[a * C_ + cp], aq);
    }
    Mk[c * C_ + cp] = ak;
    Mq[c * C_ + cp] = aq;
}

__global__ void precompute_vecs(const float* __restrict__ Wq,
                                const float* __restrict__ Wk,
                                const float* __restrict__ bq,
                                const float* __restrict__ bk,
                                float* __restrict__ uk,  float* __restrict__ uq,
                                float* __restrict__ bk2, float* __restrict__ bq2,
                                float* __restrict__ scal)
{
    const int c = threadIdx.x;
    float a_uk = 0.f, a_uq = 0.f, a_bk2 = 0.f, a_bq2 = 0.f;
    for (int a = 0; a < C_; ++a) {
        const float wqc = Wq[a * C_ + c];
        a_uk  = fmaf(wqc, bk[a], a_uk);
        a_uq  = fmaf(wqc, bq[a], a_uq);
        a_bk2 = fmaf(bq[a], Wk[a * C_ + c], a_bk2);
        a_bq2 = fmaf(bq[a], Wq[a * C_ + c], a_bq2);
    }
    uk[c] = a_uk; uq[c] = a_uq; bk2[c] = a_bk2; bq2[c] = a_bq2;
    if (c == 0) {
        float sk = 0.f, sq = 0.f;
        for (int a = 0; a < C_; ++a) { sk += bq[a] * bk[a]; sq += bq[a] * bq[a]; }
        scal[0] = sk; scal[1] = sq;
    }
}

// ---------------- helpers ----------------

__device__ __forceinline__ unsigned short f2bf(float f) {
    unsigned u = __float_as_uint(f);
    return (unsigned short)((u + 0x7FFFu + ((u >> 16) & 1u)) >> 16);
}
__device__ __forceinline__ float bf2f(unsigned short h) {
    return __uint_as_float(((unsigned)h) << 16);
}
// frag-linear byte addresses for element (c, l)
__device__ __forceinline__ int xwCL_byte(int c, int l) {   // A[m=c][k=l]
    return XWCL + (((c >> 4) * 2 + (l >> 5)) << 10)
           + (((c & 15) + (((l >> 3) & 3) << 4)) << 4) + ((l & 7) << 1);
}
__device__ __forceinline__ int xwLC_byte(int c, int l) {   // B[k=c][n=l]
    return XWLC + (((c >> 5) * 4 + (l >> 4)) << 10)
           + (((l & 15) + (((c >> 3) & 3) << 4)) << 4) + ((c & 7) << 1);
}

// ---------------- main fused kernel ----------------

__global__ __launch_bounds__(256, 3) void camixer_main(
    const float* __restrict__ x,
    const float* __restrict__ Wv,
    const float* __restrict__ bv,
    const float* __restrict__ Mk,
    const float* __restrict__ Mq,
    const float* __restrict__ uk,
    const float* __restrict__ uq,
    const float* __restrict__ bk2,
    const float* __restrict__ bq2,
    const float* __restrict__ scal,
    float* __restrict__ out)
{
    __shared__ __align__(16) unsigned char S[SMEMB];
    float* xpf  = (float*)(S + LRAW);   // xp_f32 [7][96], dead before LRAW written
    float* Lraw = (float*)(S + LRAW);   // [16][66]
    float* xvf  = (float*)(S + XVF);    // [7][96]
    float* qat  = (float*)(S + QAT);    // [64][9]
    float* avT  = (float*)(S + AVT);    // [96][8]
    float* bias16 = (float*)(S + BIAS); // [16]

    const int t = threadIdx.x;
    const int lane = t & 63, w = t >> 6;
    // bijective XCD swizzle: 4608 = 8 * 576
    const int wid = ((blockIdx.x & 7) * 576) + (blockIdx.x >> 3);
    const int b  = wid / (NWIN * NWIN);
    const int r  = wid % (NWIN * NWIN);
    const int h0 = (r / NWIN) * 8;
    const int w0 = (r % NWIN) * 8;
    const int base = b * C_ * HWp + h0 * Wimg + w0;

    // ---- P0: x window -> bf16, dual frag-linear layouts ----
    {
        const float4* x4 = reinterpret_cast<const float4*>(x);
        #pragma unroll
        for (int rr = 0; rr < 2; ++rr) {
            const int idx = t + (rr << 8);          // 384 = 24 c4 x 8 dh x 2 dw4
            if (idx < 384) {
                const int dw4 = idx & 1;
                const int dh  = (idx >> 1) & 7;
                const int c4  = idx >> 4;
                const int c0 = c4 * 4, l0 = dh * 8 + dw4 * 4;
                unsigned short bf[4][4];            // [jc][il]
                #pragma unroll
                for (int j = 0; j < 4; ++j) {
                    const float4 v = x4[(base + (c0 + j) * HWp + dh * Wimg + dw4 * 4) >> 2];
                    bf[j][0] = f2bf(v.x); bf[j][1] = f2bf(v.y);
                    bf[j][2] = f2bf(v.z); bf[j][3] = f2bf(v.w);
                }
                // xwCL: per c, pack 4 consecutive l
                #pragma unroll
                for (int j = 0; j < 4; ++j) {
                    uint2 d;
                    d.x = (unsigned)bf[j][0] | ((unsigned)bf[j][1] << 16);
                    d.y = (unsigned)bf[j][2] | ((unsigned)bf[j][3] << 16);
                    *reinterpret_cast<uint2*>(S + xwCL_byte(c0 + j, l0)) = d;
                }
                // xwLC: per l, pack 4 consecutive c
                #pragma unroll
                for (int i = 0; i < 4; ++i) {
                    uint2 d;
                    d.x = (unsigned)bf[0][i] | ((unsigned)bf[1][i] << 16);
                    d.y = (unsigned)bf[2][i] | ((unsigned)bf[3][i] << 16);
                    *reinterpret_cast<uint2*>(S + xwLC_byte(c0, l0 + i)) = d;
                }
            }
        }
    }
    __syncthreads();

    // ---- P1: adaptive pool 64->7 -> xp_f32 (each segment = 10 tokens, 2 octs) ----
    for (int idx = t; idx < Pp * C_; idx += 256) {
        const int p = idx / C_, c = idx - p * C_;
        const int s = (p << 6) / 7;                 // {0,9,18,27,36,45,54}
        const int o0 = s >> 3, j0 = s & 7;
        float acc = 0.f;
        {
            const short8 d = *reinterpret_cast<const short8*>(S + xwCL_byte(c, o0 * 8));
            #pragma unroll
            for (int j = 0; j < 8; ++j)
                if (j >= j0) acc += bf2f((unsigned short)d[j]);
        }
        {
            const short8 d = *reinterpret_cast<const short8*>(S + xwCL_byte(c, o0 * 8 + 8));
            const int j1 = j0 + 2;
            #pragma unroll
            for (int j = 0; j < 8; ++j)
                if (j < j1) acc += bf2f((unsigned short)d[j]);
        }
        xpf[p * C_ + c] = acc * 0.1f;
    }
    __syncthreads();

    // ---- P2 (scalar, as v4): gk/gq -> gkq frags (bf16 hi/lo); bias dots ----
    if (t < 192) {
        const int which = (t >= C_) ? 1 : 0;
        const int cp = t - which * C_;
        const float* __restrict__ M = which ? Mq : Mk;
        float acc[Pp] = {};
        for (int c4 = 0; c4 < 24; ++c4) {
            float4 xq[Pp];
            #pragma unroll
            for (int p = 0; p < Pp; ++p)
                xq[p] = *reinterpret_cast<const float4*>(&xpf[p * C_ + 4 * c4]);
            const float m0 = M[(4*c4 + 0) * C_ + cp];
            const float m1 = M[(4*c4 + 1) * C_ + cp];
            const float m2 = M[(4*c4 + 2) * C_ + cp];
            const float m3 = M[(4*c4 + 3) * C_ + cp];
            #pragma unroll
            for (int p = 0; p < Pp; ++p) {
                acc[p] = fmaf(xq[p].x, m0, acc[p]);
                acc[p] = fmaf(xq[p].y, m1, acc[p]);
                acc[p] = fmaf(xq[p].z, m2, acc[p]);
                acc[p] = fmaf(xq[p].w, m3, acc[p]);
            }
        }
        const float b2 = (which ? bq2 : bk2)[cp];
        const int ks = cp >> 5, lj = ((cp >> 3) & 3), jj = cp & 7;
        #pragma unroll
        for (int p = 0; p < Pp; ++p) {
            const float g = acc[p] + b2;
            const unsigned short hi = f2bf(g);
            const unsigned short lo = f2bf(g - bf2f(hi));
            const int pp = p + 8 * which;
            const int off = ((pp + 16 * lj) << 4) + (jj << 1);
            *reinterpret_cast<unsigned short*>(S + GKQF + (ks << 10) + off) = hi;
            *reinterpret_cast<unsigned short*>(S + GKQF + ((3 + ks) << 10) + off) = lo;
        }
    } else if (t < 192 + 14) {
        const int j = t - 192;                      // 0..13
        const int p = j % 7, which = j / 7;
        const float* __restrict__ u = which ? uq : uk;
        float acc = 0.f;
        #pragma unroll 4
        for (int c4 = 0; c4 < 24; ++c4) {
            const float4 xq = *reinterpret_cast<const float4*>(&xpf[p * C_ + 4 * c4]);
            const float4 uu = *reinterpret_cast<const float4*>(&u[4 * c4]);
            acc = fmaf(xq.x, uu.x, acc); acc = fmaf(xq.y, uu.y, acc);
            acc = fmaf(xq.z, uu.z, acc); acc = fmaf(xq.w, uu.w, acc);
        }
        bias16[p + 8 * which] = acc + scal[which];
    } else if (t == 206) { bias16[7] = 0.f; }
    else if (t == 207) { bias16[15] = 0.f; }
    __syncthreads();

    // ---- G1 (MFMA): L^T[16 p'][64 l] = gkq(hi+lo) @ xwLC ; wave = ntile ----
    {
        frag_u A[6], B[3];
        #pragma unroll
        for (int ks = 0; ks < 3; ++ks) {
            A[ks].s     = *reinterpret_cast<const short8*>(S + GKQF + (ks << 10) + (lane << 4));
            A[3 + ks].s = *reinterpret_cast<const short8*>(S + GKQF + ((3 + ks) << 10) + (lane << 4));
            B[ks].s     = *reinterpret_cast<const short8*>(S + XWLC + ((ks * 4 + w) << 10) + (lane << 4));
        }
        f32x4 acc = {0.f, 0.f, 0.f, 0.f};
        #pragma unroll
        for (int ks = 0; ks < 3; ++ks) {
            acc = __builtin_amdgcn_mfma_f32_16x16x32_bf16(A[ks].b,     B[ks].b, acc, 0, 0, 0);
            acc = __builtin_amdgcn_mfma_f32_16x16x32_bf16(A[3 + ks].b, B[ks].b, acc, 0, 0, 0);
        }
        const f32x4 bb = *reinterpret_cast<const f32x4*>(S + BIAS + ((lane >> 4) << 4));
        const int colL = w * 16 + (lane & 15);
        #pragma unroll
        for (int rr = 0; rr < 4; ++rr)
            Lraw[((lane >> 4) * 4 + rr) * 66 + colL] = acc[rr] + bb[rr];
    }
    __syncthreads();

    // ---- SM: k-softmax (waves 0,1) -> attn frags (hi/lo); q-softmax (wave 2) ----
    if (w < 2) {
        const int r0 = w * 4, r1 = w ? 7 : 4;
        for (int pp = r0; pp < r1; ++pp) {
            const float v = Lraw[pp * 66 + lane];
            float mx = v;
            #pragma unroll
            for (int off = 32; off; off >>= 1) mx = fmaxf(mx, __shfl_xor(mx, off));
            const float e = __expf(v - mx);
            float s = e;
            #pragma unroll
            for (int off = 32; off; off >>= 1) s += __shfl_xor(s, off);
            const float a = e / s;
            const unsigned short hi = f2bf(a);
            const unsigned short lo = f2bf(a - bf2f(hi));
            const int ks = lane >> 5;
            const int off_b = ((pp + 16 * ((lane >> 3) & 3)) << 4) + ((lane & 7) << 1);
            *reinterpret_cast<unsigned short*>(S + ATTNF + (ks << 10) + off_b) = hi;
            *reinterpret_cast<unsigned short*>(S + ATTNF + ((2 + ks) << 10) + off_b) = lo;
        }
    } else if (w == 2) {
        float vv[Pp];
        float mx = -1e30f;
        #pragma unroll
        for (int p = 0; p < Pp; ++p) { vv[p] = Lraw[(8 + p) * 66 + lane]; mx = fmaxf(mx, vv[p]); }
        float s = 0.f;
        #pragma unroll
        for (int p = 0; p < Pp; ++p) { vv[p] = __expf(vv[p] - mx); s += vv[p]; }
        const float inv = 1.f / s;
        #pragma unroll
        for (int p = 0; p < Pp; ++p) qat[lane * 9 + p] = vv[p] * inv;
    }
    __syncthreads();

    // ---- G2 (MFMA): xv^T[96 c][16 p] = xwCL @ attn(hi+lo) ; mtiles over waves ----
    {
        frag_u Bh[2], Bl[2];
        #pragma unroll
        for (int ks = 0; ks < 2; ++ks) {
            Bh[ks].s = *reinterpret_cast<const short8*>(S + ATTNF + (ks << 10) + (lane << 4));
            Bl[ks].s = *reinterpret_cast<const short8*>(S + ATTNF + ((2 + ks) << 10) + (lane << 4));
        }
        const int mt0 = (w < 2) ? w * 2 : (w + 2);
        const int nmt = (w < 2) ? 2 : 1;
        for (int m = 0; m < nmt; ++m) {
            const int mt = mt0 + m;
            f32x4 acc = {0.f, 0.f, 0.f, 0.f};
            #pragma unroll
            for (int ks = 0; ks < 2; ++ks) {
                frag_u A;
                A.s = *reinterpret_cast<const short8*>(S + XWCL + ((mt * 2 + ks) << 10) + (lane << 4));
                acc = __builtin_amdgcn_mfma_f32_16x16x32_bf16(A.b, Bh[ks].b, acc, 0, 0, 0);
                acc = __builtin_amdgcn_mfma_f32_16x16x32_bf16(A.b, Bl[ks].b, acc, 0, 0, 0);
            }
            const int p = lane & 15;
            if (p < Pp) {
                const int c0 = mt * 16 + (lane >> 4) * 4;
                *reinterpret_cast<f32x4*>(&xvf[p * C_ + c0]) = acc;
            }
        }
    }
    __syncthreads();

    // ---- P5 (scalar, as v4): avT[o][p] = xv[p]·Wv[o] + bv[o] ----
    for (int idx = t; idx < Pp * C_; idx += 256) {
        const int p = idx / C_, o = idx - p * C_;
        float acc = 0.f;
        #pragma unroll 6
        for (int c4 = 0; c4 < 24; ++c4) {
            const float4 v4 = *reinterpret_cast<const float4*>(&xvf[p * C_ + 4 * c4]);
            const float4 w4 = *reinterpret_cast<const float4*>(&Wv[o * C_ + 4 * c4]);
            acc = fmaf(v4.x, w4.x, acc); acc = fmaf(v4.y, w4.y, acc);
            acc = fmaf(v4.z, w4.z, acc); acc = fmaf(v4.w, w4.w, acc);
        }
        avT[o * 8 + p] = acc + bv[o];
    }
    __syncthreads();

    // ---- P7 (scalar, as v4): out = q_attn @ agent_v ----
    {
        float qa[Pp];
        #pragma unroll
        for (int p = 0; p < Pp; ++p) qa[p] = qat[lane * 9 + p];
        const int dh = lane >> 3, dw = lane & 7;
        const int obase = b * C_ * HWp + (h0 + dh) * Wimg + (w0 + dw);
        #pragma unroll 4
        for (int j = 0; j < 24; ++j) {
            const int o = w + 4 * j;                 // wave-uniform
            const float4 a0 = *reinterpret_cast<const float4*>(&avT[o * 8]);
            const float4 a1 = *reinterpret_cast<const float4*>(&avT[o * 8 + 4]);
            float acc = qa[0] * a0.x;
            acc = fmaf(qa[1], a0.y, acc);
            acc = fmaf(qa[2], a0.z, acc);
            acc = fmaf(qa[3], a0.w, acc);
            acc = fmaf(qa[4], a1.x, acc);
            acc = fmaf(qa[5], a1.y, acc);
            acc = fmaf(qa[6], a1.z, acc);
            out[obase + o * HWp] = acc;
        }
    }
}

// ---------------- launch ----------------

extern "C" void kernel_launch(void* const* d_in, const int* in_sizes, int n_in,
                              void* d_out, int out_size, void* d_ws, size_t ws_size,
                              hipStream_t stream)
{
    const float* x  = (const float*)d_in[0];
    const float* Wv = (const float*)d_in[1];
    const float* bv = (const float*)d_in[2];
    const float* Wq = (const float*)d_in[3];
    const float* bq = (const float*)d_in[4];
    const float* Wk = (const float*)d_in[5];
    const float* bk = (const float*)d_in[6];
    float* out = (float*)d_out;

    float* ws   = (float*)d_ws;
    float* Mk   = ws;                 // 9216
    float* Mq   = ws + 9216;          // 9216
    float* uk   = ws + 18432;         // 96
    float* uq   = ws + 18528;         // 96
    float* bk2  = ws + 18624;         // 96
    float* bq2  = ws + 18720;         // 96
    float* scal = ws + 18816;         // 2

    hipLaunchKernelGGL(precompute_mats, dim3(C_), dim3(C_), 0, stream,
                       Wq, Wk, Mk, Mq);
    hipLaunchKernelGGL(precompute_vecs, dim3(1), dim3(C_), 0, stream,
                       Wq, Wk, bq, bk, uk, uq, bk2, bq2, scal);
    hipLaunchKernelGGL(camixer_main, dim3(8 * NWIN * NWIN), dim3(256), 0, stream,
                       x, Wv, bv, Mk, Mq, uk, uq, bk2, bq2, scal, out);
}

// Round 6
// 101.859 us; speedup vs baseline: 3.7416x; 2.0008x over previous
//
#include <hip/hip_runtime.h>

// CAMixer agent-attention, fused per-window (8x8).  v6: all GEMM-shaped phases
// on MFMA (pool, gkq, logits, xv, av); scalar only P0 (load) and P7 (store).
// Weight frag tables (Mext B-frags, Wv A-frags, hi/lo bf16) precomputed in ws.
// LDS lifetime unions -> 39.7KB -> 4 blocks/CU.
//
// Algebra (exact refactor, verified round 1):
//   agent   = conv(pool(x), Wq)
//   k-logit[p][l] = xw[l]·gk[p] + bkd[p],  gk = xp @ Mk + bk2,  Mk = Wq^T Wk
//   q-logit[l][p] = xw[l]·gq[p] + bqd[p],  gq = xp @ Mq + bq2,  Mq = Wq^T Wq
//   agent_v = (a_attn @ xw) @ Wv^T + bv
//
// MFMA conventions (verified by v5's unchanged absmax):
//   A-frag: lane = row + 16*kblk holds A[row][ks*32 + kblk*8 + j], j=0..7
//   B-frag: lane = col + 16*kblk holds B[ks*32 + kblk*8 + j][col]
//   C-frag: col = lane&15, row = (lane>>4)*4 + reg
//   A-frags of M == B-frags of M^T (same register image).

constexpr int C_   = 96;
constexpr int Wimg = 192;
constexpr int HWp  = 192 * 192;
constexpr int NWIN = 24;
constexpr int Pp   = 7;

typedef __attribute__((ext_vector_type(8))) __bf16 bf16x8;
typedef __attribute__((ext_vector_type(8))) short  short8;
typedef __attribute__((ext_vector_type(4))) float  f32x4;
union frag_u { short8 s; bf16x8 b; };

// ---- LDS byte offsets (total 39,680 B -> 4 blocks/CU) ----
constexpr int XWLC  = 0;       // 12 slots: xw B-frags (k=c, n=l)
constexpr int XWCL  = 12288;   // 12 slots: xw A-frags (m=c, k=l) == B-frags of xw^T (k=l)
constexpr int R1    = 24576;   // 6400B union: XP[16][100]f32 -> LRAW[16][66] -> XVF[16][100]
constexpr int R2    = 30976;   // 6400B union: GKQ[16][100]f32 -> ATTNF(4 slots) -> AVT[96][8]
constexpr int QATB  = 37376;   // [64][9] f32
constexpr int SMEMB = 39680;

// ---- ws float offsets ----
// Mk 0, Mq 9216, uk 18432, uq 18528, bk2 18624, bq2 18720, scal 18816
constexpr int WS_FRAG_BYTE = 18944 * 4;           // Mext frags: 84 slots x 1KB
constexpr int WS_WV_BYTE   = WS_FRAG_BYTE + 84 * 1024;  // Wv frags: 36 slots x 1KB

// ---------------- helpers ----------------

__device__ __forceinline__ unsigned short f2bf(float f) {
    unsigned u = __float_as_uint(f);
    return (unsigned short)((u + 0x7FFFu + ((u >> 16) & 1u)) >> 16);
}
__device__ __forceinline__ float bf2f(unsigned short h) {
    return __uint_as_float(((unsigned)h) << 16);
}
__device__ __forceinline__ void hilo8(const float4 a, const float4 b,
                                      frag_u& H, frag_u& L) {
    const float v[8] = {a.x, a.y, a.z, a.w, b.x, b.y, b.z, b.w};
    #pragma unroll
    for (int j = 0; j < 8; ++j) {
        const unsigned short h = f2bf(v[j]);
        H.s[j] = (short)h;
        L.s[j] = (short)f2bf(v[j] - bf2f(h));
    }
}
__device__ __forceinline__ int xwCL_byte(int c, int l) {   // A[m=c][k=l]
    return XWCL + (((c >> 4) * 2 + (l >> 5)) << 10)
           + (((c & 15) + (((l >> 3) & 3) << 4)) << 4) + ((l & 7) << 1);
}
__device__ __forceinline__ int xwLC_byte(int c, int l) {   // B[k=c][n=l]
    return XWLC + (((c >> 5) * 4 + (l >> 4)) << 10)
           + (((l & 15) + (((c >> 3) & 3) << 4)) << 4) + ((c & 7) << 1);
}

// ---------------- precompute (weights only, trivial cost) ----------------

__global__ void precompute_mats(const float* __restrict__ Wq,
                                const float* __restrict__ Wk,
                                float* __restrict__ Mk,
                                float* __restrict__ Mq)
{
    const int c  = blockIdx.x;
    const int cp = threadIdx.x;
    float ak = 0.f, aq = 0.f;
    for (int a = 0; a < C_; ++a) {
        const float wq = Wq[a * C_ + c];
        ak = fmaf(wq, Wk[a * C_ + cp], ak);
        aq = fmaf(wq, Wq[a * C_ + cp], aq);
    }
    Mk[c * C_ + cp] = ak;
    Mq[c * C_ + cp] = aq;
}

__global__ void precompute_vecs(const float* __restrict__ Wq,
                                const float* __restrict__ Wk,
                                const float* __restrict__ bq,
                                const float* __restrict__ bk,
                                float* __restrict__ uk,  float* __restrict__ uq,
                                float* __restrict__ bk2, float* __restrict__ bq2,
                                float* __restrict__ scal)
{
    const int c = threadIdx.x;
    float a_uk = 0.f, a_uq = 0.f, a_bk2 = 0.f, a_bq2 = 0.f;
    for (int a = 0; a < C_; ++a) {
        const float wqc = Wq[a * C_ + c];
        a_uk  = fmaf(wqc, bk[a], a_uk);
        a_uq  = fmaf(wqc, bq[a], a_uq);
        a_bk2 = fmaf(bq[a], Wk[a * C_ + c], a_bk2);
        a_bq2 = fmaf(bq[a], Wq[a * C_ + c], a_bq2);
    }
    uk[c] = a_uk; uq[c] = a_uq; bk2[c] = a_bk2; bq2[c] = a_bq2;
    if (c == 0) {
        float sk = 0.f, sq = 0.f;
        for (int a = 0; a < C_; ++a) { sk += bq[a] * bk[a]; sq += bq[a] * bq[a]; }
        scal[0] = sk; scal[1] = sq;
    }
}

// frag tables: bid<84: Mext B-frags slot=((mat*7+nt)*3+ks)*2+hl; else Wv A-frags.
__global__ void precompute_frags(const float* __restrict__ ws,
                                 const float* __restrict__ Wv,
                                 unsigned char* __restrict__ wsb)
{
    const int bid = blockIdx.x, lane = threadIdx.x;
    short8 o;
    if (bid < 84) {
        const int hl = bid & 1, ks = (bid >> 1) % 3, nt = (bid / 6) % 7, mat = bid / 42;
        const float* M = ws + (mat ? 9216 : 0);
        const float* u = ws + (mat ? 18528 : 18432);
        const int col = nt * 16 + (lane & 15);
        #pragma unroll
        for (int j = 0; j < 8; ++j) {
            const int k = ks * 32 + (lane >> 4) * 8 + j;
            const float raw = (col < 96) ? M[k * 96 + col] : ((col == 96) ? u[k] : 0.f);
            const unsigned short hi = f2bf(raw);
            o[j] = (short)(hl ? f2bf(raw - bf2f(hi)) : hi);
        }
        *reinterpret_cast<short8*>(wsb + WS_FRAG_BYTE + bid * 1024 + lane * 16) = o;
    } else {
        const int wb = bid - 84;
        const int hl = wb & 1, ks = (wb >> 1) % 3, mt = wb / 6;
        const int row = mt * 16 + (lane & 15);
        #pragma unroll
        for (int j = 0; j < 8; ++j) {
            const int c = ks * 32 + (lane >> 4) * 8 + j;
            const float raw = Wv[row * 96 + c];
            const unsigned short hi = f2bf(raw);
            o[j] = (short)(hl ? f2bf(raw - bf2f(hi)) : hi);
        }
        *reinterpret_cast<short8*>(wsb + WS_WV_BYTE + wb * 1024 + lane * 16) = o;
    }
}

// ---------------- main fused kernel ----------------

__global__ __launch_bounds__(256, 4) void camixer_main(
    const float* __restrict__ x,
    const float* __restrict__ bv,
    const float* __restrict__ bk2,
    const float* __restrict__ bq2,
    const float* __restrict__ scal,
    const unsigned char* __restrict__ mfrag,   // ws + WS_FRAG_BYTE
    const unsigned char* __restrict__ wvfrag,  // ws + WS_WV_BYTE
    float* __restrict__ out)
{
    __shared__ __align__(16) unsigned char S[SMEMB];
    float* xpf  = (float*)(S + R1);    // [16][100]
    float* Lraw = (float*)(S + R1);    // [16][66]
    float* xvf  = (float*)(S + R1);    // [16][100]
    float* gkq  = (float*)(S + R2);    // [16][100]; col 96 = bias dot
    float* avT  = (float*)(S + R2);    // [96][8]
    float* qat  = (float*)(S + QATB);  // [64][9]

    const int t = threadIdx.x;
    const int lane = t & 63, w = t >> 6;
    const int wid = ((blockIdx.x & 7) * 576) + (blockIdx.x >> 3);  // bijective XCD swizzle
    const int b  = wid / (NWIN * NWIN);
    const int r  = wid % (NWIN * NWIN);
    const int h0 = (r / NWIN) * 8;
    const int w0 = (r % NWIN) * 8;
    const int base = b * C_ * HWp + h0 * Wimg + w0;
    const float scal0 = scal[0], scal1 = scal[1];

    // ---- P0: x window -> bf16, dual frag-linear layouts (v5 verbatim) ----
    {
        const float4* x4 = reinterpret_cast<const float4*>(x);
        #pragma unroll
        for (int rr = 0; rr < 2; ++rr) {
            const int idx = t + (rr << 8);          // 384 = 24 c4 x 8 dh x 2 dw4
            if (idx < 384) {
                const int dw4 = idx & 1;
                const int dh  = (idx >> 1) & 7;
                const int c4  = idx >> 4;
                const int c0 = c4 * 4, l0 = dh * 8 + dw4 * 4;
                unsigned short bf[4][4];
                #pragma unroll
                for (int j = 0; j < 4; ++j) {
                    const float4 v = x4[(base + (c0 + j) * HWp + dh * Wimg + dw4 * 4) >> 2];
                    bf[j][0] = f2bf(v.x); bf[j][1] = f2bf(v.y);
                    bf[j][2] = f2bf(v.z); bf[j][3] = f2bf(v.w);
                }
                #pragma unroll
                for (int j = 0; j < 4; ++j) {
                    uint2 d;
                    d.x = (unsigned)bf[j][0] | ((unsigned)bf[j][1] << 16);
                    d.y = (unsigned)bf[j][2] | ((unsigned)bf[j][3] << 16);
                    *reinterpret_cast<uint2*>(S + xwCL_byte(c0 + j, l0)) = d;
                }
                #pragma unroll
                for (int i = 0; i < 4; ++i) {
                    uint2 d;
                    d.x = (unsigned)bf[0][i] | ((unsigned)bf[1][i] << 16);
                    d.y = (unsigned)bf[2][i] | ((unsigned)bf[3][i] << 16);
                    *reinterpret_cast<uint2*>(S + xwLC_byte(c0, l0 + i)) = d;
                }
            }
        }
    }
    __syncthreads();

    // ---- G_P (MFMA): xp[16p][96c] = P^T(hi/lo) @ xw^T ; zeros rows 7-15 ----
    {
        frag_u PAh[2], PAl[2];
        {
            const int p = lane & 15, kb = lane >> 4;
            const unsigned short PH = f2bf(0.1f);
            const float phf = bf2f(PH);
            const unsigned short PL = f2bf(0.1f - phf);
            const int sp = (p < 7) ? ((p << 6) / 7) : 1000;
            #pragma unroll
            for (int ks = 0; ks < 2; ++ks)
                #pragma unroll
                for (int j = 0; j < 8; ++j) {
                    const int l = ks * 32 + kb * 8 + j;
                    const bool in = (l >= sp) && (l < sp + 10);
                    PAh[ks].s[j] = in ? (short)PH : (short)0;
                    PAl[ks].s[j] = in ? (short)PL : (short)0;
                }
        }
        #pragma unroll
        for (int rnd = 0; rnd < 2; ++rnd) {
            const int nt = rnd ? (4 + w) : w;
            if (rnd == 0 || w < 2) {
                f32x4 acc = {0.f, 0.f, 0.f, 0.f};
                #pragma unroll
                for (int ks = 0; ks < 2; ++ks) {
                    frag_u B;
                    B.s = *reinterpret_cast<const short8*>(S + XWCL + ((nt * 2 + ks) << 10) + (lane << 4));
                    acc = __builtin_amdgcn_mfma_f32_16x16x32_bf16(PAh[ks].b, B.b, acc, 0, 0, 0);
                    acc = __builtin_amdgcn_mfma_f32_16x16x32_bf16(PAl[ks].b, B.b, acc, 0, 0, 0);
                }
                const int cc = nt * 16 + (lane & 15);
                #pragma unroll
                for (int rr = 0; rr < 4; ++rr)
                    xpf[((lane >> 4) * 4 + rr) * 100 + cc] = acc[rr];
            }
        }
    }
    __syncthreads();

    // ---- G0 (MFMA): gkq[16][96] = xp(hi/lo) @ Mext(hi/lo) + b2; nt6 = bias dots ----
    {
        frag_u Ah[3], Al[3];
        #pragma unroll
        for (int ks = 0; ks < 3; ++ks) {
            const int off = (lane & 15) * 100 + ks * 32 + (lane >> 4) * 8;
            hilo8(*reinterpret_cast<const float4*>(&xpf[off]),
                  *reinterpret_cast<const float4*>(&xpf[off + 4]), Ah[ks], Al[ks]);
        }
        const int tt0 = w * 4, tt1 = (tt0 + 4 < 14) ? tt0 + 4 : 14;
        for (int tt = tt0; tt < tt1; ++tt) {
            const int mat = tt / 7, nt = tt % 7;
            f32x4 acc = {0.f, 0.f, 0.f, 0.f};
            #pragma unroll
            for (int ks = 0; ks < 3; ++ks) {
                const int slot = ((mat * 7 + nt) * 3 + ks) * 2;
                frag_u Bh, Bl;
                Bh.s = *reinterpret_cast<const short8*>(mfrag + slot * 1024 + (lane << 4));
                Bl.s = *reinterpret_cast<const short8*>(mfrag + (slot + 1) * 1024 + (lane << 4));
                acc = __builtin_amdgcn_mfma_f32_16x16x32_bf16(Ah[ks].b, Bh.b, acc, 0, 0, 0);
                acc = __builtin_amdgcn_mfma_f32_16x16x32_bf16(Ah[ks].b, Bl.b, acc, 0, 0, 0);
                acc = __builtin_amdgcn_mfma_f32_16x16x32_bf16(Al[ks].b, Bh.b, acc, 0, 0, 0);
            }
            const int row0 = (lane >> 4) * 4;
            if (nt < 6) {
                const int cc = nt * 16 + (lane & 15);
                const float b2v = (mat ? bq2 : bk2)[cc];
                #pragma unroll
                for (int rr = 0; rr < 4; ++rr) {
                    const int rw = row0 + rr;
                    if (rw < 8) gkq[(rw + 8 * mat) * 100 + cc] = acc[rr] + b2v;
                }
            } else if ((lane & 15) == 0) {
                #pragma unroll
                for (int rr = 0; rr < 4; ++rr) {
                    const int rw = row0 + rr;
                    if (rw < 8) gkq[(rw + 8 * mat) * 100 + 96] = acc[rr];
                }
            }
        }
    }
    __syncthreads();

    // ---- G1 (MFMA): L^T[16][64] = gkq(hi/lo) @ xwLC + bias ; wave = ntile ----
    {
        frag_u Ah[3], Al[3], B[3];
        #pragma unroll
        for (int ks = 0; ks < 3; ++ks) {
            const int off = (lane & 15) * 100 + ks * 32 + (lane >> 4) * 8;
            hilo8(*reinterpret_cast<const float4*>(&gkq[off]),
                  *reinterpret_cast<const float4*>(&gkq[off + 4]), Ah[ks], Al[ks]);
            B[ks].s = *reinterpret_cast<const short8*>(S + XWLC + ((ks * 4 + w) << 10) + (lane << 4));
        }
        f32x4 acc = {0.f, 0.f, 0.f, 0.f};
        #pragma unroll
        for (int ks = 0; ks < 3; ++ks) {
            acc = __builtin_amdgcn_mfma_f32_16x16x32_bf16(Ah[ks].b, B[ks].b, acc, 0, 0, 0);
            acc = __builtin_amdgcn_mfma_f32_16x16x32_bf16(Al[ks].b, B[ks].b, acc, 0, 0, 0);
        }
        const int colL = w * 16 + (lane & 15);
        #pragma unroll
        for (int rr = 0; rr < 4; ++rr) {
            const int pr = (lane >> 4) * 4 + rr;
            const float bias = gkq[pr * 100 + 96] + (pr < 8 ? scal0 : scal1);
            Lraw[pr * 66 + colL] = acc[rr] + bias;
        }
    }
    __syncthreads();

    // ---- SM: k-softmax (waves 0,1) -> attn frags hi/lo; q-softmax (wave 2) ----
    if (w < 2) {
        const int r0 = w * 4, r1 = w ? 7 : 4;
        for (int pp = r0; pp < r1; ++pp) {
            const float v = Lraw[pp * 66 + lane];
            float mx = v;
            #pragma unroll
            for (int off = 32; off; off >>= 1) mx = fmaxf(mx, __shfl_xor(mx, off));
            const float e = __expf(v - mx);
            float s = e;
            #pragma unroll
            for (int off = 32; off; off >>= 1) s += __shfl_xor(s, off);
            const float a = e / s;
            const unsigned short hi = f2bf(a);
            const unsigned short lo = f2bf(a - bf2f(hi));
            const int ks = lane >> 5;
            const int off_b = ((pp + 16 * ((lane >> 3) & 3)) << 4) + ((lane & 7) << 1);
            *reinterpret_cast<unsigned short*>(S + R2 + (ks << 10) + off_b) = hi;
            *reinterpret_cast<unsigned short*>(S + R2 + ((2 + ks) << 10) + off_b) = lo;
        }
    } else if (w == 2) {
        float vv[Pp];
        float mx = -1e30f;
        #pragma unroll
        for (int p = 0; p < Pp; ++p) { vv[p] = Lraw[(8 + p) * 66 + lane]; mx = fmaxf(mx, vv[p]); }
        float s = 0.f;
        #pragma unroll
        for (int p = 0; p < Pp; ++p) { vv[p] = __expf(vv[p] - mx); s += vv[p]; }
        const float inv = 1.f / s;
        #pragma unroll
        for (int p = 0; p < Pp; ++p) qat[lane * 9 + p] = vv[p] * inv;
    }
    __syncthreads();

    // ---- G2 (MFMA): xv^T[96c][16p] = xwCL @ attn(hi/lo) ----
    {
        frag_u Bh[2], Bl[2];
        #pragma unroll
        for (int ks = 0; ks < 2; ++ks) {
            Bh[ks].s = *reinterpret_cast<const short8*>(S + R2 + (ks << 10) + (lane << 4));
            Bl[ks].s = *reinterpret_cast<const short8*>(S + R2 + ((2 + ks) << 10) + (lane << 4));
        }
        const int mt0 = (w < 2) ? w * 2 : (w + 2);
        const int nmt = (w < 2) ? 2 : 1;
        for (int m = 0; m < nmt; ++m) {
            const int mt = mt0 + m;
            f32x4 acc = {0.f, 0.f, 0.f, 0.f};
            #pragma unroll
            for (int ks = 0; ks < 2; ++ks) {
                frag_u A;
                A.s = *reinterpret_cast<const short8*>(S + XWCL + ((mt * 2 + ks) << 10) + (lane << 4));
                acc = __builtin_amdgcn_mfma_f32_16x16x32_bf16(A.b, Bh[ks].b, acc, 0, 0, 0);
                acc = __builtin_amdgcn_mfma_f32_16x16x32_bf16(A.b, Bl[ks].b, acc, 0, 0, 0);
            }
            const int p = lane & 15;
            const int c0 = mt * 16 + (lane >> 4) * 4;
            *reinterpret_cast<f32x4*>(&xvf[p * 100 + c0]) = acc;
        }
    }
    __syncthreads();

    // ---- G3 (MFMA): av^T[96o][16p] = Wv(hi/lo) @ xv(hi/lo) + bv ----
    {
        frag_u Bh[3], Bl[3];
        #pragma unroll
        for (int ks = 0; ks < 3; ++ks) {
            const int off = (lane & 15) * 100 + ks * 32 + (lane >> 4) * 8;
            hilo8(*reinterpret_cast<const float4*>(&xvf[off]),
                  *reinterpret_cast<const float4*>(&xvf[off + 4]), Bh[ks], Bl[ks]);
        }
        #pragma unroll
        for (int rnd = 0; rnd < 2; ++rnd) {
            const int mt = rnd ? (4 + w) : w;
            if (rnd == 0 || w < 2) {
                f32x4 acc = {0.f, 0.f, 0.f, 0.f};
                #pragma unroll
                for (int ks = 0; ks < 3; ++ks) {
                    const int slot = (mt * 3 + ks) * 2;
                    frag_u Ah, Al;
                    Ah.s = *reinterpret_cast<const short8*>(wvfrag + slot * 1024 + (lane << 4));
                    Al.s = *reinterpret_cast<const short8*>(wvfrag + (slot + 1) * 1024 + (lane << 4));
                    acc = __builtin_amdgcn_mfma_f32_16x16x32_bf16(Ah.b, Bh[ks].b, acc, 0, 0, 0);
                    acc = __builtin_amdgcn_mfma_f32_16x16x32_bf16(Ah.b, Bl[ks].b, acc, 0, 0, 0);
                    acc = __builtin_amdgcn_mfma_f32_16x16x32_bf16(Al.b, Bh[ks].b, acc, 0, 0, 0);
                }
                if ((lane & 15) < 8) {
                    #pragma unroll
                    for (int rr = 0; rr < 4; ++rr) {
                        const int o = mt * 16 + (lane >> 4) * 4 + rr;
                        avT[o * 8 + (lane & 15)] = acc[rr] + bv[o];
                    }
                }
            }
        }
    }
    __syncthreads();

    // ---- P7 (scalar): out = q_attn @ agent_v ----
    {
        float qa[Pp];
        #pragma unroll
        for (int p = 0; p < Pp; ++p) qa[p] = qat[lane * 9 + p];
        const int dh = lane >> 3, dw = lane & 7;
        const int obase = b * C_ * HWp + (h0 + dh) * Wimg + (w0 + dw);
        #pragma unroll 4
        for (int j = 0; j < 24; ++j) {
            const int o = w + 4 * j;                 // wave-uniform
            const float4 a0 = *reinterpret_cast<const float4*>(&avT[o * 8]);
            const float4 a1 = *reinterpret_cast<const float4*>(&avT[o * 8 + 4]);
            float acc = qa[0] * a0.x;
            acc = fmaf(qa[1], a0.y, acc);
            acc = fmaf(qa[2], a0.z, acc);
            acc = fmaf(qa[3], a0.w, acc);
            acc = fmaf(qa[4], a1.x, acc);
            acc = fmaf(qa[5], a1.y, acc);
            acc = fmaf(qa[6], a1.z, acc);
            out[obase + o * HWp] = acc;
        }
    }
}

// ---------------- launch ----------------

extern "C" void kernel_launch(void* const* d_in, const int* in_sizes, int n_in,
                              void* d_out, int out_size, void* d_ws, size_t ws_size,
                              hipStream_t stream)
{
    const float* x  = (const float*)d_in[0];
    const float* Wv = (const float*)d_in[1];
    const float* bv = (const float*)d_in[2];
    const float* Wq = (const float*)d_in[3];
    const float* bq = (const float*)d_in[4];
    const float* Wk = (const float*)d_in[5];
    const float* bk = (const float*)d_in[6];
    float* out = (float*)d_out;

    float* ws = (float*)d_ws;
    float* Mk   = ws;                 // 9216
    float* Mq   = ws + 9216;          // 9216
    float* uk   = ws + 18432;
    float* uq   = ws + 18528;
    float* bk2  = ws + 18624;
    float* bq2  = ws + 18720;
    float* scal = ws + 18816;
    unsigned char* wsb = (unsigned char*)d_ws;

    hipLaunchKernelGGL(precompute_mats, dim3(C_), dim3(C_), 0, stream,
                       Wq, Wk, Mk, Mq);
    hipLaunchKernelGGL(precompute_vecs, dim3(1), dim3(C_), 0, stream,
                       Wq, Wk, bq, bk, uk, uq, bk2, bq2, scal);
    hipLaunchKernelGGL(precompute_frags, dim3(120), dim3(64), 0, stream,
                       ws, Wv, wsb);
    hipLaunchKernelGGL(camixer_main, dim3(8 * NWIN * NWIN), dim3(256), 0, stream,
                       x, bv, bk2, bq2, scal,
                       wsb + WS_FRAG_BYTE, wsb + WS_WV_BYTE, out);
}

// Round 7
// 89.057 us; speedup vs baseline: 4.2795x; 1.1437x over previous
//
#include <hip/hip_runtime.h>

// CAMixer agent-attention, fused per-window (8x8).  v7 = v6 + conflict fixes + native casts:
//  - xw stored ONCE as XOR-swizzled row-major bf16 (T2): A-frags (G_P/G2) read direct
//    via swizzled ds_read_b128; XWCL region deleted. P0 writes conflict-free.
//  - XWLC frag slots padded 1024->1040B (4-bank rotation/slot) -> P0 transposed writes
//    hit the 4-cycle minimum (was ~8-way aliased).
//  - f2bf/hilo8 -> native __bf16 casts (RNE, bit-identical; ~4x fewer VALU per convert).
//  - softmax phase spread over all 4 waves.
//
// Algebra (exact refactor, verified round 1):
//   agent   = conv(pool(x), Wq)
//   k-logit[p][l] = xw[l]·gk[p] + bkd[p],  gk = xp @ Mk + bk2,  Mk = Wq^T Wk
//   q-logit[l][p] = xw[l]·gq[p] + bqd[p],  gq = xp @ Mq + bq2,  Mq = Wq^T Wq
//   agent_v = (a_attn @ xw) @ Wv^T + bv
//
// MFMA conventions (verified v5/v6):
//   A-frag: lane = row + 16*kblk holds A[row][ks*32 + kblk*8 + j], j=0..7
//   B-frag: lane = col + 16*kblk holds B[ks*32 + kblk*8 + j][col]
//   C-frag: col = lane&15, row = (lane>>4)*4 + reg
//   A-frags of M == B-frags of M^T (same register image).

constexpr int C_   = 96;
constexpr int Wimg = 192;
constexpr int HWp  = 192 * 192;
constexpr int NWIN = 24;
constexpr int Pp   = 7;

typedef __attribute__((ext_vector_type(8))) __bf16 bf16x8;
typedef __attribute__((ext_vector_type(4))) __bf16 bf16x4;
typedef __attribute__((ext_vector_type(8))) short  short8;
typedef __attribute__((ext_vector_type(4))) float  f32x4;
union frag_u { short8 s; bf16x8 b; };

// ---- LDS byte offsets (total 39,872 B -> 4 blocks/CU) ----
constexpr int XWS   = 0;       // xw simple: bf16 [96][64], row 128B, XOR-swizzled
constexpr int XWLC  = 12288;   // 12 slots x 1040B: xw B-frag image (k=c, n=l)
constexpr int R1    = 24768;   // 6400B union: XP[16][100] -> LRAW[16][66] -> XVF[16][100]
constexpr int R2    = 31168;   // 6400B union: GKQ[16][100] -> ATTN(4x1KB) -> AVT[96][8]
constexpr int QATB  = 37568;   // [64][9] f32 (stride 9 -> conflict-free column reads)
constexpr int SMEMB = 39872;

// ---- ws float offsets ----
constexpr int WS_FRAG_BYTE = 18944 * 4;                 // Mext frags: 84 slots x 1KB
constexpr int WS_WV_BYTE   = WS_FRAG_BYTE + 84 * 1024;  // Wv frags: 36 slots x 1KB

// ---------------- helpers ----------------

__device__ __forceinline__ void hilo8(const float4 a, const float4 b,
                                      frag_u& H, frag_u& L) {
    float v[8] = {a.x, a.y, a.z, a.w, b.x, b.y, b.z, b.w};
    #pragma unroll
    for (int j = 0; j < 8; ++j) {
        const __bf16 h = (__bf16)v[j];
        H.b[j] = h;
        L.b[j] = (__bf16)(v[j] - (float)h);
    }
}

// A-frag (m=c, k=l) of xw, tile (mt, ks), read direct from swizzled simple layout.
// Also serves as B-frag (k=l, n=c) of xw^T (same register image).
__device__ __forceinline__ short8 xws_fragA(const unsigned char* S, int mt, int ks, int lane) {
    const int c  = mt * 16 + (lane & 15);
    const int l2 = ks * 64 + ((lane >> 4) << 4);        // l*2 (byte col)
    return *reinterpret_cast<const short8*>(S + XWS + c * 128 + (l2 ^ ((c & 7) << 4)));
}

// ---------------- precompute (weights only, trivial cost) ----------------

__global__ void precompute_mats(const float* __restrict__ Wq,
                                const float* __restrict__ Wk,
                                float* __restrict__ Mk,
                                float* __restrict__ Mq)
{
    const int c  = blockIdx.x;
    const int cp = threadIdx.x;
    float ak = 0.f, aq = 0.f;
    for (int a = 0; a < C_; ++a) {
        const float wq = Wq[a * C_ + c];
        ak = fmaf(wq, Wk[a * C_ + cp], ak);
        aq = fmaf(wq, Wq[a * C_ + cp], aq);
    }
    Mk[c * C_ + cp] = ak;
    Mq[c * C_ + cp] = aq;
}

__global__ void precompute_vecs(const float* __restrict__ Wq,
                                const float* __restrict__ Wk,
                                const float* __restrict__ bq,
                                const float* __restrict__ bk,
                                float* __restrict__ uk,  float* __restrict__ uq,
                                float* __restrict__ bk2, float* __restrict__ bq2,
                                float* __restrict__ scal)
{
    const int c = threadIdx.x;
    float a_uk = 0.f, a_uq = 0.f, a_bk2 = 0.f, a_bq2 = 0.f;
    for (int a = 0; a < C_; ++a) {
        const float wqc = Wq[a * C_ + c];
        a_uk  = fmaf(wqc, bk[a], a_uk);
        a_uq  = fmaf(wqc, bq[a], a_uq);
        a_bk2 = fmaf(bq[a], Wk[a * C_ + c], a_bk2);
        a_bq2 = fmaf(bq[a], Wq[a * C_ + c], a_bq2);
    }
    uk[c] = a_uk; uq[c] = a_uq; bk2[c] = a_bk2; bq2[c] = a_bq2;
    if (c == 0) {
        float sk = 0.f, sq = 0.f;
        for (int a = 0; a < C_; ++a) { sk += bq[a] * bk[a]; sq += bq[a] * bq[a]; }
        scal[0] = sk; scal[1] = sq;
    }
}

// frag tables: bid<84: Mext B-frags slot=((mat*7+nt)*3+ks)*2+hl; else Wv A-frags.
__global__ void precompute_frags(const float* __restrict__ ws,
                                 const float* __restrict__ Wv,
                                 unsigned char* __restrict__ wsb)
{
    const int bid = blockIdx.x, lane = threadIdx.x;
    short8 o;
    if (bid < 84) {
        const int hl = bid & 1, ks = (bid >> 1) % 3, nt = (bid / 6) % 7, mat = bid / 42;
        const float* M = ws + (mat ? 9216 : 0);
        const float* u = ws + (mat ? 18528 : 18432);
        const int col = nt * 16 + (lane & 15);
        #pragma unroll
        for (int j = 0; j < 8; ++j) {
            const int k = ks * 32 + (lane >> 4) * 8 + j;
            const float raw = (col < 96) ? M[k * 96 + col] : ((col == 96) ? u[k] : 0.f);
            const __bf16 hi = (__bf16)raw;
            union { __bf16 h; short s; } cv;
            cv.h = hl ? (__bf16)(raw - (float)hi) : hi;
            o[j] = cv.s;
        }
        *reinterpret_cast<short8*>(wsb + WS_FRAG_BYTE + bid * 1024 + lane * 16) = o;
    } else {
        const int wb = bid - 84;
        const int hl = wb & 1, ks = (wb >> 1) % 3, mt = wb / 6;
        const int row = mt * 16 + (lane & 15);
        #pragma unroll
        for (int j = 0; j < 8; ++j) {
            const int c = ks * 32 + (lane >> 4) * 8 + j;
            const float raw = Wv[row * 96 + c];
            const __bf16 hi = (__bf16)raw;
            union { __bf16 h; short s; } cv;
            cv.h = hl ? (__bf16)(raw - (float)hi) : hi;
            o[j] = cv.s;
        }
        *reinterpret_cast<short8*>(wsb + WS_WV_BYTE + wb * 1024 + lane * 16) = o;
    }
}

// ---------------- main fused kernel ----------------

__global__ __launch_bounds__(256, 4) void camixer_main(
    const float* __restrict__ x,
    const float* __restrict__ bv,
    const float* __restrict__ bk2,
    const float* __restrict__ bq2,
    const float* __restrict__ scal,
    const unsigned char* __restrict__ mfrag,
    const unsigned char* __restrict__ wvfrag,
    float* __restrict__ out)
{
    __shared__ __align__(16) unsigned char S[SMEMB];
    float* xpf  = (float*)(S + R1);    // [16][100]
    float* Lraw = (float*)(S + R1);    // [16][66]
    float* xvf  = (float*)(S + R1);    // [16][100]
    float* gkq  = (float*)(S + R2);    // [16][100]; col 96 = bias dot
    float* avT  = (float*)(S + R2);    // [96][8]
    float* qat  = (float*)(S + QATB);  // [64][9]

    const int t = threadIdx.x;
    const int lane = t & 63, w = t >> 6;
    const int wid = ((blockIdx.x & 7) * 576) + (blockIdx.x >> 3);  // bijective XCD swizzle
    const int b  = wid / (NWIN * NWIN);
    const int r  = wid % (NWIN * NWIN);
    const int h0 = (r / NWIN) * 8;
    const int w0 = (r % NWIN) * 8;
    const int base = b * C_ * HWp + h0 * Wimg + w0;
    const float scal0 = scal[0], scal1 = scal[1];

    // ---- P0: x window -> bf16: (a) XOR-swizzled simple layout, (b) XWLC frag image ----
    {
        const float4* x4 = reinterpret_cast<const float4*>(x);
        #pragma unroll
        for (int rr = 0; rr < 2; ++rr) {
            const int idx = t + (rr << 8);          // 384 = 24 c4 x 8 dh x 2 dw4
            if (idx < 384) {
                const int dw4 = idx & 1;
                const int dh  = (idx >> 1) & 7;
                const int c4  = idx >> 4;
                const int c0 = c4 * 4, l0 = dh * 8 + dw4 * 4;
                __bf16 bf[4][4];                    // [jc][il]
                #pragma unroll
                for (int j = 0; j < 4; ++j) {
                    const float4 v = x4[(base + (c0 + j) * HWp + dh * Wimg + dw4 * 4) >> 2];
                    bf[j][0] = (__bf16)v.x; bf[j][1] = (__bf16)v.y;
                    bf[j][2] = (__bf16)v.z; bf[j][3] = (__bf16)v.w;
                }
                // (a) simple: row c, 4 consecutive l (full-row coverage -> conflict-free)
                #pragma unroll
                for (int j = 0; j < 4; ++j) {
                    const int c = c0 + j;
                    bf16x4 d = {bf[j][0], bf[j][1], bf[j][2], bf[j][3]};
                    *reinterpret_cast<bf16x4*>(S + XWS + c * 128 + ((l0 * 2) ^ ((c & 7) << 4))) = d;
                }
                // (b) XWLC: per l, pack 4 c's; 1040B slot stride rotates banks
                #pragma unroll
                for (int i = 0; i < 4; ++i) {
                    const int l = l0 + i;
                    const int s = (c0 >> 5) * 4 + (l >> 4);
                    const int quad = (l & 15) + ((c0 >> 3) & 3) * 16;
                    bf16x4 d = {bf[0][i], bf[1][i], bf[2][i], bf[3][i]};
                    *reinterpret_cast<bf16x4*>(S + XWLC + s * 1040 + quad * 16 + (c0 & 7) * 2) = d;
                }
            }
        }
    }
    __syncthreads();

    // ---- G_P (MFMA): xp[16p][96c] = P^T(hi/lo) @ xw^T ; rows 7-15 zero ----
    {
        frag_u PAh[2], PAl[2];
        {
            const int p = lane & 15, kb = lane >> 4;
            const __bf16 PH = (__bf16)0.1f;
            const __bf16 PL = (__bf16)(0.1f - (float)PH);
            const int sp = (p < 7) ? ((p << 6) / 7) : 1000;
            #pragma unroll
            for (int ks = 0; ks < 2; ++ks)
                #pragma unroll
                for (int j = 0; j < 8; ++j) {
                    const int l = ks * 32 + kb * 8 + j;
                    const bool in = (l >= sp) && (l < sp + 10);
                    PAh[ks].b[j] = in ? PH : (__bf16)0.f;
                    PAl[ks].b[j] = in ? PL : (__bf16)0.f;
                }
        }
        #pragma unroll
        for (int rnd = 0; rnd < 2; ++rnd) {
            const int nt = rnd ? (4 + w) : w;
            if (rnd == 0 || w < 2) {
                f32x4 acc = {0.f, 0.f, 0.f, 0.f};
                #pragma unroll
                for (int ks = 0; ks < 2; ++ks) {
                    frag_u B;
                    B.s = xws_fragA(S, nt, ks, lane);
                    acc = __builtin_amdgcn_mfma_f32_16x16x32_bf16(PAh[ks].b, B.b, acc, 0, 0, 0);
                    acc = __builtin_amdgcn_mfma_f32_16x16x32_bf16(PAl[ks].b, B.b, acc, 0, 0, 0);
                }
                const int cc = nt * 16 + (lane & 15);
                #pragma unroll
                for (int rr = 0; rr < 4; ++rr)
                    xpf[((lane >> 4) * 4 + rr) * 100 + cc] = acc[rr];
            }
        }
    }
    __syncthreads();

    // ---- G0 (MFMA): gkq[16][96] = xp(hi/lo) @ Mext(hi/lo) + b2; nt6 = bias dots ----
    {
        frag_u Ah[3], Al[3];
        #pragma unroll
        for (int ks = 0; ks < 3; ++ks) {
            const int off = (lane & 15) * 100 + ks * 32 + (lane >> 4) * 8;
            hilo8(*reinterpret_cast<const float4*>(&xpf[off]),
                  *reinterpret_cast<const float4*>(&xpf[off + 4]), Ah[ks], Al[ks]);
        }
        #pragma unroll
        for (int rr4 = 0; rr4 < 4; ++rr4) {
            const int tt = w + 4 * rr4;              // balanced: waves 0,1 -> 4; 2,3 -> 3
            if (tt < 14) {
                const int mat = tt / 7, nt = tt % 7;
                f32x4 acc = {0.f, 0.f, 0.f, 0.f};
                #pragma unroll
                for (int ks = 0; ks < 3; ++ks) {
                    const int slot = ((mat * 7 + nt) * 3 + ks) * 2;
                    frag_u Bh, Bl;
                    Bh.s = *reinterpret_cast<const short8*>(mfrag + slot * 1024 + (lane << 4));
                    Bl.s = *reinterpret_cast<const short8*>(mfrag + (slot + 1) * 1024 + (lane << 4));
                    acc = __builtin_amdgcn_mfma_f32_16x16x32_bf16(Ah[ks].b, Bh.b, acc, 0, 0, 0);
                    acc = __builtin_amdgcn_mfma_f32_16x16x32_bf16(Ah[ks].b, Bl.b, acc, 0, 0, 0);
                    acc = __builtin_amdgcn_mfma_f32_16x16x32_bf16(Al[ks].b, Bh.b, acc, 0, 0, 0);
                }
                const int row0 = (lane >> 4) * 4;
                if (nt < 6) {
                    const int cc = nt * 16 + (lane & 15);
                    const float b2v = (mat ? bq2 : bk2)[cc];
                    #pragma unroll
                    for (int rr = 0; rr < 4; ++rr) {
                        const int rw = row0 + rr;
                        if (rw < 8) gkq[(rw + 8 * mat) * 100 + cc] = acc[rr] + b2v;
                    }
                } else if ((lane & 15) == 0) {
                    #pragma unroll
                    for (int rr = 0; rr < 4; ++rr) {
                        const int rw = row0 + rr;
                        if (rw < 8) gkq[(rw + 8 * mat) * 100 + 96] = acc[rr];
                    }
                }
            }
        }
    }
    __syncthreads();

    // ---- G1 (MFMA): L^T[16][64] = gkq(hi/lo) @ xwLC + bias ; wave = ntile ----
    {
        frag_u Ah[3], Al[3], B[3];
        #pragma unroll
        for (int ks = 0; ks < 3; ++ks) {
            const int off = (lane & 15) * 100 + ks * 32 + (lane >> 4) * 8;
            hilo8(*reinterpret_cast<const float4*>(&gkq[off]),
                  *reinterpret_cast<const float4*>(&gkq[off + 4]), Ah[ks], Al[ks]);
            B[ks].s = *reinterpret_cast<const short8*>(S + XWLC + (ks * 4 + w) * 1040 + (lane << 4));
        }
        f32x4 acc = {0.f, 0.f, 0.f, 0.f};
        #pragma unroll
        for (int ks = 0; ks < 3; ++ks) {
            acc = __builtin_amdgcn_mfma_f32_16x16x32_bf16(Ah[ks].b, B[ks].b, acc, 0, 0, 0);
            acc = __builtin_amdgcn_mfma_f32_16x16x32_bf16(Al[ks].b, B[ks].b, acc, 0, 0, 0);
        }
        const int colL = w * 16 + (lane & 15);
        #pragma unroll
        for (int rr = 0; rr < 4; ++rr) {
            const int pr = (lane >> 4) * 4 + rr;
            const float bias = gkq[pr * 100 + 96] + (pr < 8 ? scal0 : scal1);
            Lraw[pr * 66 + colL] = acc[rr] + bias;
        }
    }
    __syncthreads();

    // ---- SM: k-softmax rows spread over waves 0-3; q-softmax on wave 3 ----
    if (w < 3) {
        #pragma unroll
        for (int rr = 0; rr < 2; ++rr) {
            const int pp = w + 3 * rr;               // rows 0..5
            const float v = Lraw[pp * 66 + lane];
            float mx = v;
            #pragma unroll
            for (int off = 32; off; off >>= 1) mx = fmaxf(mx, __shfl_xor(mx, off));
            const float e = __expf(v - mx);
            float s = e;
            #pragma unroll
            for (int off = 32; off; off >>= 1) s += __shfl_xor(s, off);
            const float a = e / s;
            const __bf16 hb = (__bf16)a;
            const __bf16 lb = (__bf16)(a - (float)hb);
            const int ks = lane >> 5;
            const int off_b = ((pp + 16 * ((lane >> 3) & 3)) << 4) + ((lane & 7) << 1);
            *reinterpret_cast<__bf16*>(S + R2 + (ks << 10) + off_b) = hb;
            *reinterpret_cast<__bf16*>(S + R2 + ((2 + ks) << 10) + off_b) = lb;
        }
    } else {
        {
            const int pp = 6;
            const float v = Lraw[pp * 66 + lane];
            float mx = v;
            #pragma unroll
            for (int off = 32; off; off >>= 1) mx = fmaxf(mx, __shfl_xor(mx, off));
            const float e = __expf(v - mx);
            float s = e;
            #pragma unroll
            for (int off = 32; off; off >>= 1) s += __shfl_xor(s, off);
            const float a = e / s;
            const __bf16 hb = (__bf16)a;
            const __bf16 lb = (__bf16)(a - (float)hb);
            const int ks = lane >> 5;
            const int off_b = ((pp + 16 * ((lane >> 3) & 3)) << 4) + ((lane & 7) << 1);
            *reinterpret_cast<__bf16*>(S + R2 + (ks << 10) + off_b) = hb;
            *reinterpret_cast<__bf16*>(S + R2 + ((2 + ks) << 10) + off_b) = lb;
        }
        float vv[Pp];
        float mx = -1e30f;
        #pragma unroll
        for (int p = 0; p < Pp; ++p) { vv[p] = Lraw[(8 + p) * 66 + lane]; mx = fmaxf(mx, vv[p]); }
        float s = 0.f;
        #pragma unroll
        for (int p = 0; p < Pp; ++p) { vv[p] = __expf(vv[p] - mx); s += vv[p]; }
        const float inv = 1.f / s;
        #pragma unroll
        for (int p = 0; p < Pp; ++p) qat[lane * 9 + p] = vv[p] * inv;
    }
    __syncthreads();

    // ---- G2 (MFMA): xv^T[96c][16p] = xw(A, direct-swizzled) @ attn(hi/lo) ----
    {
        frag_u Bh[2], Bl[2];
        #pragma unroll
        for (int ks = 0; ks < 2; ++ks) {
            Bh[ks].s = *reinterpret_cast<const short8*>(S + R2 + (ks << 10) + (lane << 4));
            Bl[ks].s = *reinterpret_cast<const short8*>(S + R2 + ((2 + ks) << 10) + (lane << 4));
        }
        const int mt0 = (w < 2) ? w * 2 : (w + 2);
        const int nmt = (w < 2) ? 2 : 1;
        for (int m = 0; m < nmt; ++m) {
            const int mt = mt0 + m;
            f32x4 acc = {0.f, 0.f, 0.f, 0.f};
            #pragma unroll
            for (int ks = 0; ks < 2; ++ks) {
                frag_u A;
                A.s = xws_fragA(S, mt, ks, lane);
                acc = __builtin_amdgcn_mfma_f32_16x16x32_bf16(A.b, Bh[ks].b, acc, 0, 0, 0);
                acc = __builtin_amdgcn_mfma_f32_16x16x32_bf16(A.b, Bl[ks].b, acc, 0, 0, 0);
            }
            const int p = lane & 15;
            const int c0 = mt * 16 + (lane >> 4) * 4;
            *reinterpret_cast<f32x4*>(&xvf[p * 100 + c0]) = acc;
        }
    }
    __syncthreads();

    // ---- G3 (MFMA): av^T[96o][16p] = Wv(hi/lo) @ xv(hi/lo) + bv ----
    {
        frag_u Bh[3], Bl[3];
        #pragma unroll
        for (int ks = 0; ks < 3; ++ks) {
            const int off = (lane & 15) * 100 + ks * 32 + (lane >> 4) * 8;
            hilo8(*reinterpret_cast<const float4*>(&xvf[off]),
                  *reinterpret_cast<const float4*>(&xvf[off + 4]), Bh[ks], Bl[ks]);
        }
        #pragma unroll
        for (int rnd = 0; rnd < 2; ++rnd) {
            const int mt = rnd ? (4 + w) : w;
            if (rnd == 0 || w < 2) {
                f32x4 acc = {0.f, 0.f, 0.f, 0.f};
                #pragma unroll
                for (int ks = 0; ks < 3; ++ks) {
                    const int slot = (mt * 3 + ks) * 2;
                    frag_u Ah, Al;
                    Ah.s = *reinterpret_cast<const short8*>(wvfrag + slot * 1024 + (lane << 4));
                    Al.s = *reinterpret_cast<const short8*>(wvfrag + (slot + 1) * 1024 + (lane << 4));
                    acc = __builtin_amdgcn_mfma_f32_16x16x32_bf16(Ah.b, Bh[ks].b, acc, 0, 0, 0);
                    acc = __builtin_amdgcn_mfma_f32_16x16x32_bf16(Ah.b, Bl[ks].b, acc, 0, 0, 0);
                    acc = __builtin_amdgcn_mfma_f32_16x16x32_bf16(Al.b, Bh[ks].b, acc, 0, 0, 0);
                }
                if ((lane & 15) < 8) {
                    #pragma unroll
                    for (int rr = 0; rr < 4; ++rr) {
                        const int o = mt * 16 + (lane >> 4) * 4 + rr;
                        avT[o * 8 + (lane & 15)] = acc[rr] + bv[o];
                    }
                }
            }
        }
    }
    __syncthreads();

    // ---- P7 (scalar): out = q_attn @ agent_v ----
    {
        float qa[Pp];
        #pragma unroll
        for (int p = 0; p < Pp; ++p) qa[p] = qat[lane * 9 + p];
        const int dh = lane >> 3, dw = lane & 7;
        const int obase = b * C_ * HWp + (h0 + dh) * Wimg + (w0 + dw);
        #pragma unroll 4
        for (int j = 0; j < 24; ++j) {
            const int o = w + 4 * j;                 // wave-uniform
            const float4 a0 = *reinterpret_cast<const float4*>(&avT[o * 8]);
            const float4 a1 = *reinterpret_cast<const float4*>(&avT[o * 8 + 4]);
            float acc = qa[0] * a0.x;
            acc = fmaf(qa[1], a0.y, acc);
            acc = fmaf(qa[2], a0.z, acc);
            acc = fmaf(qa[3], a0.w, acc);
            acc = fmaf(qa[4], a1.x, acc);
            acc = fmaf(qa[5], a1.y, acc);
            acc = fmaf(qa[6], a1.z, acc);
            out[obase + o * HWp] = acc;
        }
    }
}

// ---------------- launch ----------------

extern "C" void kernel_launch(void* const* d_in, const int* in_sizes, int n_in,
                              void* d_out, int out_size, void* d_ws, size_t ws_size,
                              hipStream_t stream)
{
    const float* x  = (const float*)d_in[0];
    const float* Wv = (const float*)d_in[1];
    const float* bv = (const float*)d_in[2];
    const float* Wq = (const float*)d_in[3];
    const float* bq = (const float*)d_in[4];
    const float* Wk = (const float*)d_in[5];
    const float* bk = (const float*)d_in[6];
    float* out = (float*)d_out;

    float* ws = (float*)d_ws;
    float* Mk   = ws;                 // 9216
    float* Mq   = ws + 9216;          // 9216
    float* uk   = ws + 18432;
    float* uq   = ws + 18528;
    float* bk2  = ws + 18624;
    float* bq2  = ws + 18720;
    float* scal = ws + 18816;
    unsigned char* wsb = (unsigned char*)d_ws;

    hipLaunchKernelGGL(precompute_mats, dim3(C_), dim3(C_), 0, stream,
                       Wq, Wk, Mk, Mq);
    hipLaunchKernelGGL(precompute_vecs, dim3(1), dim3(C_), 0, stream,
                       Wq, Wk, bq, bk, uk, uq, bk2, bq2, scal);
    hipLaunchKernelGGL(precompute_frags, dim3(120), dim3(64), 0, stream,
                       ws, Wv, wsb);
    hipLaunchKernelGGL(camixer_main, dim3(8 * NWIN * NWIN), dim3(256), 0, stream,
                       x, bv, bk2, bq2, scal,
                       wsb + WS_FRAG_BYTE, wsb + WS_WV_BYTE, out);
}

// Round 8
// 81.994 us; speedup vs baseline: 4.6481x; 1.0861x over previous
//
#include <hip/hip_runtime.h>

// CAMixer agent-attention, fused per-window (8x8).  v8 = v7 + counted barriers + prefetch:
//  - all __syncthreads() -> {s_waitcnt lgkmcnt(0); raw s_barrier}: no vmcnt(0) drain,
//    global loads stay in flight across phase barriers (all inter-phase deps are LDS).
//  - G0 first-tile mfrag loads issued at kernel start (hidden under P0+G_P);
//    remaining G0 tiles hand-pipelined (load tile r+1 before MFMAs of tile r).
//  - G3 wvfrag loads issued at top of G2 (in flight across the G2->G3 barrier).
//  - G1 B-frag LDS reads hoisted before its hilo convert chain.
//
// Algebra (exact refactor, verified round 1):
//   agent   = conv(pool(x), Wq)
//   k-logit[p][l] = xw[l]·gk[p] + bkd[p],  gk = xp @ Mk + bk2,  Mk = Wq^T Wk
//   q-logit[l][p] = xw[l]·gq[p] + bqd[p],  gq = xp @ Mq + bq2,  Mq = Wq^T Wq
//   agent_v = (a_attn @ xw) @ Wv^T + bv
//
// MFMA conventions (verified v5/v6/v7):
//   A-frag: lane = row + 16*kblk holds A[row][ks*32 + kblk*8 + j], j=0..7
//   B-frag: lane = col + 16*kblk holds B[ks*32 + kblk*8 + j][col]
//   C-frag: col = lane&15, row = (lane>>4)*4 + reg

constexpr int C_   = 96;
constexpr int Wimg = 192;
constexpr int HWp  = 192 * 192;
constexpr int NWIN = 24;
constexpr int Pp   = 7;

typedef __attribute__((ext_vector_type(8))) __bf16 bf16x8;
typedef __attribute__((ext_vector_type(4))) __bf16 bf16x4;
typedef __attribute__((ext_vector_type(8))) short  short8;
typedef __attribute__((ext_vector_type(4))) float  f32x4;
union frag_u { short8 s; bf16x8 b; };

// ---- LDS byte offsets (total 39,872 B -> 4 blocks/CU) ----
constexpr int XWS   = 0;       // xw simple: bf16 [96][64], row 128B, XOR-swizzled
constexpr int XWLC  = 12288;   // 12 slots x 1040B: xw B-frag image (k=c, n=l)
constexpr int R1    = 24768;   // union: XP[16][100] -> LRAW[16][66] -> XVF[16][100]
constexpr int R2    = 31168;   // union: GKQ[16][100] -> ATTN(4x1KB) -> AVT[96][8]
constexpr int QATB  = 37568;   // [64][9] f32
constexpr int SMEMB = 39872;

// ---- ws float offsets ----
constexpr int WS_FRAG_BYTE = 18944 * 4;                 // Mext frags: 84 slots x 1KB
constexpr int WS_WV_BYTE   = WS_FRAG_BYTE + 84 * 1024;  // Wv frags: 36 slots x 1KB

// ---------------- helpers ----------------

// counted barrier: LDS-sync only, vmcnt preserved (HK pattern)
__device__ __forceinline__ void bar() {
    asm volatile("s_waitcnt lgkmcnt(0)" ::: "memory");
    __builtin_amdgcn_s_barrier();
}

__device__ __forceinline__ void hilo8(const float4 a, const float4 b,
                                      frag_u& H, frag_u& L) {
    float v[8] = {a.x, a.y, a.z, a.w, b.x, b.y, b.z, b.w};
    #pragma unroll
    for (int j = 0; j < 8; ++j) {
        const __bf16 h = (__bf16)v[j];
        H.b[j] = h;
        L.b[j] = (__bf16)(v[j] - (float)h);
    }
}

// A-frag (m=c, k=l) of xw, tile (mt, ks), direct from swizzled simple layout.
__device__ __forceinline__ short8 xws_fragA(const unsigned char* S, int mt, int ks, int lane) {
    const int c  = mt * 16 + (lane & 15);
    const int l2 = ks * 64 + ((lane >> 4) << 4);
    return *reinterpret_cast<const short8*>(S + XWS + c * 128 + (l2 ^ ((c & 7) << 4)));
}

// ---------------- precompute (weights only, trivial cost) ----------------

__global__ void precompute_mats(const float* __restrict__ Wq,
                                const float* __restrict__ Wk,
                                float* __restrict__ Mk,
                                float* __restrict__ Mq)
{
    const int c  = blockIdx.x;
    const int cp = threadIdx.x;
    float ak = 0.f, aq = 0.f;
    for (int a = 0; a < C_; ++a) {
        const float wq = Wq[a * C_ + c];
        ak = fmaf(wq, Wk[a * C_ + cp], ak);
        aq = fmaf(wq, Wq[a * C_ + cp], aq);
    }
    Mk[c * C_ + cp] = ak;
    Mq[c * C_ + cp] = aq;
}

__global__ void precompute_vecs(const float* __restrict__ Wq,
                                const float* __restrict__ Wk,
                                const float* __restrict__ bq,
                                const float* __restrict__ bk,
                                float* __restrict__ uk,  float* __restrict__ uq,
                                float* __restrict__ bk2, float* __restrict__ bq2,
                                float* __restrict__ scal)
{
    const int c = threadIdx.x;
    float a_uk = 0.f, a_uq = 0.f, a_bk2 = 0.f, a_bq2 = 0.f;
    for (int a = 0; a < C_; ++a) {
        const float wqc = Wq[a * C_ + c];
        a_uk  = fmaf(wqc, bk[a], a_uk);
        a_uq  = fmaf(wqc, bq[a], a_uq);
        a_bk2 = fmaf(bq[a], Wk[a * C_ + c], a_bk2);
        a_bq2 = fmaf(bq[a], Wq[a * C_ + c], a_bq2);
    }
    uk[c] = a_uk; uq[c] = a_uq; bk2[c] = a_bk2; bq2[c] = a_bq2;
    if (c == 0) {
        float sk = 0.f, sq = 0.f;
        for (int a = 0; a < C_; ++a) { sk += bq[a] * bk[a]; sq += bq[a] * bq[a]; }
        scal[0] = sk; scal[1] = sq;
    }
}

// frag tables: bid<84: Mext B-frags slot=((mat*7+nt)*3+ks)*2+hl; else Wv A-frags.
__global__ void precompute_frags(const float* __restrict__ ws,
                                 const float* __restrict__ Wv,
                                 unsigned char* __restrict__ wsb)
{
    const int bid = blockIdx.x, lane = threadIdx.x;
    short8 o;
    if (bid < 84) {
        const int hl = bid & 1, ks = (bid >> 1) % 3, nt = (bid / 6) % 7, mat = bid / 42;
        const float* M = ws + (mat ? 9216 : 0);
        const float* u = ws + (mat ? 18528 : 18432);
        const int col = nt * 16 + (lane & 15);
        #pragma unroll
        for (int j = 0; j < 8; ++j) {
            const int k = ks * 32 + (lane >> 4) * 8 + j;
            const float raw = (col < 96) ? M[k * 96 + col] : ((col == 96) ? u[k] : 0.f);
            const __bf16 hi = (__bf16)raw;
            union { __bf16 h; short s; } cv;
            cv.h = hl ? (__bf16)(raw - (float)hi) : hi;
            o[j] = cv.s;
        }
        *reinterpret_cast<short8*>(wsb + WS_FRAG_BYTE + bid * 1024 + lane * 16) = o;
    } else {
        const int wb = bid - 84;
        const int hl = wb & 1, ks = (wb >> 1) % 3, mt = wb / 6;
        const int row = mt * 16 + (lane & 15);
        #pragma unroll
        for (int j = 0; j < 8; ++j) {
            const int c = ks * 32 + (lane >> 4) * 8 + j;
            const float raw = Wv[row * 96 + c];
            const __bf16 hi = (__bf16)raw;
            union { __bf16 h; short s; } cv;
            cv.h = hl ? (__bf16)(raw - (float)hi) : hi;
            o[j] = cv.s;
        }
        *reinterpret_cast<short8*>(wsb + WS_WV_BYTE + wb * 1024 + lane * 16) = o;
    }
}

// load one (hi,lo) Mext/Wv frag pair, slot pair base sl*1024
#define LOADPAIR(dstH, dstL, tab, slot_h) do {                                        \
    (dstH).s = *reinterpret_cast<const short8*>((tab) + (slot_h) * 1024 + (lane << 4));      \
    (dstL).s = *reinterpret_cast<const short8*>((tab) + ((slot_h) + 1) * 1024 + (lane << 4));\
} while (0)

// ---------------- main fused kernel ----------------

__global__ __launch_bounds__(256, 4) void camixer_main(
    const float* __restrict__ x,
    const float* __restrict__ bv,
    const float* __restrict__ bk2,
    const float* __restrict__ bq2,
    const float* __restrict__ scal,
    const unsigned char* __restrict__ mfrag,
    const unsigned char* __restrict__ wvfrag,
    float* __restrict__ out)
{
    __shared__ __align__(16) unsigned char S[SMEMB];
    float* xpf  = (float*)(S + R1);    // [16][100]
    float* Lraw = (float*)(S + R1);    // [16][66]
    float* xvf  = (float*)(S + R1);    // [16][100]
    float* gkq  = (float*)(S + R2);    // [16][100]; col 96 = bias dot
    float* avT  = (float*)(S + R2);    // [96][8]
    float* qat  = (float*)(S + QATB);  // [64][9]

    const int t = threadIdx.x;
    const int lane = t & 63, w = t >> 6;
    const int wid = ((blockIdx.x & 7) * 576) + (blockIdx.x >> 3);  // bijective XCD swizzle
    const int b  = wid / (NWIN * NWIN);
    const int r  = wid % (NWIN * NWIN);
    const int h0 = (r / NWIN) * 8;
    const int w0 = (r % NWIN) * 8;
    const int base = b * C_ * HWp + h0 * Wimg + w0;
    const float scal0 = scal[0], scal1 = scal[1];

    // ---- prefetch G0 tile tt=w (mat 0, nt=w): in flight under P0 + G_P ----
    frag_u B0h[3], B0l[3];
    LOADPAIR(B0h[0], B0l[0], mfrag, (w * 3 + 0) * 2);
    LOADPAIR(B0h[1], B0l[1], mfrag, (w * 3 + 1) * 2);
    LOADPAIR(B0h[2], B0l[2], mfrag, (w * 3 + 2) * 2);

    // ---- P0: x window -> bf16: (a) XOR-swizzled simple layout, (b) XWLC frag image ----
    {
        const float4* x4 = reinterpret_cast<const float4*>(x);
        #pragma unroll
        for (int rr = 0; rr < 2; ++rr) {
            const int idx = t + (rr << 8);          // 384 = 24 c4 x 8 dh x 2 dw4
            if (idx < 384) {
                const int dw4 = idx & 1;
                const int dh  = (idx >> 1) & 7;
                const int c4  = idx >> 4;
                const int c0 = c4 * 4, l0 = dh * 8 + dw4 * 4;
                __bf16 bf[4][4];                    // [jc][il]
                #pragma unroll
                for (int j = 0; j < 4; ++j) {
                    const float4 v = x4[(base + (c0 + j) * HWp + dh * Wimg + dw4 * 4) >> 2];
                    bf[j][0] = (__bf16)v.x; bf[j][1] = (__bf16)v.y;
                    bf[j][2] = (__bf16)v.z; bf[j][3] = (__bf16)v.w;
                }
                #pragma unroll
                for (int j = 0; j < 4; ++j) {
                    const int c = c0 + j;
                    bf16x4 d = {bf[j][0], bf[j][1], bf[j][2], bf[j][3]};
                    *reinterpret_cast<bf16x4*>(S + XWS + c * 128 + ((l0 * 2) ^ ((c & 7) << 4))) = d;
                }
                #pragma unroll
                for (int i = 0; i < 4; ++i) {
                    const int l = l0 + i;
                    const int s = (c0 >> 5) * 4 + (l >> 4);
                    const int quad = (l & 15) + ((c0 >> 3) & 3) * 16;
                    bf16x4 d = {bf[0][i], bf[1][i], bf[2][i], bf[3][i]};
                    *reinterpret_cast<bf16x4*>(S + XWLC + s * 1040 + quad * 16 + (c0 & 7) * 2) = d;
                }
            }
        }
    }
    bar();

    // ---- G_P (MFMA): xp[16p][96c] = P^T(hi/lo) @ xw^T ; rows 7-15 zero ----
    {
        frag_u PAh[2], PAl[2];
        {
            const int p = lane & 15, kb = lane >> 4;
            const __bf16 PH = (__bf16)0.1f;
            const __bf16 PL = (__bf16)(0.1f - (float)PH);
            const int sp = (p < 7) ? ((p << 6) / 7) : 1000;
            #pragma unroll
            for (int ks = 0; ks < 2; ++ks)
                #pragma unroll
                for (int j = 0; j < 8; ++j) {
                    const int l = ks * 32 + kb * 8 + j;
                    const bool in = (l >= sp) && (l < sp + 10);
                    PAh[ks].b[j] = in ? PH : (__bf16)0.f;
                    PAl[ks].b[j] = in ? PL : (__bf16)0.f;
                }
        }
        #pragma unroll
        for (int rnd = 0; rnd < 2; ++rnd) {
            const int nt = rnd ? (4 + w) : w;
            if (rnd == 0 || w < 2) {
                f32x4 acc = {0.f, 0.f, 0.f, 0.f};
                #pragma unroll
                for (int ks = 0; ks < 2; ++ks) {
                    frag_u B;
                    B.s = xws_fragA(S, nt, ks, lane);
                    acc = __builtin_amdgcn_mfma_f32_16x16x32_bf16(PAh[ks].b, B.b, acc, 0, 0, 0);
                    acc = __builtin_amdgcn_mfma_f32_16x16x32_bf16(PAl[ks].b, B.b, acc, 0, 0, 0);
                }
                const int cc = nt * 16 + (lane & 15);
                #pragma unroll
                for (int rr = 0; rr < 4; ++rr)
                    xpf[((lane >> 4) * 4 + rr) * 100 + cc] = acc[rr];
            }
        }
    }
    bar();

    // ---- G0 (MFMA, pipelined): gkq[16][96] = xp(hi/lo) @ Mext(hi/lo); nt6 = bias ----
    {
        frag_u Ah[3], Al[3];
        #pragma unroll
        for (int ks = 0; ks < 3; ++ks) {
            const int off = (lane & 15) * 100 + ks * 32 + (lane >> 4) * 8;
            hilo8(*reinterpret_cast<const float4*>(&xpf[off]),
                  *reinterpret_cast<const float4*>(&xpf[off + 4]), Ah[ks], Al[ks]);
        }

        #define G0TILE(TT, BH, BL) do {                                               \
            const int tt_ = (TT);                                                     \
            const int mat_ = (tt_ >= 7) ? 1 : 0;                                      \
            const int nt_  = tt_ - 7 * mat_;                                          \
            f32x4 acc = {0.f, 0.f, 0.f, 0.f};                                         \
            acc = __builtin_amdgcn_mfma_f32_16x16x32_bf16(Ah[0].b, BH[0].b, acc, 0,0,0); \
            acc = __builtin_amdgcn_mfma_f32_16x16x32_bf16(Ah[0].b, BL[0].b, acc, 0,0,0); \
            acc = __builtin_amdgcn_mfma_f32_16x16x32_bf16(Al[0].b, BH[0].b, acc, 0,0,0); \
            acc = __builtin_amdgcn_mfma_f32_16x16x32_bf16(Ah[1].b, BH[1].b, acc, 0,0,0); \
            acc = __builtin_amdgcn_mfma_f32_16x16x32_bf16(Ah[1].b, BL[1].b, acc, 0,0,0); \
            acc = __builtin_amdgcn_mfma_f32_16x16x32_bf16(Al[1].b, BH[1].b, acc, 0,0,0); \
            acc = __builtin_amdgcn_mfma_f32_16x16x32_bf16(Ah[2].b, BH[2].b, acc, 0,0,0); \
            acc = __builtin_amdgcn_mfma_f32_16x16x32_bf16(Ah[2].b, BL[2].b, acc, 0,0,0); \
            acc = __builtin_amdgcn_mfma_f32_16x16x32_bf16(Al[2].b, BH[2].b, acc, 0,0,0); \
            const int row0_ = (lane >> 4) * 4;                                        \
            if (nt_ < 6) {                                                            \
                const int cc_ = nt_ * 16 + (lane & 15);                               \
                const float b2v_ = (mat_ ? bq2 : bk2)[cc_];                           \
                _Pragma("unroll")                                                     \
                for (int rr = 0; rr < 4; ++rr) {                                      \
                    const int rw_ = row0_ + rr;                                       \
                    if (rw_ < 8) gkq[(rw_ + 8 * mat_) * 100 + cc_] = acc[rr] + b2v_;  \
                }                                                                     \
            } else if ((lane & 15) == 0) {                                            \
                _Pragma("unroll")                                                     \
                for (int rr = 0; rr < 4; ++rr) {                                      \
                    const int rw_ = row0_ + rr;                                       \
                    if (rw_ < 8) gkq[(rw_ + 8 * mat_) * 100 + 96] = acc[rr];          \
                }                                                                     \
            }                                                                         \
        } while (0)

        frag_u B1h[3], B1l[3], B2h[3], B2l[3], B3h[3], B3l[3];
        // issue tt1 = w+4, then compute tt0 (prefetched at kernel start)
        LOADPAIR(B1h[0], B1l[0], mfrag, (((w + 4) % 7 + 7 * ((w + 4) / 7)) * 3 + 0) * 2);
        LOADPAIR(B1h[1], B1l[1], mfrag, ((w + 4) * 3 + 1) * 2);
        LOADPAIR(B1h[2], B1l[2], mfrag, ((w + 4) * 3 + 2) * 2);
        G0TILE(w, B0h, B0l);
        // issue tt2 = w+8, compute tt1
        LOADPAIR(B2h[0], B2l[0], mfrag, ((w + 8) * 3 + 0) * 2);
        LOADPAIR(B2h[1], B2l[1], mfrag, ((w + 8) * 3 + 1) * 2);
        LOADPAIR(B2h[2], B2l[2], mfrag, ((w + 8) * 3 + 2) * 2);
        G0TILE(w + 4, B1h, B1l);
        // issue tt3 = w+12 (w<2 only), compute tt2
        if (w < 2) {
            LOADPAIR(B3h[0], B3l[0], mfrag, ((w + 12) * 3 + 0) * 2);
            LOADPAIR(B3h[1], B3l[1], mfrag, ((w + 12) * 3 + 1) * 2);
            LOADPAIR(B3h[2], B3l[2], mfrag, ((w + 12) * 3 + 2) * 2);
        }
        G0TILE(w + 8, B2h, B2l);
        if (w < 2) G0TILE(w + 12, B3h, B3l);
        #undef G0TILE
    }
    bar();

    // ---- G1 (MFMA): L^T[16][64] = gkq(hi/lo) @ xwLC + bias ; wave = ntile ----
    {
        frag_u B[3];
        #pragma unroll
        for (int ks = 0; ks < 3; ++ks)
            B[ks].s = *reinterpret_cast<const short8*>(S + XWLC + (ks * 4 + w) * 1040 + (lane << 4));
        frag_u Ah[3], Al[3];
        #pragma unroll
        for (int ks = 0; ks < 3; ++ks) {
            const int off = (lane & 15) * 100 + ks * 32 + (lane >> 4) * 8;
            hilo8(*reinterpret_cast<const float4*>(&gkq[off]),
                  *reinterpret_cast<const float4*>(&gkq[off + 4]), Ah[ks], Al[ks]);
        }
        f32x4 acc = {0.f, 0.f, 0.f, 0.f};
        #pragma unroll
        for (int ks = 0; ks < 3; ++ks) {
            acc = __builtin_amdgcn_mfma_f32_16x16x32_bf16(Ah[ks].b, B[ks].b, acc, 0, 0, 0);
            acc = __builtin_amdgcn_mfma_f32_16x16x32_bf16(Al[ks].b, B[ks].b, acc, 0, 0, 0);
        }
        const int colL = w * 16 + (lane & 15);
        #pragma unroll
        for (int rr = 0; rr < 4; ++rr) {
            const int pr = (lane >> 4) * 4 + rr;
            const float bias = gkq[pr * 100 + 96] + (pr < 8 ? scal0 : scal1);
            Lraw[pr * 66 + colL] = acc[rr] + bias;
        }
    }
    bar();

    // ---- SM: k-softmax rows spread over waves; q-softmax on wave 3 ----
    if (w < 3) {
        #pragma unroll
        for (int rr = 0; rr < 2; ++rr) {
            const int pp = w + 3 * rr;               // rows 0..5
            const float v = Lraw[pp * 66 + lane];
            float mx = v;
            #pragma unroll
            for (int off = 32; off; off >>= 1) mx = fmaxf(mx, __shfl_xor(mx, off));
            const float e = __expf(v - mx);
            float s = e;
            #pragma unroll
            for (int off = 32; off; off >>= 1) s += __shfl_xor(s, off);
            const float a = e / s;
            const __bf16 hb = (__bf16)a;
            const __bf16 lb = (__bf16)(a - (float)hb);
            const int ks = lane >> 5;
            const int off_b = ((pp + 16 * ((lane >> 3) & 3)) << 4) + ((lane & 7) << 1);
            *reinterpret_cast<__bf16*>(S + R2 + (ks << 10) + off_b) = hb;
            *reinterpret_cast<__bf16*>(S + R2 + ((2 + ks) << 10) + off_b) = lb;
        }
    } else {
        {
            const int pp = 6;
            const float v = Lraw[pp * 66 + lane];
            float mx = v;
            #pragma unroll
            for (int off = 32; off; off >>= 1) mx = fmaxf(mx, __shfl_xor(mx, off));
            const float e = __expf(v - mx);
            float s = e;
            #pragma unroll
            for (int off = 32; off; off >>= 1) s += __shfl_xor(s, off);
            const float a = e / s;
            const __bf16 hb = (__bf16)a;
            const __bf16 lb = (__bf16)(a - (float)hb);
            const int ks = lane >> 5;
            const int off_b = ((pp + 16 * ((lane >> 3) & 3)) << 4) + ((lane & 7) << 1);
            *reinterpret_cast<__bf16*>(S + R2 + (ks << 10) + off_b) = hb;
            *reinterpret_cast<__bf16*>(S + R2 + ((2 + ks) << 10) + off_b) = lb;
        }
        float vv[Pp];
        float mx = -1e30f;
        #pragma unroll
        for (int p = 0; p < Pp; ++p) { vv[p] = Lraw[(8 + p) * 66 + lane]; mx = fmaxf(mx, vv[p]); }
        float s = 0.f;
        #pragma unroll
        for (int p = 0; p < Pp; ++p) { vv[p] = __expf(vv[p] - mx); s += vv[p]; }
        const float inv = 1.f / s;
        #pragma unroll
        for (int p = 0; p < Pp; ++p) qat[lane * 9 + p] = vv[p] * inv;
    }
    bar();

    // ---- G2 (MFMA) + wvfrag prefetch for G3 (in flight across the barrier) ----
    frag_u V0h[3], V0l[3], V1h[3], V1l[3];
    {
        LOADPAIR(V0h[0], V0l[0], wvfrag, (w * 3 + 0) * 2);
        LOADPAIR(V0h[1], V0l[1], wvfrag, (w * 3 + 1) * 2);
        LOADPAIR(V0h[2], V0l[2], wvfrag, (w * 3 + 2) * 2);
        if (w < 2) {
            LOADPAIR(V1h[0], V1l[0], wvfrag, ((4 + w) * 3 + 0) * 2);
            LOADPAIR(V1h[1], V1l[1], wvfrag, ((4 + w) * 3 + 1) * 2);
            LOADPAIR(V1h[2], V1l[2], wvfrag, ((4 + w) * 3 + 2) * 2);
        }

        frag_u Bh[2], Bl[2];
        #pragma unroll
        for (int ks = 0; ks < 2; ++ks) {
            Bh[ks].s = *reinterpret_cast<const short8*>(S + R2 + (ks << 10) + (lane << 4));
            Bl[ks].s = *reinterpret_cast<const short8*>(S + R2 + ((2 + ks) << 10) + (lane << 4));
        }
        const int mt0 = (w < 2) ? w * 2 : (w + 2);
        const int nmt = (w < 2) ? 2 : 1;
        for (int m = 0; m < nmt; ++m) {
            const int mt = mt0 + m;
            f32x4 acc = {0.f, 0.f, 0.f, 0.f};
            #pragma unroll
            for (int ks = 0; ks < 2; ++ks) {
                frag_u A;
                A.s = xws_fragA(S, mt, ks, lane);
                acc = __builtin_amdgcn_mfma_f32_16x16x32_bf16(A.b, Bh[ks].b, acc, 0, 0, 0);
                acc = __builtin_amdgcn_mfma_f32_16x16x32_bf16(A.b, Bl[ks].b, acc, 0, 0, 0);
            }
            const int p = lane & 15;
            const int c0 = mt * 16 + (lane >> 4) * 4;
            *reinterpret_cast<f32x4*>(&xvf[p * 100 + c0]) = acc;
        }
    }
    bar();

    // ---- G3 (MFMA): av^T[96o][16p] = Wv(hi/lo) @ xv(hi/lo) + bv ----
    {
        frag_u Bh[3], Bl[3];
        #pragma unroll
        for (int ks = 0; ks < 3; ++ks) {
            const int off = (lane & 15) * 100 + ks * 32 + (lane >> 4) * 8;
            hilo8(*reinterpret_cast<const float4*>(&xvf[off]),
                  *reinterpret_cast<const float4*>(&xvf[off + 4]), Bh[ks], Bl[ks]);
        }
        #define G3TILE(MT, VH, VL) do {                                               \
            f32x4 acc = {0.f, 0.f, 0.f, 0.f};                                         \
            acc = __builtin_amdgcn_mfma_f32_16x16x32_bf16(VH[0].b, Bh[0].b, acc, 0,0,0); \
            acc = __builtin_amdgcn_mfma_f32_16x16x32_bf16(VH[0].b, Bl[0].b, acc, 0,0,0); \
            acc = __builtin_amdgcn_mfma_f32_16x16x32_bf16(VL[0].b, Bh[0].b, acc, 0,0,0); \
            acc = __builtin_amdgcn_mfma_f32_16x16x32_bf16(VH[1].b, Bh[1].b, acc, 0,0,0); \
            acc = __builtin_amdgcn_mfma_f32_16x16x32_bf16(VH[1].b, Bl[1].b, acc, 0,0,0); \
            acc = __builtin_amdgcn_mfma_f32_16x16x32_bf16(VL[1].b, Bh[1].b, acc, 0,0,0); \
            acc = __builtin_amdgcn_mfma_f32_16x16x32_bf16(VH[2].b, Bh[2].b, acc, 0,0,0); \
            acc = __builtin_amdgcn_mfma_f32_16x16x32_bf16(VH[2].b, Bl[2].b, acc, 0,0,0); \
            acc = __builtin_amdgcn_mfma_f32_16x16x32_bf16(VL[2].b, Bh[2].b, acc, 0,0,0); \
            if ((lane & 15) < 8) {                                                    \
                _Pragma("unroll")                                                     \
                for (int rr = 0; rr < 4; ++rr) {                                      \
                    const int o_ = (MT) * 16 + (lane >> 4) * 4 + rr;                  \
                    avT[o_ * 8 + (lane & 15)] = acc[rr] + bv[o_];                     \
                }                                                                     \
            }                                                                         \
        } while (0)
        G3TILE(w, V0h, V0l);
        if (w < 2) G3TILE(4 + w, V1h, V1l);
        #undef G3TILE
    }
    bar();

    // ---- P7 (scalar): out = q_attn @ agent_v ----
    {
        float qa[Pp];
        #pragma unroll
        for (int p = 0; p < Pp; ++p) qa[p] = qat[lane * 9 + p];
        const int dh = lane >> 3, dw = lane & 7;
        const int obase = b * C_ * HWp + (h0 + dh) * Wimg + (w0 + dw);
        #pragma unroll 4
        for (int j = 0; j < 24; ++j) {
            const int o = w + 4 * j;                 // wave-uniform
            const float4 a0 = *reinterpret_cast<const float4*>(&avT[o * 8]);
            const float4 a1 = *reinterpret_cast<const float4*>(&avT[o * 8 + 4]);
            float acc = qa[0] * a0.x;
            acc = fmaf(qa[1], a0.y, acc);
            acc = fmaf(qa[2], a0.z, acc);
            acc = fmaf(qa[3], a0.w, acc);
            acc = fmaf(qa[4], a1.x, acc);
            acc = fmaf(qa[5], a1.y, acc);
            acc = fmaf(qa[6], a1.z, acc);
            out[obase + o * HWp] = acc;
        }
    }
}

// ---------------- launch ----------------

extern "C" void kernel_launch(void* const* d_in, const int* in_sizes, int n_in,
                              void* d_out, int out_size, void* d_ws, size_t ws_size,
                              hipStream_t stream)
{
    const float* x  = (const float*)d_in[0];
    const float* Wv = (const float*)d_in[1];
    const float* bv = (const float*)d_in[2];
    const float* Wq = (const float*)d_in[3];
    const float* bq = (const float*)d_in[4];
    const float* Wk = (const float*)d_in[5];
    const float* bk = (const float*)d_in[6];
    float* out = (float*)d_out;

    float* ws = (float*)d_ws;
    float* Mk   = ws;                 // 9216
    float* Mq   = ws + 9216;          // 9216
    float* uk   = ws + 18432;
    float* uq   = ws + 18528;
    float* bk2  = ws + 18624;
    float* bq2  = ws + 18720;
    float* scal = ws + 18816;
    unsigned char* wsb = (unsigned char*)d_ws;

    hipLaunchKernelGGL(precompute_mats, dim3(C_), dim3(C_), 0, stream,
                       Wq, Wk, Mk, Mq);
    hipLaunchKernelGGL(precompute_vecs, dim3(1), dim3(C_), 0, stream,
                       Wq, Wk, bq, bk, uk, uq, bk2, bq2, scal);
    hipLaunchKernelGGL(precompute_frags, dim3(120), dim3(64), 0, stream,
                       ws, Wv, wsb);
    hipLaunchKernelGGL(camixer_main, dim3(8 * NWIN * NWIN), dim3(256), 0, stream,
                       x, bv, bk2, bq2, scal,
                       wsb + WS_FRAG_BYTE, wsb + WS_WV_BYTE, out);
}

// Round 9
// 78.271 us; speedup vs baseline: 4.8692x; 1.0476x over previous
//
#include <hip/hip_runtime.h>

// CAMixer agent-attention, fused per-window (8x8).  v9 = v8 + producer-side hi/lo
// + MFMA epilogue:
//  - G_P/G0/G2 write bf16 hi/lo images directly (bit-identical values to v8's
//    consumer-side hilo8); G0/G1/G3 heads become ds_read_b128 -> MFMA.
//  - P7 as MFMA: out^T = av_ext[96][32p] @ qat^T (K=32, p>=7 zero), 18 MFMA/wave.
//  - qat hi/lo aliases XWLC (dead after G1); av hi/lo aliases attn (dead after G2).
//  - G3 B-frag lanes p>=7 zeroed (NaN guard vs aliased garbage).
//
// Algebra (exact refactor, verified round 1):
//   agent   = conv(pool(x), Wq)
//   k-logit[p][l] = xw[l]·gk[p] + bkd[p],  gk = xp @ Mk + bk2,  Mk = Wq^T Wk
//   q-logit[l][p] = xw[l]·gq[p] + bqd[p],  gq = xp @ Mq + bq2,  Mq = Wq^T Wq
//   agent_v = (a_attn @ xw) @ Wv^T + bv
//
// MFMA conventions (verified v5-v8):
//   A-frag: lane = row + 16*kblk holds A[row][ks*32 + kblk*8 + j], j=0..7
//   B-frag: lane = col + 16*kblk holds B[ks*32 + kblk*8 + j][col]
//   C-frag: col = lane&15, row = (lane>>4)*4 + reg

constexpr int C_   = 96;
constexpr int Wimg = 192;
constexpr int HWp  = 192 * 192;
constexpr int NWIN = 24;
constexpr int Pp   = 7;

typedef __attribute__((ext_vector_type(8))) __bf16 bf16x8;
typedef __attribute__((ext_vector_type(4))) __bf16 bf16x4;
typedef __attribute__((ext_vector_type(8))) short  short8;
typedef __attribute__((ext_vector_type(4))) float  f32x4;
union frag_u { short8 s; bf16x8 b; };

// ---- LDS byte offsets (total 37,632 B -> 4 blocks/CU) ----
constexpr int XWS   = 0;       // xw simple: bf16 [96][64], row 128B, XOR-swizzled
constexpr int XWLC  = 12288;   // 12 slots x 1040B xw B-frag image; after G1: qat hi/lo [64][20]bf16 x2
constexpr int R1    = 24768;   // 6400B: xp hi/lo [16][100]bf16 -> Lraw[16][66]f32 -> xv hi/lo
constexpr int R2    = 31168;   // 6400B: gkq hi/lo [16][100]bf16 -> attn(4x1KB) -> av hi/lo [96][16]bf16
constexpr int QATH  = XWLC;            // qat_hi, rows 40B
constexpr int QATL  = XWLC + 2560;     // qat_lo
constexpr int AVH   = R2;              // av_hi [96][16] bf16 (32B rows)
constexpr int AVL   = R2 + 3072;       // av_lo
constexpr int BIAS  = 37568;   // f32[16]
constexpr int SMEMB = 37632;

// ---- ws float offsets ----
constexpr int WS_FRAG_BYTE = 18944 * 4;                 // Mext frags: 84 slots x 1KB
constexpr int WS_WV_BYTE   = WS_FRAG_BYTE + 84 * 1024;  // Wv frags: 36 slots x 1KB

// ---------------- helpers ----------------

__device__ __forceinline__ void bar() {
    asm volatile("s_waitcnt lgkmcnt(0)" ::: "memory");
    __builtin_amdgcn_s_barrier();
}

// A-frag (m=c, k=l) of xw, tile (mt, ks), direct from swizzled simple layout.
__device__ __forceinline__ short8 xws_fragA(const unsigned char* S, int mt, int ks, int lane) {
    const int c  = mt * 16 + (lane & 15);
    const int l2 = ks * 64 + ((lane >> 4) << 4);
    return *reinterpret_cast<const short8*>(S + XWS + c * 128 + (l2 ^ ((c & 7) << 4)));
}

// write one f32 as bf16 hi/lo pair into two LDS arrays
__device__ __forceinline__ void put_hilo(unsigned char* S, int hi_off, int lo_off, float v) {
    const __bf16 h = (__bf16)v;
    *reinterpret_cast<__bf16*>(S + hi_off) = h;
    *reinterpret_cast<__bf16*>(S + lo_off) = (__bf16)(v - (float)h);
}

// ---------------- precompute (weights only, trivial cost) ----------------

__global__ void precompute_mats(const float* __restrict__ Wq,
                                const float* __restrict__ Wk,
                                float* __restrict__ Mk,
                                float* __restrict__ Mq)
{
    const int c  = blockIdx.x;
    const int cp = threadIdx.x;
    float ak = 0.f, aq = 0.f;
    for (int a = 0; a < C_; ++a) {
        const float wq = Wq[a * C_ + c];
        ak = fmaf(wq, Wk[a * C_ + cp], ak);
        aq = fmaf(wq, Wq[a * C_ + cp], aq);
    }
    Mk[c * C_ + cp] = ak;
    Mq[c * C_ + cp] = aq;
}

__global__ void precompute_vecs(const float* __restrict__ Wq,
                                const float* __restrict__ Wk,
                                const float* __restrict__ bq,
                                const float* __restrict__ bk,
                                float* __restrict__ uk,  float* __restrict__ uq,
                                float* __restrict__ bk2, float* __restrict__ bq2,
                                float* __restrict__ scal)
{
    const int c = threadIdx.x;
    float a_uk = 0.f, a_uq = 0.f, a_bk2 = 0.f, a_bq2 = 0.f;
    for (int a = 0; a < C_; ++a) {
        const float wqc = Wq[a * C_ + c];
        a_uk  = fmaf(wqc, bk[a], a_uk);
        a_uq  = fmaf(wqc, bq[a], a_uq);
        a_bk2 = fmaf(bq[a], Wk[a * C_ + c], a_bk2);
        a_bq2 = fmaf(bq[a], Wq[a * C_ + c], a_bq2);
    }
    uk[c] = a_uk; uq[c] = a_uq; bk2[c] = a_bk2; bq2[c] = a_bq2;
    if (c == 0) {
        float sk = 0.f, sq = 0.f;
        for (int a = 0; a < C_; ++a) { sk += bq[a] * bk[a]; sq += bq[a] * bq[a]; }
        scal[0] = sk; scal[1] = sq;
    }
}

// frag tables: bid<84: Mext B-frags slot=((mat*7+nt)*3+ks)*2+hl; else Wv A-frags.
__global__ void precompute_frags(const float* __restrict__ ws,
                                 const float* __restrict__ Wv,
                                 unsigned char* __restrict__ wsb)
{
    const int bid = blockIdx.x, lane = threadIdx.x;
    short8 o;
    if (bid < 84) {
        const int hl = bid & 1, ks = (bid >> 1) % 3, nt = (bid / 6) % 7, mat = bid / 42;
        const float* M = ws + (mat ? 9216 : 0);
        const float* u = ws + (mat ? 18528 : 18432);
        const int col = nt * 16 + (lane & 15);
        #pragma unroll
        for (int j = 0; j < 8; ++j) {
            const int k = ks * 32 + (lane >> 4) * 8 + j;
            const float raw = (col < 96) ? M[k * 96 + col] : ((col == 96) ? u[k] : 0.f);
            const __bf16 hi = (__bf16)raw;
            union { __bf16 h; short s; } cv;
            cv.h = hl ? (__bf16)(raw - (float)hi) : hi;
            o[j] = cv.s;
        }
        *reinterpret_cast<short8*>(wsb + WS_FRAG_BYTE + bid * 1024 + lane * 16) = o;
    } else {
        const int wb = bid - 84;
        const int hl = wb & 1, ks = (wb >> 1) % 3, mt = wb / 6;
        const int row = mt * 16 + (lane & 15);
        #pragma unroll
        for (int j = 0; j < 8; ++j) {
            const int c = ks * 32 + (lane >> 4) * 8 + j;
            const float raw = Wv[row * 96 + c];
            const __bf16 hi = (__bf16)raw;
            union { __bf16 h; short s; } cv;
            cv.h = hl ? (__bf16)(raw - (float)hi) : hi;
            o[j] = cv.s;
        }
        *reinterpret_cast<short8*>(wsb + WS_WV_BYTE + wb * 1024 + lane * 16) = o;
    }
}

#define LOADPAIR(dstH, dstL, tab, slot_h) do {                                               \
    (dstH).s = *reinterpret_cast<const short8*>((tab) + (slot_h) * 1024 + (lane << 4));      \
    (dstL).s = *reinterpret_cast<const short8*>((tab) + ((slot_h) + 1) * 1024 + (lane << 4));\
} while (0)

// ---------------- main fused kernel ----------------

__global__ __launch_bounds__(256, 4) void camixer_main(
    const float* __restrict__ x,
    const float* __restrict__ bv,
    const float* __restrict__ bk2,
    const float* __restrict__ bq2,
    const float* __restrict__ scal,
    const unsigned char* __restrict__ mfrag,
    const unsigned char* __restrict__ wvfrag,
    float* __restrict__ out)
{
    __shared__ __align__(16) unsigned char S[SMEMB];
    float* Lraw   = (float*)(S + R1);    // [16][66]
    float* bias16 = (float*)(S + BIAS);  // [16]

    const int t = threadIdx.x;
    const int lane = t & 63, w = t >> 6;
    const int wid = ((blockIdx.x & 7) * 576) + (blockIdx.x >> 3);  // bijective XCD swizzle
    const int b  = wid / (NWIN * NWIN);
    const int r  = wid % (NWIN * NWIN);
    const int h0 = (r / NWIN) * 8;
    const int w0 = (r % NWIN) * 8;
    const int base = b * C_ * HWp + h0 * Wimg + w0;
    const float scal0 = scal[0], scal1 = scal[1];
    const short8 zero8 = {0, 0, 0, 0, 0, 0, 0, 0};

    // ---- prefetch G0 tile tt=w: in flight under P0 + G_P ----
    frag_u B0h[3], B0l[3];
    LOADPAIR(B0h[0], B0l[0], mfrag, (w * 3 + 0) * 2);
    LOADPAIR(B0h[1], B0l[1], mfrag, (w * 3 + 1) * 2);
    LOADPAIR(B0h[2], B0l[2], mfrag, (w * 3 + 2) * 2);

    // ---- P0: x window -> bf16: XOR-swizzled simple + XWLC frag image ----
    {
        const float4* x4 = reinterpret_cast<const float4*>(x);
        #pragma unroll
        for (int rr = 0; rr < 2; ++rr) {
            const int idx = t + (rr << 8);          // 384 = 24 c4 x 8 dh x 2 dw4
            if (idx < 384) {
                const int dw4 = idx & 1;
                const int dh  = (idx >> 1) & 7;
                const int c4  = idx >> 4;
                const int c0 = c4 * 4, l0 = dh * 8 + dw4 * 4;
                __bf16 bf[4][4];
                #pragma unroll
                for (int j = 0; j < 4; ++j) {
                    const float4 v = x4[(base + (c0 + j) * HWp + dh * Wimg + dw4 * 4) >> 2];
                    bf[j][0] = (__bf16)v.x; bf[j][1] = (__bf16)v.y;
                    bf[j][2] = (__bf16)v.z; bf[j][3] = (__bf16)v.w;
                }
                #pragma unroll
                for (int j = 0; j < 4; ++j) {
                    const int c = c0 + j;
                    bf16x4 d = {bf[j][0], bf[j][1], bf[j][2], bf[j][3]};
                    *reinterpret_cast<bf16x4*>(S + XWS + c * 128 + ((l0 * 2) ^ ((c & 7) << 4))) = d;
                }
                #pragma unroll
                for (int i = 0; i < 4; ++i) {
                    const int l = l0 + i;
                    const int s = (c0 >> 5) * 4 + (l >> 4);
                    const int quad = (l & 15) + ((c0 >> 3) & 3) * 16;
                    bf16x4 d = {bf[0][i], bf[1][i], bf[2][i], bf[3][i]};
                    *reinterpret_cast<bf16x4*>(S + XWLC + s * 1040 + quad * 16 + (c0 & 7) * 2) = d;
                }
            }
        }
    }
    bar();

    // ---- G_P (MFMA): xp = P^T(hi/lo) @ xw^T ; write xp hi/lo bf16 [16][100] ----
    {
        frag_u PAh[2], PAl[2];
        {
            const int p = lane & 15;
            const __bf16 PH = (__bf16)0.1f;
            const __bf16 PL = (__bf16)(0.1f - (float)PH);
            const int sp = (p < 7) ? ((p << 6) / 7) : 1000;
            #pragma unroll
            for (int ks = 0; ks < 2; ++ks)
                #pragma unroll
                for (int j = 0; j < 8; ++j) {
                    const int l = ks * 32 + (lane >> 4) * 8 + j;
                    const bool in = (l >= sp) && (l < sp + 10);
                    PAh[ks].b[j] = in ? PH : (__bf16)0.f;
                    PAl[ks].b[j] = in ? PL : (__bf16)0.f;
                }
        }
        #pragma unroll
        for (int rnd = 0; rnd < 2; ++rnd) {
            const int nt = rnd ? (4 + w) : w;
            if (rnd == 0 || w < 2) {
                f32x4 acc = {0.f, 0.f, 0.f, 0.f};
                #pragma unroll
                for (int ks = 0; ks < 2; ++ks) {
                    frag_u B;
                    B.s = xws_fragA(S, nt, ks, lane);
                    acc = __builtin_amdgcn_mfma_f32_16x16x32_bf16(PAh[ks].b, B.b, acc, 0, 0, 0);
                    acc = __builtin_amdgcn_mfma_f32_16x16x32_bf16(PAl[ks].b, B.b, acc, 0, 0, 0);
                }
                const int cc = nt * 16 + (lane & 15);
                #pragma unroll
                for (int rr = 0; rr < 4; ++rr) {
                    const int p = (lane >> 4) * 4 + rr;
                    put_hilo(S, R1 + p * 200 + cc * 2, R1 + 3200 + p * 200 + cc * 2, acc[rr]);
                }
            }
        }
    }
    bar();

    // ---- G0 (MFMA, pipelined): gkq = xp(hi/lo) @ Mext(hi/lo); write gkq hi/lo ----
    {
        frag_u Ah[3], Al[3];
        #pragma unroll
        for (int ks = 0; ks < 3; ++ks) {
            const int off = (lane & 15) * 200 + (ks * 32 + (lane >> 4) * 8) * 2;
            Ah[ks].s = *reinterpret_cast<const short8*>(S + R1 + off);
            Al[ks].s = *reinterpret_cast<const short8*>(S + R1 + 3200 + off);
        }

        #define G0TILE(TT, BH, BL) do {                                               \
            const int tt_ = (TT);                                                     \
            const int mat_ = (tt_ >= 7) ? 1 : 0;                                      \
            const int nt_  = tt_ - 7 * mat_;                                          \
            f32x4 acc = {0.f, 0.f, 0.f, 0.f};                                         \
            acc = __builtin_amdgcn_mfma_f32_16x16x32_bf16(Ah[0].b, BH[0].b, acc, 0,0,0); \
            acc = __builtin_amdgcn_mfma_f32_16x16x32_bf16(Ah[0].b, BL[0].b, acc, 0,0,0); \
            acc = __builtin_amdgcn_mfma_f32_16x16x32_bf16(Al[0].b, BH[0].b, acc, 0,0,0); \
            acc = __builtin_amdgcn_mfma_f32_16x16x32_bf16(Ah[1].b, BH[1].b, acc, 0,0,0); \
            acc = __builtin_amdgcn_mfma_f32_16x16x32_bf16(Ah[1].b, BL[1].b, acc, 0,0,0); \
            acc = __builtin_amdgcn_mfma_f32_16x16x32_bf16(Al[1].b, BH[1].b, acc, 0,0,0); \
            acc = __builtin_amdgcn_mfma_f32_16x16x32_bf16(Ah[2].b, BH[2].b, acc, 0,0,0); \
            acc = __builtin_amdgcn_mfma_f32_16x16x32_bf16(Ah[2].b, BL[2].b, acc, 0,0,0); \
            acc = __builtin_amdgcn_mfma_f32_16x16x32_bf16(Al[2].b, BH[2].b, acc, 0,0,0); \
            const int row0_ = (lane >> 4) * 4;                                        \
            if (nt_ < 6) {                                                            \
                const int cc_ = nt_ * 16 + (lane & 15);                               \
                const float b2v_ = (mat_ ? bq2 : bk2)[cc_];                           \
                _Pragma("unroll")                                                     \
                for (int rr = 0; rr < 4; ++rr) {                                      \
                    const int rw_ = row0_ + rr;                                       \
                    if (rw_ < 8) {                                                    \
                        const int pr_ = rw_ + 8 * mat_;                               \
                        put_hilo(S, R2 + pr_ * 200 + cc_ * 2,                         \
                                 R2 + 3200 + pr_ * 200 + cc_ * 2, acc[rr] + b2v_);    \
                    }                                                                 \
                }                                                                     \
            } else if ((lane & 15) == 0) {                                            \
                _Pragma("unroll")                                                     \
                for (int rr = 0; rr < 4; ++rr) {                                      \
                    const int rw_ = row0_ + rr;                                       \
                    if (rw_ < 8) bias16[rw_ + 8 * mat_] = acc[rr];                    \
                }                                                                     \
            }                                                                         \
        } while (0)

        frag_u B1h[3], B1l[3], B2h[3], B2l[3], B3h[3], B3l[3];
        LOADPAIR(B1h[0], B1l[0], mfrag, ((w + 4) * 3 + 0) * 2);
        LOADPAIR(B1h[1], B1l[1], mfrag, ((w + 4) * 3 + 1) * 2);
        LOADPAIR(B1h[2], B1l[2], mfrag, ((w + 4) * 3 + 2) * 2);
        G0TILE(w, B0h, B0l);
        LOADPAIR(B2h[0], B2l[0], mfrag, ((w + 8) * 3 + 0) * 2);
        LOADPAIR(B2h[1], B2l[1], mfrag, ((w + 8) * 3 + 1) * 2);
        LOADPAIR(B2h[2], B2l[2], mfrag, ((w + 8) * 3 + 2) * 2);
        G0TILE(w + 4, B1h, B1l);
        if (w < 2) {
            LOADPAIR(B3h[0], B3l[0], mfrag, ((w + 12) * 3 + 0) * 2);
            LOADPAIR(B3h[1], B3l[1], mfrag, ((w + 12) * 3 + 1) * 2);
            LOADPAIR(B3h[2], B3l[2], mfrag, ((w + 12) * 3 + 2) * 2);
        }
        G0TILE(w + 8, B2h, B2l);
        if (w < 2) G0TILE(w + 12, B3h, B3l);
        #undef G0TILE
    }
    bar();

    // ---- G1 (MFMA): L^T = gkq(hi/lo) @ xwLC + bias ; wave = ntile ----
    {
        frag_u B[3];
        #pragma unroll
        for (int ks = 0; ks < 3; ++ks)
            B[ks].s = *reinterpret_cast<const short8*>(S + XWLC + (ks * 4 + w) * 1040 + (lane << 4));
        frag_u Ah[3], Al[3];
        #pragma unroll
        for (int ks = 0; ks < 3; ++ks) {
            const int off = (lane & 15) * 200 + (ks * 32 + (lane >> 4) * 8) * 2;
            Ah[ks].s = *reinterpret_cast<const short8*>(S + R2 + off);
            Al[ks].s = *reinterpret_cast<const short8*>(S + R2 + 3200 + off);
        }
        f32x4 acc = {0.f, 0.f, 0.f, 0.f};
        #pragma unroll
        for (int ks = 0; ks < 3; ++ks) {
            acc = __builtin_amdgcn_mfma_f32_16x16x32_bf16(Ah[ks].b, B[ks].b, acc, 0, 0, 0);
            acc = __builtin_amdgcn_mfma_f32_16x16x32_bf16(Al[ks].b, B[ks].b, acc, 0, 0, 0);
        }
        const int colL = w * 16 + (lane & 15);
        #pragma unroll
        for (int rr = 0; rr < 4; ++rr) {
            const int pr = (lane >> 4) * 4 + rr;
            Lraw[pr * 66 + colL] = acc[rr] + bias16[pr] + (pr < 8 ? scal0 : scal1);
        }
    }
    bar();

    // ---- SM: k-softmax rows over waves; q-softmax + qat hi/lo on wave 3 ----
    if (w < 3) {
        #pragma unroll
        for (int rr = 0; rr < 2; ++rr) {
            const int pp = w + 3 * rr;               // rows 0..5
            const float v = Lraw[pp * 66 + lane];
            float mx = v;
            #pragma unroll
            for (int off = 32; off; off >>= 1) mx = fmaxf(mx, __shfl_xor(mx, off));
            const float e = __expf(v - mx);
            float s = e;
            #pragma unroll
            for (int off = 32; off; off >>= 1) s += __shfl_xor(s, off);
            const float a = e / s;
            const __bf16 hb = (__bf16)a;
            const __bf16 lb = (__bf16)(a - (float)hb);
            const int ks = lane >> 5;
            const int off_b = ((pp + 16 * ((lane >> 3) & 3)) << 4) + ((lane & 7) << 1);
            *reinterpret_cast<__bf16*>(S + R2 + (ks << 10) + off_b) = hb;
            *reinterpret_cast<__bf16*>(S + R2 + ((2 + ks) << 10) + off_b) = lb;
        }
    } else {
        {
            const int pp = 6;
            const float v = Lraw[pp * 66 + lane];
            float mx = v;
            #pragma unroll
            for (int off = 32; off; off >>= 1) mx = fmaxf(mx, __shfl_xor(mx, off));
            const float e = __expf(v - mx);
            float s = e;
            #pragma unroll
            for (int off = 32; off; off >>= 1) s += __shfl_xor(s, off);
            const float a = e / s;
            const __bf16 hb = (__bf16)a;
            const __bf16 lb = (__bf16)(a - (float)hb);
            const int ks = lane >> 5;
            const int off_b = ((pp + 16 * ((lane >> 3) & 3)) << 4) + ((lane & 7) << 1);
            *reinterpret_cast<__bf16*>(S + R2 + (ks << 10) + off_b) = hb;
            *reinterpret_cast<__bf16*>(S + R2 + ((2 + ks) << 10) + off_b) = lb;
        }
        float vv[Pp];
        float mx = -1e30f;
        #pragma unroll
        for (int p = 0; p < Pp; ++p) { vv[p] = Lraw[(8 + p) * 66 + lane]; mx = fmaxf(mx, vv[p]); }
        float s = 0.f;
        #pragma unroll
        for (int p = 0; p < Pp; ++p) { vv[p] = __expf(vv[p] - mx); s += vv[p]; }
        const float inv = 1.f / s;
        frag_u qh, ql;
        #pragma unroll
        for (int p = 0; p < 8; ++p) {
            const float a = (p < Pp) ? vv[p] * inv : 0.f;
            const __bf16 hb = (__bf16)a;
            qh.b[p] = hb;
            ql.b[p] = (__bf16)(a - (float)hb);
        }
        *reinterpret_cast<short8*>(S + QATH + lane * 40)      = qh.s;
        *reinterpret_cast<short8*>(S + QATH + lane * 40 + 16) = zero8;
        *reinterpret_cast<short8*>(S + QATL + lane * 40)      = ql.s;
        *reinterpret_cast<short8*>(S + QATL + lane * 40 + 16) = zero8;
    }
    bar();

    // ---- G2 (MFMA) + wvfrag prefetch: xv^T = xw @ attn(hi/lo); write xv hi/lo ----
    frag_u V0h[3], V0l[3], V1h[3], V1l[3];
    {
        LOADPAIR(V0h[0], V0l[0], wvfrag, (w * 3 + 0) * 2);
        LOADPAIR(V0h[1], V0l[1], wvfrag, (w * 3 + 1) * 2);
        LOADPAIR(V0h[2], V0l[2], wvfrag, (w * 3 + 2) * 2);
        if (w < 2) {
            LOADPAIR(V1h[0], V1l[0], wvfrag, ((4 + w) * 3 + 0) * 2);
            LOADPAIR(V1h[1], V1l[1], wvfrag, ((4 + w) * 3 + 1) * 2);
            LOADPAIR(V1h[2], V1l[2], wvfrag, ((4 + w) * 3 + 2) * 2);
        }

        frag_u Bh[2], Bl[2];
        #pragma unroll
        for (int ks = 0; ks < 2; ++ks) {
            Bh[ks].s = *reinterpret_cast<const short8*>(S + R2 + (ks << 10) + (lane << 4));
            Bl[ks].s = *reinterpret_cast<const short8*>(S + R2 + ((2 + ks) << 10) + (lane << 4));
        }
        const int mt0 = (w < 2) ? w * 2 : (w + 2);
        const int nmt = (w < 2) ? 2 : 1;
        for (int m = 0; m < nmt; ++m) {
            const int mt = mt0 + m;
            f32x4 acc = {0.f, 0.f, 0.f, 0.f};
            #pragma unroll
            for (int ks = 0; ks < 2; ++ks) {
                frag_u A;
                A.s = xws_fragA(S, mt, ks, lane);
                acc = __builtin_amdgcn_mfma_f32_16x16x32_bf16(A.b, Bh[ks].b, acc, 0, 0, 0);
                acc = __builtin_amdgcn_mfma_f32_16x16x32_bf16(A.b, Bl[ks].b, acc, 0, 0, 0);
            }
            const int p = lane & 15;
            #pragma unroll
            for (int rr = 0; rr < 4; ++rr) {
                const int c = mt * 16 + (lane >> 4) * 4 + rr;
                put_hilo(S, R1 + p * 200 + c * 2, R1 + 3200 + p * 200 + c * 2, acc[rr]);
            }
        }
    }
    bar();

    // ---- G3 (MFMA): av^T = Wv(hi/lo) @ xv(hi/lo) + bv; write av hi/lo [96][16] ----
    {
        const bool pok = (lane & 15) < Pp;           // NaN guard: attn cols 7-15 aliased garbage
        frag_u Bh[3], Bl[3];
        #pragma unroll
        for (int ks = 0; ks < 3; ++ks) {
            const int off = (lane & 15) * 200 + (ks * 32 + (lane >> 4) * 8) * 2;
            Bh[ks].s = pok ? *reinterpret_cast<const short8*>(S + R1 + off)        : zero8;
            Bl[ks].s = pok ? *reinterpret_cast<const short8*>(S + R1 + 3200 + off) : zero8;
        }
        #define G3TILE(MT, VH, VL) do {                                               \
            f32x4 acc = {0.f, 0.f, 0.f, 0.f};                                         \
            acc = __builtin_amdgcn_mfma_f32_16x16x32_bf16(VH[0].b, Bh[0].b, acc, 0,0,0); \
            acc = __builtin_amdgcn_mfma_f32_16x16x32_bf16(VH[0].b, Bl[0].b, acc, 0,0,0); \
            acc = __builtin_amdgcn_mfma_f32_16x16x32_bf16(VL[0].b, Bh[0].b, acc, 0,0,0); \
            acc = __builtin_amdgcn_mfma_f32_16x16x32_bf16(VH[1].b, Bh[1].b, acc, 0,0,0); \
            acc = __builtin_amdgcn_mfma_f32_16x16x32_bf16(VH[1].b, Bl[1].b, acc, 0,0,0); \
            acc = __builtin_amdgcn_mfma_f32_16x16x32_bf16(VL[1].b, Bh[1].b, acc, 0,0,0); \
            acc = __builtin_amdgcn_mfma_f32_16x16x32_bf16(VH[2].b, Bh[2].b, acc, 0,0,0); \
            acc = __builtin_amdgcn_mfma_f32_16x16x32_bf16(VH[2].b, Bl[2].b, acc, 0,0,0); \
            acc = __builtin_amdgcn_mfma_f32_16x16x32_bf16(VL[2].b, Bh[2].b, acc, 0,0,0); \
            _Pragma("unroll")                                                         \
            for (int rr = 0; rr < 4; ++rr) {                                          \
                const int o_ = (MT) * 16 + (lane >> 4) * 4 + rr;                      \
                const float v_ = acc[rr] + bv[o_];                                    \
                put_hilo(S, AVH + o_ * 32 + (lane & 15) * 2,                          \
                         AVL + o_ * 32 + (lane & 15) * 2, v_);                        \
            }                                                                         \
        } while (0)
        G3TILE(w, V0h, V0l);
        if (w < 2) G3TILE(4 + w, V1h, V1l);
        #undef G3TILE
    }
    bar();

    // ---- P7 (MFMA): out^T[96o][64l] = av_ext @ qat^T (K=32, 3-term hi/lo) ----
    {
        const int kblk = lane >> 4, nlow = lane & 15;
        const int l = w * 16 + nlow;
        frag_u Bh, Bl;
        if (kblk < 2) {
            Bh.s = *reinterpret_cast<const short8*>(S + QATH + l * 40 + kblk * 16);
            Bl.s = *reinterpret_cast<const short8*>(S + QATL + l * 40 + kblk * 16);
        } else { Bh.s = zero8; Bl.s = zero8; }
        const int obase = b * C_ * HWp + (h0 + (l >> 3)) * Wimg + w0 + (l & 7);
        #pragma unroll
        for (int mt = 0; mt < 6; ++mt) {
            frag_u Ah, Al;
            if (kblk < 2) {
                Ah.s = *reinterpret_cast<const short8*>(S + AVH + (mt * 16 + nlow) * 32 + kblk * 16);
                Al.s = *reinterpret_cast<const short8*>(S + AVL + (mt * 16 + nlow) * 32 + kblk * 16);
            } else { Ah.s = zero8; Al.s = zero8; }
            f32x4 acc = {0.f, 0.f, 0.f, 0.f};
            acc = __builtin_amdgcn_mfma_f32_16x16x32_bf16(Ah.b, Bh.b, acc, 0, 0, 0);
            acc = __builtin_amdgcn_mfma_f32_16x16x32_bf16(Ah.b, Bl.b, acc, 0, 0, 0);
            acc = __builtin_amdgcn_mfma_f32_16x16x32_bf16(Al.b, Bh.b, acc, 0, 0, 0);
            #pragma unroll
            for (int rr = 0; rr < 4; ++rr) {
                const int o = mt * 16 + kblk * 4 + rr;
                out[obase + o * HWp] = acc[rr];
            }
        }
    }
}

// ---------------- launch ----------------

extern "C" void kernel_launch(void* const* d_in, const int* in_sizes, int n_in,
                              void* d_out, int out_size, void* d_ws, size_t ws_size,
                              hipStream_t stream)
{
    const float* x  = (const float*)d_in[0];
    const float* Wv = (const float*)d_in[1];
    const float* bv = (const float*)d_in[2];
    const float* Wq = (const float*)d_in[3];
    const float* bq = (const float*)d_in[4];
    const float* Wk = (const float*)d_in[5];
    const float* bk = (const float*)d_in[6];
    float* out = (float*)d_out;

    float* ws = (float*)d_ws;
    float* Mk   = ws;                 // 9216
    float* Mq   = ws + 9216;          // 9216
    float* uk   = ws + 18432;
    float* uq   = ws + 18528;
    float* bk2  = ws + 18624;
    float* bq2  = ws + 18720;
    float* scal = ws + 18816;
    unsigned char* wsb = (unsigned char*)d_ws;

    hipLaunchKernelGGL(precompute_mats, dim3(C_), dim3(C_), 0, stream,
                       Wq, Wk, Mk, Mq);
    hipLaunchKernelGGL(precompute_vecs, dim3(1), dim3(C_), 0, stream,
                       Wq, Wk, bq, bk, uk, uq, bk2, bq2, scal);
    hipLaunchKernelGGL(precompute_frags, dim3(120), dim3(64), 0, stream,
                       ws, Wv, wsb);
    hipLaunchKernelGGL(camixer_main, dim3(8 * NWIN * NWIN), dim3(256), 0, stream,
                       x, bv, bk2, bq2, scal,
                       wsb + WS_FRAG_BYTE, wsb + WS_WV_BYTE, out);
}

// Round 11
// 75.377 us; speedup vs baseline: 5.0562x; 1.0384x over previous
//
#include <hip/hip_runtime.h>

// CAMixer agent-attention, fused per-window (8x8).  v11 = v9 numerics + LDS diet:
//  - single xw copy (XWS row-major XOR-swizzled, proven since v7). The XWLC
//    duplicate (12.5KB) is deleted; G1's c-contiguous B-frag is gathered with
//    24 ds_read_u16/lane (one phase, once per block). v10's tr-read reverted
//    (semantics mismatch -> absmax 5.3).
//  - 8-row xp/xv hi/lo images; gkq->attn->av lifetime-aliased region.
//    LDS 37,888 -> 31,296 B -> 5 blocks/CU (was 4).
//
// Algebra (exact refactor, verified round 1):
//   agent   = conv(pool(x), Wq)
//   k-logit[p][l] = xw[l]·gk[p] + bkd[p],  gk = xp @ Mk + bk2,  Mk = Wq^T Wk
//   q-logit[l][p] = xw[l]·gq[p] + bqd[p],  gq = xp @ Mq + bq2,  Mq = Wq^T Wq
//   agent_v = (a_attn @ xw) @ Wv^T + bv
//
// MFMA conventions (verified v5-v9):
//   A-frag: lane = row + 16*kblk holds A[row][ks*32 + kblk*8 + j], j=0..7
//   B-frag: lane = col + 16*kblk holds B[ks*32 + kblk*8 + j][col]
//   C-frag: col = lane&15, row = (lane>>4)*4 + reg
//
// XWS layout (v7-proven): element (c,l) at byte c*128 + ((l*2) ^ ((c&7)<<4))

constexpr int C_   = 96;
constexpr int Wimg = 192;
constexpr int HWp  = 192 * 192;
constexpr int NWIN = 24;
constexpr int Pp   = 7;

typedef __attribute__((ext_vector_type(8))) __bf16 bf16x8;
typedef __attribute__((ext_vector_type(4))) __bf16 bf16x4;
typedef __attribute__((ext_vector_type(8))) short  short8;
typedef __attribute__((ext_vector_type(4))) float  f32x4;
union frag_u { short8 s; bf16x8 b; };

// ---- LDS byte offsets (total 31,296 B -> 5 blocks/CU) ----
constexpr int XWS   = 0;       // xw bf16 [96][64], 128B rows, XOR-swizzled (12,288)
constexpr int XPH   = 12288;   // xp/xv hi [8][100]bf16 (1,600); xp: G_P->G0, xv: G2->G3
constexpr int XPL   = 13888;   // xp/xv lo
constexpr int GKA   = 15488;   // region 6,400: gkq hi/lo -> attn(4x1KB) -> av hi/lo
constexpr int GKQH  = GKA;             // [16][100]bf16 (3,200)
constexpr int GKQL  = GKA + 3200;
constexpr int AVH   = GKA;             // av hi [96][16]bf16 (3,072), after attn dead
constexpr int AVL   = GKA + 3072;
constexpr int QATH  = 21888;   // qat hi [64][20]bf16 (2,560)
constexpr int QATL  = 24448;   // qat lo
constexpr int LRAW  = 27008;   // [16][66] f32 (4,224)
constexpr int BIAS  = 31232;   // f32[16]
constexpr int SMEMB = 31296;

// ---- ws float offsets ----
constexpr int WS_FRAG_BYTE = 18944 * 4;                 // Mext frags: 84 slots x 1KB
constexpr int WS_WV_BYTE   = WS_FRAG_BYTE + 84 * 1024;  // Wv frags: 36 slots x 1KB

// ---------------- helpers ----------------

__device__ __forceinline__ void bar() {
    asm volatile("s_waitcnt lgkmcnt(0)" ::: "memory");
    __builtin_amdgcn_s_barrier();
}

// A-frag (m=c, k=l) of xw, tile (mt, ks), from swizzled row-major (v7-proven).
__device__ __forceinline__ short8 xws_fragA(const unsigned char* S, int mt, int ks, int lane) {
    const int c  = mt * 16 + (lane & 15);
    const int l2 = ks * 64 + ((lane >> 4) << 4);
    return *reinterpret_cast<const short8*>(S + XWS + c * 128 + (l2 ^ ((c & 7) << 4)));
}

__device__ __forceinline__ void put_hilo(unsigned char* S, int hi_off, int lo_off, float v) {
    const __bf16 h = (__bf16)v;
    *reinterpret_cast<__bf16*>(S + hi_off) = h;
    *reinterpret_cast<__bf16*>(S + lo_off) = (__bf16)(v - (float)h);
}

// ---------------- precompute (weights only, trivial cost) ----------------

__global__ void precompute_mats(const float* __restrict__ Wq,
                                const float* __restrict__ Wk,
                                float* __restrict__ Mk,
                                float* __restrict__ Mq)
{
    const int c  = blockIdx.x;
    const int cp = threadIdx.x;
    float ak = 0.f, aq = 0.f;
    for (int a = 0; a < C_; ++a) {
        const float wq = Wq[a * C_ + c];
        ak = fmaf(wq, Wk[a * C_ + cp], ak);
        aq = fmaf(wq, Wq[a * C_ + cp], aq);
    }
    Mk[c * C_ + cp] = ak;
    Mq[c * C_ + cp] = aq;
}

__global__ void precompute_vecs(const float* __restrict__ Wq,
                                const float* __restrict__ Wk,
                                const float* __restrict__ bq,
                                const float* __restrict__ bk,
                                float* __restrict__ uk,  float* __restrict__ uq,
                                float* __restrict__ bk2, float* __restrict__ bq2,
                                float* __restrict__ scal)
{
    const int c = threadIdx.x;
    float a_uk = 0.f, a_uq = 0.f, a_bk2 = 0.f, a_bq2 = 0.f;
    for (int a = 0; a < C_; ++a) {
        const float wqc = Wq[a * C_ + c];
        a_uk  = fmaf(wqc, bk[a], a_uk);
        a_uq  = fmaf(wqc, bq[a], a_uq);
        a_bk2 = fmaf(bq[a], Wk[a * C_ + c], a_bk2);
        a_bq2 = fmaf(bq[a], Wq[a * C_ + c], a_bq2);
    }
    uk[c] = a_uk; uq[c] = a_uq; bk2[c] = a_bk2; bq2[c] = a_bq2;
    if (c == 0) {
        float sk = 0.f, sq = 0.f;
        for (int a = 0; a < C_; ++a) { sk += bq[a] * bk[a]; sq += bq[a] * bq[a]; }
        scal[0] = sk; scal[1] = sq;
    }
}

// frag tables: bid<84: Mext B-frags slot=((mat*7+nt)*3+ks)*2+hl; else Wv A-frags.
__global__ void precompute_frags(const float* __restrict__ ws,
                                 const float* __restrict__ Wv,
                                 unsigned char* __restrict__ wsb)
{
    const int bid = blockIdx.x, lane = threadIdx.x;
    short8 o;
    if (bid < 84) {
        const int hl = bid & 1, ks = (bid >> 1) % 3, nt = (bid / 6) % 7, mat = bid / 42;
        const float* M = ws + (mat ? 9216 : 0);
        const float* u = ws + (mat ? 18528 : 18432);
        const int col = nt * 16 + (lane & 15);
        #pragma unroll
        for (int j = 0; j < 8; ++j) {
            const int k = ks * 32 + (lane >> 4) * 8 + j;
            const float raw = (col < 96) ? M[k * 96 + col] : ((col == 96) ? u[k] : 0.f);
            const __bf16 hi = (__bf16)raw;
            union { __bf16 h; short s; } cv;
            cv.h = hl ? (__bf16)(raw - (float)hi) : hi;
            o[j] = cv.s;
        }
        *reinterpret_cast<short8*>(wsb + WS_FRAG_BYTE + bid * 1024 + lane * 16) = o;
    } else {
        const int wb = bid - 84;
        const int hl = wb & 1, ks = (wb >> 1) % 3, mt = wb / 6;
        const int row = mt * 16 + (lane & 15);
        #pragma unroll
        for (int j = 0; j < 8; ++j) {
            const int c = ks * 32 + (lane >> 4) * 8 + j;
            const float raw = Wv[row * 96 + c];
            const __bf16 hi = (__bf16)raw;
            union { __bf16 h; short s; } cv;
            cv.h = hl ? (__bf16)(raw - (float)hi) : hi;
            o[j] = cv.s;
        }
        *reinterpret_cast<short8*>(wsb + WS_WV_BYTE + wb * 1024 + lane * 16) = o;
    }
}

#define LOADPAIR(dstH, dstL, tab, slot_h) do {                                               \
    (dstH).s = *reinterpret_cast<const short8*>((tab) + (slot_h) * 1024 + (lane << 4));      \
    (dstL).s = *reinterpret_cast<const short8*>((tab) + ((slot_h) + 1) * 1024 + (lane << 4));\
} while (0)

// ---------------- main fused kernel ----------------

__global__ __launch_bounds__(256, 5) void camixer_main(
    const float* __restrict__ x,
    const float* __restrict__ bv,
    const float* __restrict__ bk2,
    const float* __restrict__ bq2,
    const float* __restrict__ scal,
    const unsigned char* __restrict__ mfrag,
    const unsigned char* __restrict__ wvfrag,
    float* __restrict__ out)
{
    __shared__ __align__(16) unsigned char S[SMEMB];
    float* Lraw   = (float*)(S + LRAW);  // [16][66]
    float* bias16 = (float*)(S + BIAS);  // [16]

    const int t = threadIdx.x;
    const int lane = t & 63, w = t >> 6;
    const int wid = ((blockIdx.x & 7) * 576) + (blockIdx.x >> 3);  // bijective XCD swizzle
    const int b  = wid / (NWIN * NWIN);
    const int r  = wid % (NWIN * NWIN);
    const int h0 = (r / NWIN) * 8;
    const int w0 = (r % NWIN) * 8;
    const int base = b * C_ * HWp + h0 * Wimg + w0;
    const float scal0 = scal[0], scal1 = scal[1];
    const short8 zero8 = {0, 0, 0, 0, 0, 0, 0, 0};

    // ---- prefetch G0 tile tt=w: in flight under P0 + G_P ----
    frag_u B0h[3], B0l[3];
    LOADPAIR(B0h[0], B0l[0], mfrag, (w * 3 + 0) * 2);
    LOADPAIR(B0h[1], B0l[1], mfrag, (w * 3 + 1) * 2);
    LOADPAIR(B0h[2], B0l[2], mfrag, (w * 3 + 2) * 2);

    // ---- P0: x window -> bf16 XOR-swizzled row-major (single copy) ----
    {
        const float4* x4 = reinterpret_cast<const float4*>(x);
        #pragma unroll
        for (int rr = 0; rr < 2; ++rr) {
            const int idx = t + (rr << 8);          // 384 = 24 c4 x 8 dh x 2 dw4
            if (idx < 384) {
                const int dw4 = idx & 1;
                const int dh  = (idx >> 1) & 7;
                const int c4  = idx >> 4;
                const int c0 = c4 * 4, l0 = dh * 8 + dw4 * 4;
                #pragma unroll
                for (int j = 0; j < 4; ++j) {
                    const int c = c0 + j;
                    const float4 v = x4[(base + c * HWp + dh * Wimg + dw4 * 4) >> 2];
                    bf16x4 d = {(__bf16)v.x, (__bf16)v.y, (__bf16)v.z, (__bf16)v.w};
                    *reinterpret_cast<bf16x4*>(S + XWS + c * 128 + ((l0 * 2) ^ ((c & 7) << 4))) = d;
                }
            }
        }
    }
    bar();

    // ---- G_P (MFMA): xp = P^T(hi/lo) @ xw^T ; write xp hi/lo (8 rows) ----
    {
        frag_u PAh[2], PAl[2];
        {
            const int p = lane & 15;
            const __bf16 PH = (__bf16)0.1f;
            const __bf16 PL = (__bf16)(0.1f - (float)PH);
            const int sp = (p < 7) ? ((p << 6) / 7) : 1000;
            #pragma unroll
            for (int ks = 0; ks < 2; ++ks)
                #pragma unroll
                for (int j = 0; j < 8; ++j) {
                    const int l = ks * 32 + (lane >> 4) * 8 + j;
                    const bool in = (l >= sp) && (l < sp + 10);
                    PAh[ks].b[j] = in ? PH : (__bf16)0.f;
                    PAl[ks].b[j] = in ? PL : (__bf16)0.f;
                }
        }
        #pragma unroll
        for (int rnd = 0; rnd < 2; ++rnd) {
            const int nt = rnd ? (4 + w) : w;
            if (rnd == 0 || w < 2) {
                f32x4 acc = {0.f, 0.f, 0.f, 0.f};
                #pragma unroll
                for (int ks = 0; ks < 2; ++ks) {
                    frag_u B;
                    B.s = xws_fragA(S, nt, ks, lane);
                    acc = __builtin_amdgcn_mfma_f32_16x16x32_bf16(PAh[ks].b, B.b, acc, 0, 0, 0);
                    acc = __builtin_amdgcn_mfma_f32_16x16x32_bf16(PAl[ks].b, B.b, acc, 0, 0, 0);
                }
                const int cc = nt * 16 + (lane & 15);
                #pragma unroll
                for (int rr = 0; rr < 4; ++rr) {
                    const int p = (lane >> 4) * 4 + rr;
                    if (p < 8)
                        put_hilo(S, XPH + p * 200 + cc * 2, XPL + p * 200 + cc * 2, acc[rr]);
                }
            }
        }
    }
    bar();

    // ---- G0 (MFMA, pipelined): gkq = xp(hi/lo) @ Mext(hi/lo); nt6 = bias dots ----
    {
        frag_u Ah[3], Al[3];
        #pragma unroll
        for (int ks = 0; ks < 3; ++ks) {
            const int off = ((lane & 15) & 7) * 200 + (ks * 32 + (lane >> 4) * 8) * 2;
            Ah[ks].s = *reinterpret_cast<const short8*>(S + XPH + off);
            Al[ks].s = *reinterpret_cast<const short8*>(S + XPL + off);
        }

        #define G0TILE(TT, BH, BL) do {                                               \
            const int tt_ = (TT);                                                     \
            const int mat_ = (tt_ >= 7) ? 1 : 0;                                      \
            const int nt_  = tt_ - 7 * mat_;                                          \
            f32x4 acc = {0.f, 0.f, 0.f, 0.f};                                         \
            acc = __builtin_amdgcn_mfma_f32_16x16x32_bf16(Ah[0].b, BH[0].b, acc, 0,0,0); \
            acc = __builtin_amdgcn_mfma_f32_16x16x32_bf16(Ah[0].b, BL[0].b, acc, 0,0,0); \
            acc = __builtin_amdgcn_mfma_f32_16x16x32_bf16(Al[0].b, BH[0].b, acc, 0,0,0); \
            acc = __builtin_amdgcn_mfma_f32_16x16x32_bf16(Ah[1].b, BH[1].b, acc, 0,0,0); \
            acc = __builtin_amdgcn_mfma_f32_16x16x32_bf16(Ah[1].b, BL[1].b, acc, 0,0,0); \
            acc = __builtin_amdgcn_mfma_f32_16x16x32_bf16(Al[1].b, BH[1].b, acc, 0,0,0); \
            acc = __builtin_amdgcn_mfma_f32_16x16x32_bf16(Ah[2].b, BH[2].b, acc, 0,0,0); \
            acc = __builtin_amdgcn_mfma_f32_16x16x32_bf16(Ah[2].b, BL[2].b, acc, 0,0,0); \
            acc = __builtin_amdgcn_mfma_f32_16x16x32_bf16(Al[2].b, BH[2].b, acc, 0,0,0); \
            const int row0_ = (lane >> 4) * 4;                                        \
            if (nt_ < 6) {                                                            \
                const int cc_ = nt_ * 16 + (lane & 15);                               \
                const float b2v_ = (mat_ ? bq2 : bk2)[cc_];                           \
                _Pragma("unroll")                                                     \
                for (int rr = 0; rr < 4; ++rr) {                                      \
                    const int rw_ = row0_ + rr;                                       \
                    if (rw_ < 8) {                                                    \
                        const int pr_ = rw_ + 8 * mat_;                               \
                        put_hilo(S, GKQH + pr_ * 200 + cc_ * 2,                       \
                                 GKQL + pr_ * 200 + cc_ * 2, acc[rr] + b2v_);         \
                    }                                                                 \
                }                                                                     \
            } else if ((lane & 15) == 0) {                                            \
                _Pragma("unroll")                                                     \
                for (int rr = 0; rr < 4; ++rr) {                                      \
                    const int rw_ = row0_ + rr;                                       \
                    if (rw_ < 8) bias16[rw_ + 8 * mat_] = acc[rr];                    \
                }                                                                     \
            }                                                                         \
        } while (0)

        frag_u B1h[3], B1l[3], B2h[3], B2l[3], B3h[3], B3l[3];
        LOADPAIR(B1h[0], B1l[0], mfrag, ((w + 4) * 3 + 0) * 2);
        LOADPAIR(B1h[1], B1l[1], mfrag, ((w + 4) * 3 + 1) * 2);
        LOADPAIR(B1h[2], B1l[2], mfrag, ((w + 4) * 3 + 2) * 2);
        G0TILE(w, B0h, B0l);
        LOADPAIR(B2h[0], B2l[0], mfrag, ((w + 8) * 3 + 0) * 2);
        LOADPAIR(B2h[1], B2l[1], mfrag, ((w + 8) * 3 + 1) * 2);
        LOADPAIR(B2h[2], B2l[2], mfrag, ((w + 8) * 3 + 2) * 2);
        G0TILE(w + 4, B1h, B1l);
        if (w < 2) {
            LOADPAIR(B3h[0], B3l[0], mfrag, ((w + 12) * 3 + 0) * 2);
            LOADPAIR(B3h[1], B3l[1], mfrag, ((w + 12) * 3 + 1) * 2);
            LOADPAIR(B3h[2], B3l[2], mfrag, ((w + 12) * 3 + 2) * 2);
        }
        G0TILE(w + 8, B2h, B2l);
        if (w < 2) G0TILE(w + 12, B3h, B3l);
        #undef G0TILE
    }
    bar();

    // ---- G1 (MFMA): L^T = gkq(hi/lo) @ xw + bias ; B via u16 gather from XWS ----
    {
        // B-frag: lane needs xw[c = ks*32 + kblk*8 + j][l = w*16 + (lane&15)],
        // c-contiguous -> 8 computed addrs (swizzle XOR varies with j), ks via imm.
        frag_u B[3];
        {
            const int l2 = (w * 16 + (lane & 15)) * 2;
            const int kb = (lane >> 4) << 10;          // kblk*8 rows * 128B
            #pragma unroll
            for (int j = 0; j < 8; ++j) {
                const int aj = kb + j * 128 + (l2 ^ (j << 4));
                B[0].b[j] = *reinterpret_cast<const __bf16*>(S + XWS + aj);
                B[1].b[j] = *reinterpret_cast<const __bf16*>(S + XWS + 4096 + aj);
                B[2].b[j] = *reinterpret_cast<const __bf16*>(S + XWS + 8192 + aj);
            }
        }
        frag_u Ah[3], Al[3];
        #pragma unroll
        for (int ks = 0; ks < 3; ++ks) {
            const int off = (lane & 15) * 200 + (ks * 32 + (lane >> 4) * 8) * 2;
            Ah[ks].s = *reinterpret_cast<const short8*>(S + GKQH + off);
            Al[ks].s = *reinterpret_cast<const short8*>(S + GKQL + off);
        }
        f32x4 acc = {0.f, 0.f, 0.f, 0.f};
        #pragma unroll
        for (int ks = 0; ks < 3; ++ks) {
            acc = __builtin_amdgcn_mfma_f32_16x16x32_bf16(Ah[ks].b, B[ks].b, acc, 0, 0, 0);
            acc = __builtin_amdgcn_mfma_f32_16x16x32_bf16(Al[ks].b, B[ks].b, acc, 0, 0, 0);
        }
        const int colL = w * 16 + (lane & 15);
        #pragma unroll
        for (int rr = 0; rr < 4; ++rr) {
            const int pr = (lane >> 4) * 4 + rr;
            Lraw[pr * 66 + colL] = acc[rr] + bias16[pr] + (pr < 8 ? scal0 : scal1);
        }
    }
    bar();

    // ---- SM: k-softmax rows over waves; q-softmax + qat hi/lo on wave 3 ----
    if (w < 3) {
        #pragma unroll
        for (int rr = 0; rr < 2; ++rr) {
            const int pp = w + 3 * rr;               // rows 0..5
            const float v = Lraw[pp * 66 + lane];
            float mx = v;
            #pragma unroll
            for (int off = 32; off; off >>= 1) mx = fmaxf(mx, __shfl_xor(mx, off));
            const float e = __expf(v - mx);
            float s = e;
            #pragma unroll
            for (int off = 32; off; off >>= 1) s += __shfl_xor(s, off);
            const float a = e / s;
            const __bf16 hb = (__bf16)a;
            const __bf16 lb = (__bf16)(a - (float)hb);
            const int ks = lane >> 5;
            const int off_b = ((pp + 16 * ((lane >> 3) & 3)) << 4) + ((lane & 7) << 1);
            *reinterpret_cast<__bf16*>(S + GKA + (ks << 10) + off_b) = hb;
            *reinterpret_cast<__bf16*>(S + GKA + ((2 + ks) << 10) + off_b) = lb;
        }
    } else {
        {
            const int pp = 6;
            const float v = Lraw[pp * 66 + lane];
            float mx = v;
            #pragma unroll
            for (int off = 32; off; off >>= 1) mx = fmaxf(mx, __shfl_xor(mx, off));
            const float e = __expf(v - mx);
            float s = e;
            #pragma unroll
            for (int off = 32; off; off >>= 1) s += __shfl_xor(s, off);
            const float a = e / s;
            const __bf16 hb = (__bf16)a;
            const __bf16 lb = (__bf16)(a - (float)hb);
            const int ks = lane >> 5;
            const int off_b = ((pp + 16 * ((lane >> 3) & 3)) << 4) + ((lane & 7) << 1);
            *reinterpret_cast<__bf16*>(S + GKA + (ks << 10) + off_b) = hb;
            *reinterpret_cast<__bf16*>(S + GKA + ((2 + ks) << 10) + off_b) = lb;
        }
        float vv[Pp];
        float mx = -1e30f;
        #pragma unroll
        for (int p = 0; p < Pp; ++p) { vv[p] = Lraw[(8 + p) * 66 + lane]; mx = fmaxf(mx, vv[p]); }
        float s = 0.f;
        #pragma unroll
        for (int p = 0; p < Pp; ++p) { vv[p] = __expf(vv[p] - mx); s += vv[p]; }
        const float inv = 1.f / s;
        frag_u qh, ql;
        #pragma unroll
        for (int p = 0; p < 8; ++p) {
            const float a = (p < Pp) ? vv[p] * inv : 0.f;
            const __bf16 hb = (__bf16)a;
            qh.b[p] = hb;
            ql.b[p] = (__bf16)(a - (float)hb);
        }
        *reinterpret_cast<short8*>(S + QATH + lane * 40)      = qh.s;
        *reinterpret_cast<short8*>(S + QATH + lane * 40 + 16) = zero8;
        *reinterpret_cast<short8*>(S + QATL + lane * 40)      = ql.s;
        *reinterpret_cast<short8*>(S + QATL + lane * 40 + 16) = zero8;
    }
    bar();

    // ---- G2 (MFMA) + wvfrag prefetch: xv^T = xw @ attn(hi/lo); write xv hi/lo ----
    frag_u V0h[3], V0l[3], V1h[3], V1l[3];
    {
        LOADPAIR(V0h[0], V0l[0], wvfrag, (w * 3 + 0) * 2);
        LOADPAIR(V0h[1], V0l[1], wvfrag, (w * 3 + 1) * 2);
        LOADPAIR(V0h[2], V0l[2], wvfrag, (w * 3 + 2) * 2);
        if (w < 2) {
            LOADPAIR(V1h[0], V1l[0], wvfrag, ((4 + w) * 3 + 0) * 2);
            LOADPAIR(V1h[1], V1l[1], wvfrag, ((4 + w) * 3 + 1) * 2);
            LOADPAIR(V1h[2], V1l[2], wvfrag, ((4 + w) * 3 + 2) * 2);
        }

        frag_u Bh[2], Bl[2];
        #pragma unroll
        for (int ks = 0; ks < 2; ++ks) {
            Bh[ks].s = *reinterpret_cast<const short8*>(S + GKA + (ks << 10) + (lane << 4));
            Bl[ks].s = *reinterpret_cast<const short8*>(S + GKA + ((2 + ks) << 10) + (lane << 4));
        }
        const int mt0 = (w < 2) ? w * 2 : (w + 2);
        const int nmt = (w < 2) ? 2 : 1;
        for (int m = 0; m < nmt; ++m) {
            const int mt = mt0 + m;
            f32x4 acc = {0.f, 0.f, 0.f, 0.f};
            #pragma unroll
            for (int ks = 0; ks < 2; ++ks) {
                frag_u A;
                A.s = xws_fragA(S, mt, ks, lane);
                acc = __builtin_amdgcn_mfma_f32_16x16x32_bf16(A.b, Bh[ks].b, acc, 0, 0, 0);
                acc = __builtin_amdgcn_mfma_f32_16x16x32_bf16(A.b, Bl[ks].b, acc, 0, 0, 0);
            }
            const int p = lane & 15;
            if (p < 8) {                              // rows >=8 never read
                #pragma unroll
                for (int rr = 0; rr < 4; ++rr) {
                    const int c = mt * 16 + (lane >> 4) * 4 + rr;
                    put_hilo(S, XPH + p * 200 + c * 2, XPL + p * 200 + c * 2, acc[rr]);
                }
            }
        }
    }
    bar();

    // ---- G3 (MFMA): av^T = Wv(hi/lo) @ xv(hi/lo) + bv; write av hi/lo [96][16] ----
    {
        const bool pok = (lane & 15) < Pp;           // NaN/garbage guard (xv row 7, cols>=7)
        frag_u Bh[3], Bl[3];
        #pragma unroll
        for (int ks = 0; ks < 3; ++ks) {
            const int off = ((lane & 15) & 7) * 200 + (ks * 32 + (lane >> 4) * 8) * 2;
            Bh[ks].s = pok ? *reinterpret_cast<const short8*>(S + XPH + off) : zero8;
            Bl[ks].s = pok ? *reinterpret_cast<const short8*>(S + XPL + off) : zero8;
        }
        #define G3TILE(MT, VH, VL) do {                                               \
            f32x4 acc = {0.f, 0.f, 0.f, 0.f};                                         \
            acc = __builtin_amdgcn_mfma_f32_16x16x32_bf16(VH[0].b, Bh[0].b, acc, 0,0,0); \
            acc = __builtin_amdgcn_mfma_f32_16x16x32_bf16(VH[0].b, Bl[0].b, acc, 0,0,0); \
            acc = __builtin_amdgcn_mfma_f32_16x16x32_bf16(VL[0].b, Bh[0].b, acc, 0,0,0); \
            acc = __builtin_amdgcn_mfma_f32_16x16x32_bf16(VH[1].b, Bh[1].b, acc, 0,0,0); \
            acc = __builtin_amdgcn_mfma_f32_16x16x32_bf16(VH[1].b, Bl[1].b, acc, 0,0,0); \
            acc = __builtin_amdgcn_mfma_f32_16x16x32_bf16(VL[1].b, Bh[1].b, acc, 0,0,0); \
            acc = __builtin_amdgcn_mfma_f32_16x16x32_bf16(VH[2].b, Bh[2].b, acc, 0,0,0); \
            acc = __builtin_amdgcn_mfma_f32_16x16x32_bf16(VH[2].b, Bl[2].b, acc, 0,0,0); \
            acc = __builtin_amdgcn_mfma_f32_16x16x32_bf16(VL[2].b, Bh[2].b, acc, 0,0,0); \
            _Pragma("unroll")                                                         \
            for (int rr = 0; rr < 4; ++rr) {                                          \
                const int o_ = (MT) * 16 + (lane >> 4) * 4 + rr;                      \
                const float v_ = acc[rr] + bv[o_];                                    \
                put_hilo(S, AVH + o_ * 32 + (lane & 15) * 2,                          \
                         AVL + o_ * 32 + (lane & 15) * 2, v_);                        \
            }                                                                         \
        } while (0)
        G3TILE(w, V0h, V0l);
        if (w < 2) G3TILE(4 + w, V1h, V1l);
        #undef G3TILE
    }
    bar();

    // ---- P7 (MFMA): out^T[96o][64l] = av_ext @ qat^T (K=32, 3-term hi/lo) ----
    {
        const int kblk = lane >> 4, nlow = lane & 15;
        const int l = w * 16 + nlow;
        frag_u Bh, Bl;
        if (kblk < 2) {
            Bh.s = *reinterpret_cast<const short8*>(S + QATH + l * 40 + kblk * 16);
            Bl.s = *reinterpret_cast<const short8*>(S + QATL + l * 40 + kblk * 16);
        } else { Bh.s = zero8; Bl.s = zero8; }
        const int obase = b * C_ * HWp + (h0 + (l >> 3)) * Wimg + w0 + (l & 7);
        #pragma unroll
        for (int mt = 0; mt < 6; ++mt) {
            frag_u Ah, Al;
            if (kblk < 2) {
                Ah.s = *reinterpret_cast<const short8*>(S + AVH + (mt * 16 + nlow) * 32 + kblk * 16);
                Al.s = *reinterpret_cast<const short8*>(S + AVL + (mt * 16 + nlow) * 32 + kblk * 16);
            } else { Ah.s = zero8; Al.s = zero8; }
            f32x4 acc = {0.f, 0.f, 0.f, 0.f};
            acc = __builtin_amdgcn_mfma_f32_16x16x32_bf16(Ah.b, Bh.b, acc, 0, 0, 0);
            acc = __builtin_amdgcn_mfma_f32_16x16x32_bf16(Ah.b, Bl.b, acc, 0, 0, 0);
            acc = __builtin_amdgcn_mfma_f32_16x16x32_bf16(Al.b, Bh.b, acc, 0, 0, 0);
            #pragma unroll
            for (int rr = 0; rr < 4; ++rr) {
                const int o = mt * 16 + kblk * 4 + rr;
                out[obase + o * HWp] = acc[rr];
            }
        }
    }
}

// ---------------- launch ----------------

extern "C" void kernel_launch(void* const* d_in, const int* in_sizes, int n_in,
                              void* d_out, int out_size, void* d_ws, size_t ws_size,
                              hipStream_t stream)
{
    const float* x  = (const float*)d_in[0];
    const float* Wv = (const float*)d_in[1];
    const float* bv = (const float*)d_in[2];
    const float* Wq = (const float*)d_in[3];
    const float* bq = (const float*)d_in[4];
    const float* Wk = (const float*)d_in[5];
    const float* bk = (const float*)d_in[6];
    float* out = (float*)d_out;

    float* ws = (float*)d_ws;
    float* Mk   = ws;                 // 9216
    float* Mq   = ws + 9216;          // 9216
    float* uk   = ws + 18432;
    float* uq   = ws + 18528;
    float* bk2  = ws + 18624;
    float* bq2  = ws + 18720;
    float* scal = ws + 18816;
    unsigned char* wsb = (unsigned char*)d_ws;

    hipLaunchKernelGGL(precompute_mats, dim3(C_), dim3(C_), 0, stream,
                       Wq, Wk, Mk, Mq);
    hipLaunchKernelGGL(precompute_vecs, dim3(1), dim3(C_), 0, stream,
                       Wq, Wk, bq, bk, uk, uq, bk2, bq2, scal);
    hipLaunchKernelGGL(precompute_frags, dim3(120), dim3(64), 0, stream,
                       ws, Wv, wsb);
    hipLaunchKernelGGL(camixer_main, dim3(8 * NWIN * NWIN), dim3(256), 0, stream,
                       x, bv, bk2, bq2, scal,
                       wsb + WS_FRAG_BYTE, wsb + WS_WV_BYTE, out);
}